// Round 1
// baseline (2177.087 us; speedup 1.0000x reference)
//
#include <hip/hip_runtime.h>
#include <hip/hip_bf16.h>
#include <cstddef>
#include <cstdint>

// Problem constants (from reference): B=16, CIN=COUT=64, HID=32, H=W=32, K=5, PAD=2
#define NTOK 1024      // H*W
#define NB   16        // batch
#define NC   64        // channels (CIN == COUT)
#define NHID 32        // attention hidden

__device__ __forceinline__ float wave_max(float v) {
#pragma unroll
  for (int off = 32; off > 0; off >>= 1) v = fmaxf(v, __shfl_xor(v, off, 64));
  return v;
}
__device__ __forceinline__ float wave_sum(float v) {
#pragma unroll
  for (int off = 32; off > 0; off >>= 1) v += __shfl_xor(v, off, 64);
  return v;
}

// out[b,d,n] = sum_c W[d,c] * x[b,c,n];  x:[B,64,1024], W:[D,64]
__global__ __launch_bounds__(256) void proj_kernel(
    const float* __restrict__ W, const float* __restrict__ x,
    float* __restrict__ out, int D) {
  int n = blockIdx.x * 256 + threadIdx.x;
  int d = blockIdx.y, b = blockIdx.z;
  const float* xb = x + (size_t)b * NC * NTOK + n;
  const float* wr = W + (size_t)d * NC;   // uniform per block -> scalar loads
  float acc = 0.f;
#pragma unroll 8
  for (int c = 0; c < NC; ++c) acc = fmaf(wr[c], xb[(size_t)c * NTOK], acc);
  out[((size_t)b * D + d) * NTOK + n] = acc;
}

// One block per (n, b): scores[b,n,m] = sum_d q[b,d,n]*k[b,d,m]; softmax over m; write row.
__global__ __launch_bounds__(256) void attn_softmax_kernel(
    const float* __restrict__ q, const float* __restrict__ k,
    float* __restrict__ attn) {
  int n = blockIdx.x, b = blockIdx.y, t = threadIdx.x;
  __shared__ float qv[NHID];
  __shared__ float wred[4];
  if (t < NHID) qv[t] = q[((size_t)b * NHID + t) * NTOK + n];
  __syncthreads();
  const float* kb = k + (size_t)b * NHID * NTOK;
  float s0 = 0.f, s1 = 0.f, s2 = 0.f, s3 = 0.f;
#pragma unroll
  for (int d = 0; d < NHID; ++d) {
    float qd = qv[d];
    const float* kr = kb + (size_t)d * NTOK;
    s0 = fmaf(qd, kr[t], s0);
    s1 = fmaf(qd, kr[t + 256], s1);
    s2 = fmaf(qd, kr[t + 512], s2);
    s3 = fmaf(qd, kr[t + 768], s3);
  }
  // block max
  float mx = fmaxf(fmaxf(s0, s1), fmaxf(s2, s3));
  mx = wave_max(mx);
  int wave = t >> 6;
  if ((t & 63) == 0) wred[wave] = mx;
  __syncthreads();
  mx = fmaxf(fmaxf(wred[0], wred[1]), fmaxf(wred[2], wred[3]));
  __syncthreads();
  s0 = expf(s0 - mx); s1 = expf(s1 - mx); s2 = expf(s2 - mx); s3 = expf(s3 - mx);
  float sm = wave_sum(s0 + s1 + s2 + s3);
  if ((t & 63) == 0) wred[wave] = sm;
  __syncthreads();
  float inv = 1.f / (wred[0] + wred[1] + wred[2] + wred[3]);
  float* arow = attn + ((size_t)b * NTOK + n) * NTOK;
  arow[t]       = s0 * inv;
  arow[t + 256] = s1 * inv;
  arow[t + 512] = s2 * inv;
  arow[t + 768] = s3 * inv;
}

// One block per (n, b): out[b,c,n] = scale * (resid[b,c,n] + sum_m v[b,c,m]*attn[b,n,m])
__global__ __launch_bounds__(256) void aggregate_kernel(
    const float* __restrict__ v, const float* __restrict__ attn,
    const float* __restrict__ resid, float* __restrict__ out, float scale) {
  int n = blockIdx.x, b = blockIdx.y, t = threadIdx.x;
  __shared__ __align__(16) float arow[NTOK];
  __shared__ float partial[4][64];
  const float* ar = attn + ((size_t)b * NTOK + n) * NTOK;
#pragma unroll
  for (int j = 0; j < 4; ++j) arow[t + j * 256] = ar[t + j * 256];
  __syncthreads();
  int wave = t >> 6, lane = t & 63;
  // wave w covers m-chunk [w*256, w*256+256), lane c = lane's channel
  const float* vrow = v + ((size_t)b * NC + lane) * NTOK + wave * 256;
  const float* al = arow + wave * 256;
  float acc = 0.f;
#pragma unroll 8
  for (int m = 0; m < 256; m += 4) {
    float4 vv = *(const float4*)(vrow + m);
    float4 av = *(const float4*)(al + m);
    acc = fmaf(vv.x, av.x, fmaf(vv.y, av.y, fmaf(vv.z, av.z, fmaf(vv.w, av.w, acc))));
  }
  partial[wave][lane] = acc;
  __syncthreads();
  if (t < 64) {
    float dot = partial[0][t] + partial[1][t] + partial[2][t] + partial[3][t];
    size_t idx = ((size_t)b * NC + t) * NTOK + n;
    out[idx] = scale * (resid[idx] + dot);
  }
}

// 5x5 conv, pad 2, in = concat(X[64], h[64]), out channel oc. One block per (oc, b).
// LDS tile 36 rows x 40-pitch (pad to break bank conflicts). 4 consecutive px/thread.
#define TP 40
__global__ __launch_bounds__(256) void conv_kernel(
    const float* __restrict__ X, const float* __restrict__ h,
    const float* __restrict__ W, const float* __restrict__ bias,
    float* __restrict__ gates) {
  int oc = blockIdx.x, b = blockIdx.y, t = threadIdx.x;
  __shared__ __align__(16) float tile[36 * TP];
  float acc0 = 0.f, acc1 = 0.f, acc2 = 0.f, acc3 = 0.f;
  int p0 = t * 4;
  int y = p0 >> 5, x0 = p0 & 31;
  for (int ic = 0; ic < 2 * NC; ++ic) {
    const float* src = (ic < NC) ? X + ((size_t)b * NC + ic) * NTOK
                                 : h + ((size_t)b * NC + (ic - NC)) * NTOK;
    __syncthreads();
    for (int i = t; i < 36 * 36; i += 256) {
      int ty = i / 36, tx = i - ty * 36;
      int sy = ty - 2, sx = tx - 2;
      float vv = 0.f;
      if (sy >= 0 && sy < 32 && sx >= 0 && sx < 32) vv = src[sy * 32 + sx];
      tile[ty * TP + tx] = vv;
    }
    __syncthreads();
    const float* w = W + ((size_t)oc * (2 * NC) + ic) * 25;  // uniform -> scalar loads
    float wr[25];
#pragma unroll
    for (int u = 0; u < 25; ++u) wr[u] = w[u];
    const float* trow = tile + y * TP + x0;
#pragma unroll
    for (int ky = 0; ky < 5; ++ky) {
      float r[8];
#pragma unroll
      for (int u = 0; u < 8; ++u) r[u] = trow[ky * TP + u];
#pragma unroll
      for (int kx = 0; kx < 5; ++kx) {
        float wv = wr[ky * 5 + kx];
        acc0 = fmaf(wv, r[kx + 0], acc0);
        acc1 = fmaf(wv, r[kx + 1], acc1);
        acc2 = fmaf(wv, r[kx + 2], acc2);
        acc3 = fmaf(wv, r[kx + 3], acc3);
      }
    }
  }
  float bv = bias[oc];
  float4 res = make_float4(acc0 + bv, acc1 + bv, acc2 + bv, acc3 + bv);
  *(float4*)(gates + ((size_t)b * 256 + oc) * NTOK + p0) = res;
}

// gates:[B,256,1024] -> c_new, h_new
__global__ __launch_bounds__(256) void lstm_kernel(
    const float* __restrict__ gates, const float* __restrict__ c_in,
    float* __restrict__ c_out, float* __restrict__ h_out) {
  size_t idx = (size_t)blockIdx.x * 256 + threadIdx.x;  // over B*64*1024
  size_t b = idx >> 16;
  size_t r = idx & 65535;
  const float* gb = gates + b * (size_t)(256 * NTOK);
  float iv = gb[r];
  float fv = gb[65536 + r];
  float ov = gb[131072 + r];
  float gv = gb[196608 + r];
  iv = 1.f / (1.f + expf(-iv));
  fv = 1.f / (1.f + expf(-fv));
  ov = 1.f / (1.f + expf(-ov));
  gv = tanhf(gv);
  float cn = fv * c_in[idx] + iv * gv;
  c_out[idx] = cn;
  h_out[idx] = ov * tanhf(cn);
}

extern "C" void kernel_launch(void* const* d_in, const int* in_sizes, int n_in,
                              void* d_out, int out_size, void* d_ws, size_t ws_size,
                              hipStream_t stream) {
  const float* x      = (const float*)d_in[0];
  const float* h      = (const float*)d_in[1];
  const float* c      = (const float*)d_in[2];
  const float* Wq_x   = (const float*)d_in[3];
  const float* Wk_x   = (const float*)d_in[4];
  const float* Wv_x   = (const float*)d_in[5];
  const float* Wq_h   = (const float*)d_in[6];
  const float* Wk_h   = (const float*)d_in[7];
  const float* Wv_h   = (const float*)d_in[8];
  const float* W_lstm = (const float*)d_in[9];
  const float* b_lstm = (const float*)d_in[10];

  float* out   = (float*)d_out;
  float* new_h = out;                 // [16,64,32,32]  = 1,048,576 f32
  float* new_c = out + 1048576;       // [16,64,32,32]  = 1,048,576 f32
  float* atten = out + 2097152;       // [16,1024,1024] = 16,777,216 f32

  // Workspace (12.6 MB): q,k,v and X (reused as h_mid).
  float* ws   = (float*)d_ws;
  float* q    = ws;                   //   524,288 f32
  float* kk   = ws + 524288;          //   524,288 f32
  float* v    = ws + 1048576;         // 1,048,576 f32
  float* X    = ws + 2097152;         // 1,048,576 f32 (attn1 out; later h_mid)
  float* h_mid = X;
  // attn1 scores AND conv gates both scratch-live in the atten output region
  // (dead before attn2 rewrites all of it).
  float* scores1 = atten;             // 16,777,216 f32
  float* gates   = atten;             //  4,194,304 f32 (after scores1 dead)

  dim3 blk(256);
  // ---- attention 1 on x ----
  proj_kernel<<<dim3(4, NHID, NB), blk, 0, stream>>>(Wq_x, x, q, NHID);
  proj_kernel<<<dim3(4, NHID, NB), blk, 0, stream>>>(Wk_x, x, kk, NHID);
  proj_kernel<<<dim3(4, NC,   NB), blk, 0, stream>>>(Wv_x, x, v, NC);
  attn_softmax_kernel<<<dim3(NTOK, NB), blk, 0, stream>>>(q, kk, scores1);
  aggregate_kernel<<<dim3(NTOK, NB), blk, 0, stream>>>(v, scores1, x, X, 1.0f);
  // ---- conv-lstm ----
  conv_kernel<<<dim3(256, NB), blk, 0, stream>>>(X, h, W_lstm, b_lstm, gates);
  lstm_kernel<<<4096, blk, 0, stream>>>(gates, c, new_c, h_mid);
  // ---- attention 2 on h_mid (atten is a real output; final new_h doubled) ----
  proj_kernel<<<dim3(4, NHID, NB), blk, 0, stream>>>(Wq_h, h_mid, q, NHID);
  proj_kernel<<<dim3(4, NHID, NB), blk, 0, stream>>>(Wk_h, h_mid, kk, NHID);
  proj_kernel<<<dim3(4, NC,   NB), blk, 0, stream>>>(Wv_h, h_mid, v, NC);
  attn_softmax_kernel<<<dim3(NTOK, NB), blk, 0, stream>>>(q, kk, atten);
  aggregate_kernel<<<dim3(NTOK, NB), blk, 0, stream>>>(v, atten, h_mid, new_h, 2.0f);
}

// Round 2
// 1177.063 us; speedup vs baseline: 1.8496x; 1.8496x over previous
//
#include <hip/hip_runtime.h>
#include <hip/hip_bf16.h>
#include <cstddef>
#include <cstdint>

// Problem constants: B=16, CIN=COUT=64, HID=32, H=W=32, K=5, PAD=2
#define NTOK 1024      // H*W
#define NB   16        // batch
#define NC   64        // channels (CIN == COUT)
#define NHID 32        // attention hidden

typedef __attribute__((ext_vector_type(8))) short short8;   // 8 bf16 = 4 VGPR (MFMA A/B frag)
typedef __attribute__((ext_vector_type(4))) float f32x4;    // MFMA acc frag

// round-to-nearest-even f32 -> bf16 (as raw ushort)
__device__ __forceinline__ ushort f2b(float f) {
  uint32_t u = __builtin_bit_cast(uint32_t, f);
  return (ushort)((u + 0x7FFFu + ((u >> 16) & 1u)) >> 16);
}

__device__ __forceinline__ float wave_max(float v) {
#pragma unroll
  for (int off = 32; off > 0; off >>= 1) v = fmaxf(v, __shfl_xor(v, off, 64));
  return v;
}
__device__ __forceinline__ float wave_sum(float v) {
#pragma unroll
  for (int off = 32; off > 0; off >>= 1) v += __shfl_xor(v, off, 64);
  return v;
}

// out[b,d,n] = sum_c W[d,c] * x[b,c,n];  x:[B,64,1024], W:[D,64]
__global__ __launch_bounds__(256) void proj_kernel(
    const float* __restrict__ W, const float* __restrict__ x,
    float* __restrict__ out, int D) {
  int n = blockIdx.x * 256 + threadIdx.x;
  int d = blockIdx.y, b = blockIdx.z;
  const float* xb = x + (size_t)b * NC * NTOK + n;
  const float* wr = W + (size_t)d * NC;   // uniform per block -> scalar loads
  float acc = 0.f;
#pragma unroll 8
  for (int c = 0; c < NC; ++c) acc = fmaf(wr[c], xb[(size_t)c * NTOK], acc);
  out[((size_t)b * D + d) * NTOK + n] = acc;
}

// One block per (n, b): scores[b,n,m] = sum_d q[b,d,n]*k[b,d,m]; softmax over m.
__global__ __launch_bounds__(256) void attn_softmax_kernel(
    const float* __restrict__ q, const float* __restrict__ k,
    float* __restrict__ attn) {
  int n = blockIdx.x, b = blockIdx.y, t = threadIdx.x;
  __shared__ float qv[NHID];
  __shared__ float wred[4];
  if (t < NHID) qv[t] = q[((size_t)b * NHID + t) * NTOK + n];
  __syncthreads();
  const float* kb = k + (size_t)b * NHID * NTOK;
  float s0 = 0.f, s1 = 0.f, s2 = 0.f, s3 = 0.f;
#pragma unroll
  for (int d = 0; d < NHID; ++d) {
    float qd = qv[d];
    const float* kr = kb + (size_t)d * NTOK;
    s0 = fmaf(qd, kr[t], s0);
    s1 = fmaf(qd, kr[t + 256], s1);
    s2 = fmaf(qd, kr[t + 512], s2);
    s3 = fmaf(qd, kr[t + 768], s3);
  }
  float mx = fmaxf(fmaxf(s0, s1), fmaxf(s2, s3));
  mx = wave_max(mx);
  int wave = t >> 6;
  if ((t & 63) == 0) wred[wave] = mx;
  __syncthreads();
  mx = fmaxf(fmaxf(wred[0], wred[1]), fmaxf(wred[2], wred[3]));
  __syncthreads();
  s0 = expf(s0 - mx); s1 = expf(s1 - mx); s2 = expf(s2 - mx); s3 = expf(s3 - mx);
  float sm = wave_sum(s0 + s1 + s2 + s3);
  if ((t & 63) == 0) wred[wave] = sm;
  __syncthreads();
  float inv = 1.f / (wred[0] + wred[1] + wred[2] + wred[3]);
  float* arow = attn + ((size_t)b * NTOK + n) * NTOK;
  arow[t]       = s0 * inv;
  arow[t + 256] = s1 * inv;
  arow[t + 512] = s2 * inv;
  arow[t + 768] = s3 * inv;
}

// One block per (n, b): val = scale * (resid[b,c,n] + sum_m v[b,c,m]*attn[b,n,m])
// outb != nullptr -> write bf16 to outb, else f32 to outf.
__global__ __launch_bounds__(256) void aggregate_kernel(
    const float* __restrict__ v, const float* __restrict__ attn,
    const float* __restrict__ resid, float* __restrict__ outf,
    ushort* __restrict__ outb, float scale) {
  int n = blockIdx.x, b = blockIdx.y, t = threadIdx.x;
  __shared__ __align__(16) float arow[NTOK];
  __shared__ float partial[4][64];
  const float* ar = attn + ((size_t)b * NTOK + n) * NTOK;
#pragma unroll
  for (int j = 0; j < 4; ++j) arow[t + j * 256] = ar[t + j * 256];
  __syncthreads();
  int wave = t >> 6, lane = t & 63;
  const float* vrow = v + ((size_t)b * NC + lane) * NTOK + wave * 256;
  const float* al = arow + wave * 256;
  float acc = 0.f;
#pragma unroll 8
  for (int m = 0; m < 256; m += 4) {
    float4 vv = *(const float4*)(vrow + m);
    float4 av = *(const float4*)(al + m);
    acc = fmaf(vv.x, av.x, fmaf(vv.y, av.y, fmaf(vv.z, av.z, fmaf(vv.w, av.w, acc))));
  }
  partial[wave][lane] = acc;
  __syncthreads();
  if (t < 64) {
    float dot = partial[0][t] + partial[1][t] + partial[2][t] + partial[3][t];
    size_t idx = ((size_t)b * NC + t) * NTOK + n;
    float val = scale * (resid[idx] + dot);
    if (outb) outb[idx] = f2b(val);
    else      outf[idx] = val;
  }
}

// Weight pre-pass: W_lstm[oc][ic][5][5] f32 -> Wb[oc][kk=25][ic=128] bf16
__global__ __launch_bounds__(256) void wpre_kernel(
    const float* __restrict__ W, ushort* __restrict__ Wb) {
  int idx = blockIdx.x * 256 + threadIdx.x;   // 256*128 threads: (oc, ic)
  int oc = idx >> 7, ic = idx & 127;
  const float* src = W + (size_t)idx * 25;    // contiguous 25 taps, coalesced reads
#pragma unroll
  for (int kk = 0; kk < 25; ++kk)
    Wb[((size_t)oc * 25 + kk) * 128 + ic] = f2b(src[kk]);
}

// f32 -> bf16 bulk convert (h input for conv)
__global__ __launch_bounds__(256) void hpre_kernel(
    const float* __restrict__ h, ushort* __restrict__ hb) {
  int i = (blockIdx.x * 256 + threadIdx.x) * 4;
  float4 v = *(const float4*)(h + i);
  ushort4 o = {f2b(v.x), f2b(v.y), f2b(v.z), f2b(v.w)};
  *(ushort4*)(hb + i) = o;
}

// Implicit-GEMM conv via bf16 MFMA. One wg per (row-pair, b).
// Output tile: 256 oc x 64 px (2 rows). K = 25 taps x 128 ic = 3200.
// LDS: full input window [6 rows][36 x (zero-padded)][ic pad 136] bf16 = 58.75 KB.
// ic pitch 136: ds_read_b128 x-step = 272B = 17 quads -> quad-conflict-minimal.
#define ICP 136
__global__ __launch_bounds__(256) void conv_mfma_kernel(
    const ushort* __restrict__ Xb, const ushort* __restrict__ hb,
    const ushort* __restrict__ Wb, const float* __restrict__ bias,
    float* __restrict__ gates) {
  __shared__ ushort lds[6 * 36 * ICP];
  int t = threadIdx.x, wave = t >> 6, lane = t & 63;
  int lo = lane & 15, lg = lane >> 4;
  int rp = blockIdx.x, b = blockIdx.y;
  int y0 = rp * 2;
  // zero-fill LDS (covers x/row zero-padding)
  for (int i = t; i < 6 * 36 * ICP / 8; i += 256)
    ((uint4*)lds)[i] = make_uint4(0u, 0u, 0u, 0u);
  __syncthreads();
  // stage: thread (ic = t&127, xh = t>>7) copies 16 x-consecutive bf16 per row
  {
    int ic = t & 127, xh = t >> 7;
    const ushort* src = (ic < NC) ? (Xb + (size_t)(b * NC + ic) * NTOK)
                                  : (hb + (size_t)(b * NC + ic - NC) * NTOK);
    for (int r = 0; r < 6; ++r) {
      int gr = y0 - 2 + r;
      if (gr < 0 || gr >= 32) continue;
      ushort tmp[16];
      *(uint4*)(tmp)     = *(const uint4*)(src + gr * 32 + xh * 16);
      *(uint4*)(tmp + 8) = *(const uint4*)(src + gr * 32 + xh * 16 + 8);
      int base = (r * 36 + 2 + xh * 16) * ICP + ic;
#pragma unroll
      for (int j = 0; j < 16; ++j) lds[base + j * ICP] = tmp[j];
    }
  }
  __syncthreads();

  f32x4 acc[4][4];
#pragma unroll
  for (int i = 0; i < 4; ++i)
#pragma unroll
    for (int j = 0; j < 4; ++j) acc[i][j] = {0.f, 0.f, 0.f, 0.f};

  const ushort* wb = Wb + (size_t)(wave * 64) * 25 * 128;  // wave's 64-oc slab
  for (int kk = 0; kk < 25; ++kk) {
    int ky = kk / 5, kx = kk - ky * 5;
#pragma unroll
    for (int icc = 0; icc < 4; ++icc) {
      int ic0 = icc * 32 + 8 * lg;   // k = 8*(lane>>4)+j, contiguous along ic
      short8 a[4], bf[4];
#pragma unroll
      for (int g = 0; g < 4; ++g)    // A: row = lane&15 (oc), 16B global (L2-hot)
        a[g] = *(const short8*)(wb + ((size_t)(g * 16 + lo) * 25 + kk) * 128 + ic0);
#pragma unroll
      for (int g = 0; g < 4; ++g) {  // B: col = lane&15 (px), ds_read_b128
        int row = (g >> 1) + ky;                 // LDS row = py + ky
        int x   = (g & 1) * 16 + lo + kx;        // LDS x   = out_x + kx (pad absorbs -2)
        bf[g] = *(const short8*)(lds + (row * 36 + x) * ICP + ic0);
      }
#pragma unroll
      for (int i = 0; i < 4; ++i)
#pragma unroll
        for (int j = 0; j < 4; ++j)
          acc[i][j] = __builtin_amdgcn_mfma_f32_16x16x32_bf16(a[i], bf[j], acc[i][j], 0, 0, 0);
    }
  }
  // epilogue: C/D map col=lane&15, row=(lane>>4)*4+reg
#pragma unroll
  for (int i = 0; i < 4; ++i) {
#pragma unroll
    for (int j = 0; j < 4; ++j) {
#pragma unroll
      for (int r = 0; r < 4; ++r) {
        int oc = wave * 64 + i * 16 + lg * 4 + r;
        int p  = y0 * 32 + (j >> 1) * 32 + (j & 1) * 16 + lo;
        gates[(size_t)(b * 256 + oc) * NTOK + p] = acc[i][j][r] + bias[oc];
      }
    }
  }
}

// gates:[B,256,1024] -> c_new, h_new
__global__ __launch_bounds__(256) void lstm_kernel(
    const float* __restrict__ gates, const float* __restrict__ c_in,
    float* __restrict__ c_out, float* __restrict__ h_out) {
  size_t idx = (size_t)blockIdx.x * 256 + threadIdx.x;
  size_t b = idx >> 16;
  size_t r = idx & 65535;
  const float* gb = gates + b * (size_t)(256 * NTOK);
  float iv = gb[r];
  float fv = gb[65536 + r];
  float ov = gb[131072 + r];
  float gv = gb[196608 + r];
  iv = 1.f / (1.f + expf(-iv));
  fv = 1.f / (1.f + expf(-fv));
  ov = 1.f / (1.f + expf(-ov));
  gv = tanhf(gv);
  float cn = fv * c_in[idx] + iv * gv;
  c_out[idx] = cn;
  h_out[idx] = ov * tanhf(cn);
}

extern "C" void kernel_launch(void* const* d_in, const int* in_sizes, int n_in,
                              void* d_out, int out_size, void* d_ws, size_t ws_size,
                              hipStream_t stream) {
  const float* x      = (const float*)d_in[0];
  const float* h      = (const float*)d_in[1];
  const float* c      = (const float*)d_in[2];
  const float* Wq_x   = (const float*)d_in[3];
  const float* Wk_x   = (const float*)d_in[4];
  const float* Wv_x   = (const float*)d_in[5];
  const float* Wq_h   = (const float*)d_in[6];
  const float* Wk_h   = (const float*)d_in[7];
  const float* Wv_h   = (const float*)d_in[8];
  const float* W_lstm = (const float*)d_in[9];
  const float* b_lstm = (const float*)d_in[10];

  float* out   = (float*)d_out;
  float* new_h = out;                 // [16,64,32,32]
  float* new_c = out + 1048576;       // [16,64,32,32]
  float* atten = out + 2097152;       // [16,1024,1024]

  // ws (10.5 MB of proven-available 12.6 MB)
  float* ws = (float*)d_ws;
  float*  q    = ws;                          //   524,288 f32
  float*  kk   = ws + 524288;                 //   524,288 f32
  float*  v    = ws + 1048576;                // 1,048,576 f32
  ushort* Xbf  = (ushort*)(ws + 2097152);     // 1,048,576 bf16 (attn1 out -> conv in)

  // scratch aliased into the atten output region, live only between
  // aggregate1 (scores1 death) and softmax2 (full rewrite):
  float*  scores1 = atten;                    // [b][n][m] f32 (attn1 scores)
  float*  gates   = atten;                    // 4,194,304 f32 (conv out)
  ushort* Wb      = (ushort*)(atten + 8388608);  //   819,200 bf16 weights
  ushort* hb      = (ushort*)(atten + 9437184);  // 1,048,576 bf16 h
  float*  h_mid   = new_h;                    // lstm h lives in new_h slot until aggregate2

  dim3 blk(256);
  // ---- attention 1 on x ----
  proj_kernel<<<dim3(4, NHID, NB), blk, 0, stream>>>(Wq_x, x, q, NHID);
  proj_kernel<<<dim3(4, NHID, NB), blk, 0, stream>>>(Wk_x, x, kk, NHID);
  proj_kernel<<<dim3(4, NC,   NB), blk, 0, stream>>>(Wv_x, x, v, NC);
  attn_softmax_kernel<<<dim3(NTOK, NB), blk, 0, stream>>>(q, kk, scores1);
  aggregate_kernel<<<dim3(NTOK, NB), blk, 0, stream>>>(v, scores1, x, nullptr, Xbf, 1.0f);
  // ---- conv-lstm (bf16 MFMA implicit GEMM) ----
  wpre_kernel<<<128, blk, 0, stream>>>(W_lstm, Wb);      // after scores1 dead
  hpre_kernel<<<1024, blk, 0, stream>>>(h, hb);
  conv_mfma_kernel<<<dim3(16, NB), blk, 0, stream>>>(Xbf, hb, Wb, b_lstm, gates);
  lstm_kernel<<<4096, blk, 0, stream>>>(gates, c, new_c, h_mid);
  // ---- attention 2 on h_mid ----
  proj_kernel<<<dim3(4, NHID, NB), blk, 0, stream>>>(Wq_h, h_mid, q, NHID);
  proj_kernel<<<dim3(4, NHID, NB), blk, 0, stream>>>(Wk_h, h_mid, kk, NHID);
  proj_kernel<<<dim3(4, NC,   NB), blk, 0, stream>>>(Wv_h, h_mid, v, NC);
  attn_softmax_kernel<<<dim3(NTOK, NB), blk, 0, stream>>>(q, kk, atten);
  aggregate_kernel<<<dim3(NTOK, NB), blk, 0, stream>>>(v, atten, h_mid, new_h, nullptr, 2.0f);
}

// Round 3
// 356.171 us; speedup vs baseline: 6.1125x; 3.3048x over previous
//
#include <hip/hip_runtime.h>
#include <hip/hip_bf16.h>
#include <cstddef>
#include <cstdint>

// Problem constants: B=16, CIN=COUT=64, HID=32, H=W=32, K=5, PAD=2
#define NTOK 1024      // H*W
#define NB   16        // batch
#define NC   64        // channels (CIN == COUT)
#define NHID 32        // attention hidden

typedef __attribute__((ext_vector_type(8))) short short8;   // 8 bf16 = 4 VGPR (MFMA A/B frag)
typedef __attribute__((ext_vector_type(4))) float f32x4;    // MFMA acc frag

// round-to-nearest-even f32 -> bf16 (as raw ushort)
__device__ __forceinline__ ushort f2b(float f) {
  uint32_t u = __builtin_bit_cast(uint32_t, f);
  return (ushort)((u + 0x7FFFu + ((u >> 16) & 1u)) >> 16);
}

__device__ __forceinline__ float wave_max(float v) {
#pragma unroll
  for (int off = 32; off > 0; off >>= 1) v = fmaxf(v, __shfl_xor(v, off, 64));
  return v;
}
__device__ __forceinline__ float wave_sum(float v) {
#pragma unroll
  for (int off = 32; off > 0; off >>= 1) v += __shfl_xor(v, off, 64);
  return v;
}

// out[b,d,n] = sum_c W[d,c] * x[b,c,n];  x:[B,64,1024], W:[D,64]
// Writes f32 (outf) or bf16 (outb).
__global__ __launch_bounds__(256) void proj_kernel(
    const float* __restrict__ W, const float* __restrict__ x,
    float* __restrict__ outf, ushort* __restrict__ outb, int D) {
  int n = blockIdx.x * 256 + threadIdx.x;
  int d = blockIdx.y, b = blockIdx.z;
  const float* xb = x + (size_t)b * NC * NTOK + n;
  const float* wr = W + (size_t)d * NC;   // uniform per block -> scalar loads
  float acc = 0.f;
#pragma unroll 8
  for (int c = 0; c < NC; ++c) acc = fmaf(wr[c], xb[(size_t)c * NTOK], acc);
  size_t idx = ((size_t)b * D + d) * NTOK + n;
  if (outb) outb[idx] = f2b(acc);
  else      outf[idx] = acc;
}

// One block per (n, b): scores[b,n,m] = sum_d q[b,d,n]*k[b,d,m]; softmax over m.
// Writes f32 row (attnf) and/or bf16 row (attnb).
__global__ __launch_bounds__(256) void attn_softmax_kernel(
    const float* __restrict__ q, const float* __restrict__ k,
    float* __restrict__ attnf, ushort* __restrict__ attnb) {
  int n = blockIdx.x, b = blockIdx.y, t = threadIdx.x;
  __shared__ float qv[NHID];
  __shared__ float wred[4];
  if (t < NHID) qv[t] = q[((size_t)b * NHID + t) * NTOK + n];
  __syncthreads();
  const float* kb = k + (size_t)b * NHID * NTOK;
  float s0 = 0.f, s1 = 0.f, s2 = 0.f, s3 = 0.f;
#pragma unroll
  for (int d = 0; d < NHID; ++d) {
    float qd = qv[d];
    const float* kr = kb + (size_t)d * NTOK;
    s0 = fmaf(qd, kr[t], s0);
    s1 = fmaf(qd, kr[t + 256], s1);
    s2 = fmaf(qd, kr[t + 512], s2);
    s3 = fmaf(qd, kr[t + 768], s3);
  }
  float mx = fmaxf(fmaxf(s0, s1), fmaxf(s2, s3));
  mx = wave_max(mx);
  int wave = t >> 6;
  if ((t & 63) == 0) wred[wave] = mx;
  __syncthreads();
  mx = fmaxf(fmaxf(wred[0], wred[1]), fmaxf(wred[2], wred[3]));
  __syncthreads();
  s0 = expf(s0 - mx); s1 = expf(s1 - mx); s2 = expf(s2 - mx); s3 = expf(s3 - mx);
  float sm = wave_sum(s0 + s1 + s2 + s3);
  if ((t & 63) == 0) wred[wave] = sm;
  __syncthreads();
  float inv = 1.f / (wred[0] + wred[1] + wred[2] + wred[3]);
  if (attnf) {
    float* arow = attnf + ((size_t)b * NTOK + n) * NTOK;
    arow[t]       = s0 * inv;
    arow[t + 256] = s1 * inv;
    arow[t + 512] = s2 * inv;
    arow[t + 768] = s3 * inv;
  }
  if (attnb) {
    ushort* brow = attnb + ((size_t)b * NTOK + n) * NTOK;
    brow[t]       = f2b(s0 * inv);
    brow[t + 256] = f2b(s1 * inv);
    brow[t + 512] = f2b(s2 * inv);
    brow[t + 768] = f2b(s3 * inv);
  }
}

// MFMA aggregate: out[b,c,n] = scale*(resid[b,c,n] + sum_m vb[b,c,m]*attn[b,n,m])
// One wave per (64-n tile, b). 64c x 64n output tile, K=m=1024.
// B operand from bf16 (abf) if BF16B, else from f32 (af32) with in-reg convert.
template <bool BF16B>
__global__ __launch_bounds__(64) void aggregate_mfma_kernel(
    const ushort* __restrict__ vb, const ushort* __restrict__ abf,
    const float* __restrict__ af32, const float* __restrict__ resid,
    float* __restrict__ outf, ushort* __restrict__ outb, float scale) {
  int lane = threadIdx.x & 63;
  int lo = lane & 15, lg = lane >> 4;
  int n0 = blockIdx.x * 64, b = blockIdx.y;
  const ushort* V = vb + (size_t)b * NC * NTOK;            // [64][1024] bf16
  const ushort* Ab = BF16B ? abf + ((size_t)b * NTOK + n0) * NTOK : nullptr;
  const float*  Af = BF16B ? nullptr : af32 + ((size_t)b * NTOK + n0) * NTOK;

  f32x4 acc[4][4];
#pragma unroll
  for (int i = 0; i < 4; ++i)
#pragma unroll
    for (int j = 0; j < 4; ++j) acc[i][j] = {0.f, 0.f, 0.f, 0.f};

  for (int m0 = 0; m0 < NTOK; m0 += 32) {
    int mk = m0 + 8 * lg;                                   // k = 8*(lane>>4)+j
    short8 a[4], bf[4];
#pragma unroll
    for (int g = 0; g < 4; ++g)                             // A row = c = g*16+lo
      a[g] = *(const short8*)(V + (size_t)(g * 16 + lo) * NTOK + mk);
    if constexpr (BF16B) {
#pragma unroll
      for (int g = 0; g < 4; ++g)                           // B col = n = g*16+lo
        bf[g] = *(const short8*)(Ab + (size_t)(g * 16 + lo) * NTOK + mk);
    } else {
#pragma unroll
      for (int g = 0; g < 4; ++g) {
        const float* p = Af + (size_t)(g * 16 + lo) * NTOK + mk;
        float4 f0 = *(const float4*)(p);
        float4 f1 = *(const float4*)(p + 4);
        short8 r;
        r[0] = (short)f2b(f0.x); r[1] = (short)f2b(f0.y);
        r[2] = (short)f2b(f0.z); r[3] = (short)f2b(f0.w);
        r[4] = (short)f2b(f1.x); r[5] = (short)f2b(f1.y);
        r[6] = (short)f2b(f1.z); r[7] = (short)f2b(f1.w);
        bf[g] = r;
      }
    }
#pragma unroll
    for (int i = 0; i < 4; ++i)
#pragma unroll
      for (int j = 0; j < 4; ++j)
        acc[i][j] = __builtin_amdgcn_mfma_f32_16x16x32_bf16(a[i], bf[j], acc[i][j], 0, 0, 0);
  }
  // C/D: col(lane&15)=n, row=(lane>>4)*4+reg = c
#pragma unroll
  for (int i = 0; i < 4; ++i) {
#pragma unroll
    for (int j = 0; j < 4; ++j) {
#pragma unroll
      for (int r = 0; r < 4; ++r) {
        int cch = i * 16 + lg * 4 + r;
        int n = n0 + j * 16 + lo;
        size_t idx = ((size_t)b * NC + cch) * NTOK + n;
        float val = scale * (resid[idx] + acc[i][j][r]);
        if (outb) outb[idx] = f2b(val);
        else      outf[idx] = val;
      }
    }
  }
}

// Weight pre-pass: W_lstm[oc][ic][5][5] f32 -> Wb[oc][kk=25][ic=128] bf16
__global__ __launch_bounds__(256) void wpre_kernel(
    const float* __restrict__ W, ushort* __restrict__ Wb) {
  int idx = blockIdx.x * 256 + threadIdx.x;   // 256*128 threads: (oc, ic)
  int oc = idx >> 7, ic = idx & 127;
  const float* src = W + (size_t)idx * 25;
#pragma unroll
  for (int kk = 0; kk < 25; ++kk)
    Wb[((size_t)oc * 25 + kk) * 128 + ic] = f2b(src[kk]);
}

// f32 -> bf16 bulk convert (h input for conv)
__global__ __launch_bounds__(256) void hpre_kernel(
    const float* __restrict__ h, ushort* __restrict__ hb) {
  int i = (blockIdx.x * 256 + threadIdx.x) * 4;
  float4 v = *(const float4*)(h + i);
  ushort4 o = {f2b(v.x), f2b(v.y), f2b(v.z), f2b(v.w)};
  *(ushort4*)(hb + i) = o;
}

// Implicit-GEMM conv via bf16 MFMA. One wg per (row-pair, b).
#define ICP 136
__global__ __launch_bounds__(256) void conv_mfma_kernel(
    const ushort* __restrict__ Xb, const ushort* __restrict__ hb,
    const ushort* __restrict__ Wb, const float* __restrict__ bias,
    float* __restrict__ gates) {
  __shared__ ushort lds[6 * 36 * ICP];
  int t = threadIdx.x, wave = t >> 6, lane = t & 63;
  int lo = lane & 15, lg = lane >> 4;
  int rp = blockIdx.x, b = blockIdx.y;
  int y0 = rp * 2;
  for (int i = t; i < 6 * 36 * ICP / 8; i += 256)
    ((uint4*)lds)[i] = make_uint4(0u, 0u, 0u, 0u);
  __syncthreads();
  {
    int ic = t & 127, xh = t >> 7;
    const ushort* src = (ic < NC) ? (Xb + (size_t)(b * NC + ic) * NTOK)
                                  : (hb + (size_t)(b * NC + ic - NC) * NTOK);
    for (int r = 0; r < 6; ++r) {
      int gr = y0 - 2 + r;
      if (gr < 0 || gr >= 32) continue;
      ushort tmp[16];
      *(uint4*)(tmp)     = *(const uint4*)(src + gr * 32 + xh * 16);
      *(uint4*)(tmp + 8) = *(const uint4*)(src + gr * 32 + xh * 16 + 8);
      int base = (r * 36 + 2 + xh * 16) * ICP + ic;
#pragma unroll
      for (int j = 0; j < 16; ++j) lds[base + j * ICP] = tmp[j];
    }
  }
  __syncthreads();

  f32x4 acc[4][4];
#pragma unroll
  for (int i = 0; i < 4; ++i)
#pragma unroll
    for (int j = 0; j < 4; ++j) acc[i][j] = {0.f, 0.f, 0.f, 0.f};

  const ushort* wb = Wb + (size_t)(wave * 64) * 25 * 128;
  for (int kk = 0; kk < 25; ++kk) {
    int ky = kk / 5, kx = kk - ky * 5;
#pragma unroll
    for (int icc = 0; icc < 4; ++icc) {
      int ic0 = icc * 32 + 8 * lg;
      short8 a[4], bf[4];
#pragma unroll
      for (int g = 0; g < 4; ++g)
        a[g] = *(const short8*)(wb + ((size_t)(g * 16 + lo) * 25 + kk) * 128 + ic0);
#pragma unroll
      for (int g = 0; g < 4; ++g) {
        int row = (g >> 1) + ky;
        int x   = (g & 1) * 16 + lo + kx;
        bf[g] = *(const short8*)(lds + (row * 36 + x) * ICP + ic0);
      }
#pragma unroll
      for (int i = 0; i < 4; ++i)
#pragma unroll
        for (int j = 0; j < 4; ++j)
          acc[i][j] = __builtin_amdgcn_mfma_f32_16x16x32_bf16(a[i], bf[j], acc[i][j], 0, 0, 0);
    }
  }
#pragma unroll
  for (int i = 0; i < 4; ++i) {
#pragma unroll
    for (int j = 0; j < 4; ++j) {
#pragma unroll
      for (int r = 0; r < 4; ++r) {
        int oc = wave * 64 + i * 16 + lg * 4 + r;
        int p  = y0 * 32 + (j >> 1) * 32 + (j & 1) * 16 + lo;
        gates[(size_t)(b * 256 + oc) * NTOK + p] = acc[i][j][r] + bias[oc];
      }
    }
  }
}

// gates:[B,256,1024] -> c_new, h_new
__global__ __launch_bounds__(256) void lstm_kernel(
    const float* __restrict__ gates, const float* __restrict__ c_in,
    float* __restrict__ c_out, float* __restrict__ h_out) {
  size_t idx = (size_t)blockIdx.x * 256 + threadIdx.x;
  size_t b = idx >> 16;
  size_t r = idx & 65535;
  const float* gb = gates + b * (size_t)(256 * NTOK);
  float iv = gb[r];
  float fv = gb[65536 + r];
  float ov = gb[131072 + r];
  float gv = gb[196608 + r];
  iv = 1.f / (1.f + expf(-iv));
  fv = 1.f / (1.f + expf(-fv));
  ov = 1.f / (1.f + expf(-ov));
  gv = tanhf(gv);
  float cn = fv * c_in[idx] + iv * gv;
  c_out[idx] = cn;
  h_out[idx] = ov * tanhf(cn);
}

extern "C" void kernel_launch(void* const* d_in, const int* in_sizes, int n_in,
                              void* d_out, int out_size, void* d_ws, size_t ws_size,
                              hipStream_t stream) {
  const float* x      = (const float*)d_in[0];
  const float* h      = (const float*)d_in[1];
  const float* c      = (const float*)d_in[2];
  const float* Wq_x   = (const float*)d_in[3];
  const float* Wk_x   = (const float*)d_in[4];
  const float* Wv_x   = (const float*)d_in[5];
  const float* Wq_h   = (const float*)d_in[6];
  const float* Wk_h   = (const float*)d_in[7];
  const float* Wv_h   = (const float*)d_in[8];
  const float* W_lstm = (const float*)d_in[9];
  const float* b_lstm = (const float*)d_in[10];

  float* out   = (float*)d_out;
  float* new_h = out;                 // [16,64,32,32]
  float* new_c = out + 1048576;       // [16,64,32,32]
  float* atten = out + 2097152;       // [16,1024,1024]

  // ws layout (8 MB of proven-available 12.6 MB)
  float* ws = (float*)d_ws;
  float*  q   = ws;                           //   524,288 f32
  float*  kk  = ws + 524288;                  //   524,288 f32
  ushort* vb  = (ushort*)(ws + 1048576);      // 1,048,576 bf16 (v in bf16)
  ushort* Xbf = (ushort*)(ws + 1572864);      // 1,048,576 bf16 (attn1 out -> conv in)

  // scratch aliased into the atten output region:
  ushort* ab1   = (ushort*)atten;                // attn1 bf16 scores [b][n][m], 32MB
  float*  gates = atten;                         // conv out (after ab1 dead), 16MB
  ushort* Wb    = (ushort*)(atten + 8388608);    // weights bf16 (byte off 33.5MB)
  ushort* hb    = (ushort*)(atten + 9437184);    // h bf16
  float*  h_mid = new_h;                         // lstm h lives in new_h slot

  dim3 blk(256);
  // ---- attention 1 on x ----
  proj_kernel<<<dim3(4, NHID, NB), blk, 0, stream>>>(Wq_x, x, q, nullptr, NHID);
  proj_kernel<<<dim3(4, NHID, NB), blk, 0, stream>>>(Wk_x, x, kk, nullptr, NHID);
  proj_kernel<<<dim3(4, NC,   NB), blk, 0, stream>>>(Wv_x, x, nullptr, vb, NC);
  attn_softmax_kernel<<<dim3(NTOK, NB), blk, 0, stream>>>(q, kk, nullptr, ab1);
  aggregate_mfma_kernel<true><<<dim3(16, NB), 64, 0, stream>>>(
      vb, ab1, nullptr, x, nullptr, Xbf, 1.0f);
  // ---- conv-lstm (bf16 MFMA implicit GEMM) ----
  wpre_kernel<<<128, blk, 0, stream>>>(W_lstm, Wb);
  hpre_kernel<<<1024, blk, 0, stream>>>(h, hb);
  conv_mfma_kernel<<<dim3(16, NB), blk, 0, stream>>>(Xbf, hb, Wb, b_lstm, gates);
  lstm_kernel<<<4096, blk, 0, stream>>>(gates, c, new_c, h_mid);
  // ---- attention 2 on h_mid (atten f32 is a real output) ----
  proj_kernel<<<dim3(4, NHID, NB), blk, 0, stream>>>(Wq_h, h_mid, q, nullptr, NHID);
  proj_kernel<<<dim3(4, NHID, NB), blk, 0, stream>>>(Wk_h, h_mid, kk, nullptr, NHID);
  proj_kernel<<<dim3(4, NC,   NB), blk, 0, stream>>>(Wv_h, h_mid, nullptr, vb, NC);
  attn_softmax_kernel<<<dim3(NTOK, NB), blk, 0, stream>>>(q, kk, atten, nullptr);
  aggregate_mfma_kernel<false><<<dim3(16, NB), 64, 0, stream>>>(
      vb, nullptr, atten, h_mid, new_h, nullptr, 2.0f);
}

// Round 4
// 240.903 us; speedup vs baseline: 9.0372x; 1.4785x over previous
//
#include <hip/hip_runtime.h>
#include <hip/hip_bf16.h>
#include <cstddef>
#include <cstdint>

// Problem constants: B=16, CIN=COUT=64, HID=32, H=W=32, K=5, PAD=2
#define NTOK 1024      // H*W
#define NB   16        // batch
#define NC   64        // channels (CIN == COUT)
#define NHID 32        // attention hidden

typedef __attribute__((ext_vector_type(8))) short short8;   // 8 bf16 = 4 VGPR (MFMA A/B frag)
typedef __attribute__((ext_vector_type(4))) float f32x4;    // MFMA acc frag

// round-to-nearest-even f32 -> bf16 (as raw ushort)
__device__ __forceinline__ ushort f2b(float f) {
  uint32_t u = __builtin_bit_cast(uint32_t, f);
  return (ushort)((u + 0x7FFFu + ((u >> 16) & 1u)) >> 16);
}

// ---- transpose + convert: src f32 [b][64c][1024n] -> dst bf16 [b][1024n][64c]
__global__ __launch_bounds__(256) void tpose_bf16_kernel(
    const float* __restrict__ src, ushort* __restrict__ dst) {
  __shared__ float tile[64][65];
  int t = threadIdx.x;
  int n0 = blockIdx.x * 64, b = blockIdx.y;
  const float* s = src + (size_t)b * NC * NTOK;
#pragma unroll
  for (int r = 0; r < 4; ++r) {
    int c = r * 16 + (t >> 4);
    int nl = (t & 15) * 4;
    float4 v = *(const float4*)(s + (size_t)c * NTOK + n0 + nl);
    tile[c][nl] = v.x; tile[c][nl + 1] = v.y; tile[c][nl + 2] = v.z; tile[c][nl + 3] = v.w;
  }
  __syncthreads();
  int tok = t >> 2, c0 = (t & 3) * 16;
  __attribute__((aligned(16))) ushort tmp[16];
#pragma unroll
  for (int i = 0; i < 16; ++i) tmp[i] = f2b(tile[c0 + i][tok]);
  ushort* d = dst + ((size_t)b * NTOK + n0 + tok) * NC + c0;
  *(uint4*)(d)     = *(const uint4*)(tmp);
  *(uint4*)(d + 8) = *(const uint4*)(tmp + 8);
}

// ---- Wq/Wk f32 [32][64] -> bf16 (same layout). 8 blocks x 256 = 2048 elems.
__global__ __launch_bounds__(256) void wqk_pre_kernel(
    const float* __restrict__ Wq, const float* __restrict__ Wk,
    ushort* __restrict__ wqb, ushort* __restrict__ wkb) {
  int i = blockIdx.x * 256 + threadIdx.x;
  wqb[i] = f2b(Wq[i]);
  wkb[i] = f2b(Wk[i]);
}

// ---- q,k projection via MFMA: qT/kT[b][n][32] = xT[b][n][64] x W[32][64]^T
// One wg (4 waves) per 64 tokens; wave handles 16 tokens, K=64 (2 k-steps).
__global__ __launch_bounds__(256) void qkproj_kernel(
    const ushort* __restrict__ xT, const ushort* __restrict__ wqb,
    const ushort* __restrict__ wkb, ushort* __restrict__ qT,
    ushort* __restrict__ kT) {
  __shared__ ushort sq[64][32], sk[64][32];
  int t = threadIdx.x, wave = t >> 6, lane = t & 63;
  int lo = lane & 15, lg = lane >> 4;
  int n0 = blockIdx.x * 64, b = blockIdx.y;
  int nw = n0 + wave * 16;
  const ushort* xrow = xT + ((size_t)b * NTOK + nw + lo) * NC + 8 * lg;
  short8 a0 = *(const short8*)(xrow);        // k = c in [0,32)
  short8 a1 = *(const short8*)(xrow + 32);   // k = c in [32,64)
  f32x4 aq[2], ak[2];
#pragma unroll
  for (int dg = 0; dg < 2; ++dg) {
    const ushort* wq = wqb + (size_t)(dg * 16 + lo) * NC + 8 * lg;
    const ushort* wk = wkb + (size_t)(dg * 16 + lo) * NC + 8 * lg;
    f32x4 z = {0.f, 0.f, 0.f, 0.f};
    aq[dg] = __builtin_amdgcn_mfma_f32_16x16x32_bf16(a0, *(const short8*)(wq), z, 0, 0, 0);
    aq[dg] = __builtin_amdgcn_mfma_f32_16x16x32_bf16(a1, *(const short8*)(wq + 32), aq[dg], 0, 0, 0);
    ak[dg] = __builtin_amdgcn_mfma_f32_16x16x32_bf16(a0, *(const short8*)(wk), z, 0, 0, 0);
    ak[dg] = __builtin_amdgcn_mfma_f32_16x16x32_bf16(a1, *(const short8*)(wk + 32), ak[dg], 0, 0, 0);
  }
#pragma unroll
  for (int dg = 0; dg < 2; ++dg)
#pragma unroll
    for (int r = 0; r < 4; ++r) {
      sq[wave * 16 + 4 * lg + r][dg * 16 + lo] = f2b(aq[dg][r]);
      sk[wave * 16 + 4 * lg + r][dg * 16 + lo] = f2b(ak[dg][r]);
    }
  __syncthreads();
  int tok = t >> 2, d0 = (t & 3) * 8;
  size_t base = ((size_t)b * NTOK + n0 + tok) * NHID + d0;
  *(short8*)(qT + base) = *(const short8*)(&sq[tok][d0]);
  *(short8*)(kT + base) = *(const short8*)(&sk[tok][d0]);
}

// ---- scores + softmax, MFMA. One wg (4 waves) per 16 n-rows; wave w owns
// m-chunk [w*256, w*256+256). S[n,m] = sum_d qT[n,d] kT[m,d]  (K=32, 1 step).
template <bool F32OUT>
__global__ __launch_bounds__(256) void scores_softmax_kernel(
    const ushort* __restrict__ qT, const ushort* __restrict__ kT,
    float* __restrict__ attnf, ushort* __restrict__ attnb) {
  __shared__ float wmax[4][16], wsum[4][16];
  int t = threadIdx.x, wave = t >> 6, lane = t & 63;
  int lo = lane & 15, lg = lane >> 4;
  int n0 = blockIdx.x * 16, b = blockIdx.y;
  int m0 = wave * 256;
  short8 a = *(const short8*)(qT + ((size_t)b * NTOK + n0 + lo) * NHID + 8 * lg);
  f32x4 acc[16];
#pragma unroll
  for (int j = 0; j < 16; ++j) {
    short8 bf = *(const short8*)(kT + ((size_t)b * NTOK + m0 + j * 16 + lo) * NHID + 8 * lg);
    f32x4 z = {0.f, 0.f, 0.f, 0.f};
    acc[j] = __builtin_amdgcn_mfma_f32_16x16x32_bf16(a, bf, z, 0, 0, 0);
  }
  // per-row (n = 4*lg + r) max over this wave's 256 m
  float pm[4];
#pragma unroll
  for (int r = 0; r < 4; ++r) {
    float m = acc[0][r];
#pragma unroll
    for (int j = 1; j < 16; ++j) m = fmaxf(m, acc[j][r]);
#pragma unroll
    for (int off = 1; off < 16; off <<= 1) m = fmaxf(m, __shfl_xor(m, off, 64));
    pm[r] = m;
  }
  if (lo == 0)
#pragma unroll
    for (int r = 0; r < 4; ++r) wmax[wave][4 * lg + r] = pm[r];
  __syncthreads();
  float mr[4];
#pragma unroll
  for (int r = 0; r < 4; ++r)
    mr[r] = fmaxf(fmaxf(wmax[0][4 * lg + r], wmax[1][4 * lg + r]),
                  fmaxf(wmax[2][4 * lg + r], wmax[3][4 * lg + r]));
  float ps[4] = {0.f, 0.f, 0.f, 0.f};
#pragma unroll
  for (int j = 0; j < 16; ++j)
#pragma unroll
    for (int r = 0; r < 4; ++r) {
      float e = __expf(acc[j][r] - mr[r]);
      acc[j][r] = e;
      ps[r] += e;
    }
#pragma unroll
  for (int r = 0; r < 4; ++r)
#pragma unroll
    for (int off = 1; off < 16; off <<= 1) ps[r] += __shfl_xor(ps[r], off, 64);
  if (lo == 0)
#pragma unroll
    for (int r = 0; r < 4; ++r) wsum[wave][4 * lg + r] = ps[r];
  __syncthreads();
  float inv[4];
#pragma unroll
  for (int r = 0; r < 4; ++r)
    inv[r] = 1.f / (wsum[0][4 * lg + r] + wsum[1][4 * lg + r] +
                    wsum[2][4 * lg + r] + wsum[3][4 * lg + r]);
#pragma unroll
  for (int j = 0; j < 16; ++j)
#pragma unroll
    for (int r = 0; r < 4; ++r) {
      size_t idx = ((size_t)b * NTOK + n0 + 4 * lg + r) * NTOK + m0 + j * 16 + lo;
      float val = acc[j][r] * inv[r];
      if constexpr (F32OUT) attnf[idx] = val;
      else                  attnb[idx] = f2b(val);
    }
}

// ---- v projection (scalar; writes bf16 [b][c][m] token-minor for aggregate A-op)
__global__ __launch_bounds__(256) void proj_kernel(
    const float* __restrict__ W, const float* __restrict__ x,
    ushort* __restrict__ outb, int D) {
  int n = blockIdx.x * 256 + threadIdx.x;
  int d = blockIdx.y, b = blockIdx.z;
  const float* xb = x + (size_t)b * NC * NTOK + n;
  const float* wr = W + (size_t)d * NC;
  float acc = 0.f;
#pragma unroll 8
  for (int c = 0; c < NC; ++c) acc = fmaf(wr[c], xb[(size_t)c * NTOK], acc);
  outb[((size_t)b * D + d) * NTOK + n] = f2b(acc);
}

// ---- MFMA aggregate: out[b,c,n] = scale*(resid + sum_m vb[c,m]*attn[n,m])
template <bool BF16B>
__global__ __launch_bounds__(64) void aggregate_mfma_kernel(
    const ushort* __restrict__ vb, const ushort* __restrict__ abf,
    const float* __restrict__ af32, const float* __restrict__ resid,
    float* __restrict__ outf, ushort* __restrict__ outb, float scale) {
  int lane = threadIdx.x & 63;
  int lo = lane & 15, lg = lane >> 4;
  int n0 = blockIdx.x * 64, b = blockIdx.y;
  const ushort* V = vb + (size_t)b * NC * NTOK;
  const ushort* Ab = BF16B ? abf + ((size_t)b * NTOK + n0) * NTOK : nullptr;
  const float*  Af = BF16B ? nullptr : af32 + ((size_t)b * NTOK + n0) * NTOK;

  f32x4 acc[4][4];
#pragma unroll
  for (int i = 0; i < 4; ++i)
#pragma unroll
    for (int j = 0; j < 4; ++j) acc[i][j] = {0.f, 0.f, 0.f, 0.f};

  for (int m0 = 0; m0 < NTOK; m0 += 32) {
    int mk = m0 + 8 * lg;
    short8 a[4], bf[4];
#pragma unroll
    for (int g = 0; g < 4; ++g)
      a[g] = *(const short8*)(V + (size_t)(g * 16 + lo) * NTOK + mk);
    if constexpr (BF16B) {
#pragma unroll
      for (int g = 0; g < 4; ++g)
        bf[g] = *(const short8*)(Ab + (size_t)(g * 16 + lo) * NTOK + mk);
    } else {
#pragma unroll
      for (int g = 0; g < 4; ++g) {
        const float* p = Af + (size_t)(g * 16 + lo) * NTOK + mk;
        float4 f0 = *(const float4*)(p);
        float4 f1 = *(const float4*)(p + 4);
        short8 r;
        r[0] = (short)f2b(f0.x); r[1] = (short)f2b(f0.y);
        r[2] = (short)f2b(f0.z); r[3] = (short)f2b(f0.w);
        r[4] = (short)f2b(f1.x); r[5] = (short)f2b(f1.y);
        r[6] = (short)f2b(f1.z); r[7] = (short)f2b(f1.w);
        bf[g] = r;
      }
    }
#pragma unroll
    for (int i = 0; i < 4; ++i)
#pragma unroll
      for (int j = 0; j < 4; ++j)
        acc[i][j] = __builtin_amdgcn_mfma_f32_16x16x32_bf16(a[i], bf[j], acc[i][j], 0, 0, 0);
  }
#pragma unroll
  for (int i = 0; i < 4; ++i)
#pragma unroll
    for (int j = 0; j < 4; ++j)
#pragma unroll
      for (int r = 0; r < 4; ++r) {
        int cch = i * 16 + lg * 4 + r;
        int n = n0 + j * 16 + lo;
        size_t idx = ((size_t)b * NC + cch) * NTOK + n;
        float val = scale * (resid[idx] + acc[i][j][r]);
        if (outb) outb[idx] = f2b(val);
        else      outf[idx] = val;
      }
}

// ---- conv weight pre-pass: W_lstm[oc][ic][5][5] f32 -> Wb[oc][25][128] bf16
__global__ __launch_bounds__(256) void wpre_kernel(
    const float* __restrict__ W, ushort* __restrict__ Wb) {
  int idx = blockIdx.x * 256 + threadIdx.x;
  int oc = idx >> 7, ic = idx & 127;
  const float* src = W + (size_t)idx * 25;
#pragma unroll
  for (int kk = 0; kk < 25; ++kk)
    Wb[((size_t)oc * 25 + kk) * 128 + ic] = f2b(src[kk]);
}

// ---- h f32 -> bf16 (conv input, token-minor)
__global__ __launch_bounds__(256) void hpre_kernel(
    const float* __restrict__ h, ushort* __restrict__ hb) {
  int i = (blockIdx.x * 256 + threadIdx.x) * 4;
  float4 v = *(const float4*)(h + i);
  ushort4 o = {f2b(v.x), f2b(v.y), f2b(v.z), f2b(v.w)};
  *(ushort4*)(hb + i) = o;
}

// ---- implicit-GEMM conv via bf16 MFMA
#define ICP 136
__global__ __launch_bounds__(256) void conv_mfma_kernel(
    const ushort* __restrict__ Xb, const ushort* __restrict__ hb,
    const ushort* __restrict__ Wb, const float* __restrict__ bias,
    float* __restrict__ gates) {
  __shared__ ushort lds[6 * 36 * ICP];
  int t = threadIdx.x, wave = t >> 6, lane = t & 63;
  int lo = lane & 15, lg = lane >> 4;
  int rp = blockIdx.x, b = blockIdx.y;
  int y0 = rp * 2;
  for (int i = t; i < 6 * 36 * ICP / 8; i += 256)
    ((uint4*)lds)[i] = make_uint4(0u, 0u, 0u, 0u);
  __syncthreads();
  {
    int ic = t & 127, xh = t >> 7;
    const ushort* src = (ic < NC) ? (Xb + (size_t)(b * NC + ic) * NTOK)
                                  : (hb + (size_t)(b * NC + ic - NC) * NTOK);
    for (int r = 0; r < 6; ++r) {
      int gr = y0 - 2 + r;
      if (gr < 0 || gr >= 32) continue;
      ushort tmp[16];
      *(uint4*)(tmp)     = *(const uint4*)(src + gr * 32 + xh * 16);
      *(uint4*)(tmp + 8) = *(const uint4*)(src + gr * 32 + xh * 16 + 8);
      int base = (r * 36 + 2 + xh * 16) * ICP + ic;
#pragma unroll
      for (int j = 0; j < 16; ++j) lds[base + j * ICP] = tmp[j];
    }
  }
  __syncthreads();

  f32x4 acc[4][4];
#pragma unroll
  for (int i = 0; i < 4; ++i)
#pragma unroll
    for (int j = 0; j < 4; ++j) acc[i][j] = {0.f, 0.f, 0.f, 0.f};

  const ushort* wb = Wb + (size_t)(wave * 64) * 25 * 128;
  for (int kk = 0; kk < 25; ++kk) {
    int ky = kk / 5, kx = kk - ky * 5;
#pragma unroll
    for (int icc = 0; icc < 4; ++icc) {
      int ic0 = icc * 32 + 8 * lg;
      short8 a[4], bf[4];
#pragma unroll
      for (int g = 0; g < 4; ++g)
        a[g] = *(const short8*)(wb + ((size_t)(g * 16 + lo) * 25 + kk) * 128 + ic0);
#pragma unroll
      for (int g = 0; g < 4; ++g) {
        int row = (g >> 1) + ky;
        int x   = (g & 1) * 16 + lo + kx;
        bf[g] = *(const short8*)(lds + (row * 36 + x) * ICP + ic0);
      }
#pragma unroll
      for (int i = 0; i < 4; ++i)
#pragma unroll
        for (int j = 0; j < 4; ++j)
          acc[i][j] = __builtin_amdgcn_mfma_f32_16x16x32_bf16(a[i], bf[j], acc[i][j], 0, 0, 0);
    }
  }
#pragma unroll
  for (int i = 0; i < 4; ++i)
#pragma unroll
    for (int j = 0; j < 4; ++j)
#pragma unroll
      for (int r = 0; r < 4; ++r) {
        int oc = wave * 64 + i * 16 + lg * 4 + r;
        int p  = y0 * 32 + (j >> 1) * 32 + (j & 1) * 16 + lo;
        gates[(size_t)(b * 256 + oc) * NTOK + p] = acc[i][j][r] + bias[oc];
      }
}

// ---- gates -> c_new, h_new
__global__ __launch_bounds__(256) void lstm_kernel(
    const float* __restrict__ gates, const float* __restrict__ c_in,
    float* __restrict__ c_out, float* __restrict__ h_out) {
  size_t idx = (size_t)blockIdx.x * 256 + threadIdx.x;
  size_t b = idx >> 16;
  size_t r = idx & 65535;
  const float* gb = gates + b * (size_t)(256 * NTOK);
  float iv = gb[r];
  float fv = gb[65536 + r];
  float ov = gb[131072 + r];
  float gv = gb[196608 + r];
  iv = 1.f / (1.f + expf(-iv));
  fv = 1.f / (1.f + expf(-fv));
  ov = 1.f / (1.f + expf(-ov));
  gv = tanhf(gv);
  float cn = fv * c_in[idx] + iv * gv;
  c_out[idx] = cn;
  h_out[idx] = ov * tanhf(cn);
}

extern "C" void kernel_launch(void* const* d_in, const int* in_sizes, int n_in,
                              void* d_out, int out_size, void* d_ws, size_t ws_size,
                              hipStream_t stream) {
  const float* x      = (const float*)d_in[0];
  const float* h      = (const float*)d_in[1];
  const float* c      = (const float*)d_in[2];
  const float* Wq_x   = (const float*)d_in[3];
  const float* Wk_x   = (const float*)d_in[4];
  const float* Wv_x   = (const float*)d_in[5];
  const float* Wq_h   = (const float*)d_in[6];
  const float* Wk_h   = (const float*)d_in[7];
  const float* Wv_h   = (const float*)d_in[8];
  const float* W_lstm = (const float*)d_in[9];
  const float* b_lstm = (const float*)d_in[10];

  float* out   = (float*)d_out;
  float* new_h = out;                 // [16,64,32,32]
  float* new_c = out + 1048576;       // [16,64,32,32]
  float* atten = out + 2097152;       // [16,1024,1024]

  // ws layout (ushort granularity, ~8.4 MB of proven-available 12.4 MB)
  ushort* wsu = (ushort*)d_ws;
  ushort* qT  = wsu;                  //   524,288 ushort [b][n][32]
  ushort* kT  = wsu + 524288;         //   524,288
  ushort* vb  = wsu + 1048576;        // 1,048,576 [b][c][m]
  ushort* Xbf = wsu + 2097152;        // 1,048,576 (attn1 out -> conv in, [b][c][n])
  ushort* xT  = wsu + 3145728;        // 1,048,576 [b][n][64] (x, later h_mid)
  ushort* wqb = wsu + 4194304;        //     2,048
  ushort* wkb = wsu + 4196352;        //     2,048

  // scratch aliased into the atten output region:
  ushort* ab1   = (ushort*)atten;                // attn1 bf16 [b][n][m], 32MB
  float*  gates = atten;                         // conv out (after ab1 dead), 16MB
  ushort* Wb    = (ushort*)(atten + 8388608);    // conv weights bf16
  ushort* hb    = (ushort*)(atten + 9437184);    // h bf16 [b][c][n]
  float*  h_mid = new_h;                         // lstm h lives in new_h slot

  dim3 blk(256);
  // ---- attention 1 on x ----
  tpose_bf16_kernel<<<dim3(16, NB), blk, 0, stream>>>(x, xT);
  wqk_pre_kernel<<<8, blk, 0, stream>>>(Wq_x, Wk_x, wqb, wkb);
  qkproj_kernel<<<dim3(16, NB), blk, 0, stream>>>(xT, wqb, wkb, qT, kT);
  proj_kernel<<<dim3(4, NC, NB), blk, 0, stream>>>(Wv_x, x, vb, NC);
  scores_softmax_kernel<false><<<dim3(64, NB), blk, 0, stream>>>(qT, kT, nullptr, ab1);
  aggregate_mfma_kernel<true><<<dim3(16, NB), 64, 0, stream>>>(
      vb, ab1, nullptr, x, nullptr, Xbf, 1.0f);
  // ---- conv-lstm (bf16 MFMA implicit GEMM) ----
  wpre_kernel<<<128, blk, 0, stream>>>(W_lstm, Wb);
  hpre_kernel<<<1024, blk, 0, stream>>>(h, hb);
  conv_mfma_kernel<<<dim3(16, NB), blk, 0, stream>>>(Xbf, hb, Wb, b_lstm, gates);
  lstm_kernel<<<4096, blk, 0, stream>>>(gates, c, new_c, h_mid);
  // ---- attention 2 on h_mid (atten f32 is a real output) ----
  tpose_bf16_kernel<<<dim3(16, NB), blk, 0, stream>>>(h_mid, xT);
  wqk_pre_kernel<<<8, blk, 0, stream>>>(Wq_h, Wk_h, wqb, wkb);
  qkproj_kernel<<<dim3(16, NB), blk, 0, stream>>>(xT, wqb, wkb, qT, kT);
  proj_kernel<<<dim3(4, NC, NB), blk, 0, stream>>>(Wv_h, h_mid, vb, NC);
  scores_softmax_kernel<true><<<dim3(64, NB), blk, 0, stream>>>(qT, kT, atten, nullptr);
  aggregate_mfma_kernel<false><<<dim3(16, NB), 64, 0, stream>>>(
      vb, nullptr, atten, h_mid, new_h, nullptr, 2.0f);
}

// Round 5
// 184.264 us; speedup vs baseline: 11.8150x; 1.3074x over previous
//
#include <hip/hip_runtime.h>
#include <hip/hip_bf16.h>
#include <cstddef>
#include <cstdint>

// Problem constants: B=16, CIN=COUT=64, HID=32, H=W=32, K=5, PAD=2
#define NTOK 1024      // H*W
#define NB   16        // batch
#define NC   64        // channels (CIN == COUT)
#define NHID 32        // attention hidden

typedef __attribute__((ext_vector_type(8))) short short8;   // 8 bf16 = 4 VGPR (MFMA A/B frag)
typedef __attribute__((ext_vector_type(4))) float f32x4;    // MFMA acc frag

// round-to-nearest-even f32 -> bf16 (as raw ushort)
__device__ __forceinline__ ushort f2b(float f) {
  uint32_t u = __builtin_bit_cast(uint32_t, f);
  return (ushort)((u + 0x7FFFu + ((u >> 16) & 1u)) >> 16);
}

// ---- transpose + convert: src f32 [b][64c][1024n] -> dst bf16 [b][1024n][64c]
__global__ __launch_bounds__(256) void tpose_bf16_kernel(
    const float* __restrict__ src, ushort* __restrict__ dst) {
  __shared__ float tile[64][65];
  int t = threadIdx.x;
  int n0 = blockIdx.x * 64, b = blockIdx.y;
  const float* s = src + (size_t)b * NC * NTOK;
#pragma unroll
  for (int r = 0; r < 4; ++r) {
    int c = r * 16 + (t >> 4);
    int nl = (t & 15) * 4;
    float4 v = *(const float4*)(s + (size_t)c * NTOK + n0 + nl);
    tile[c][nl] = v.x; tile[c][nl + 1] = v.y; tile[c][nl + 2] = v.z; tile[c][nl + 3] = v.w;
  }
  __syncthreads();
  int tok = t >> 2, c0 = (t & 3) * 16;
  __attribute__((aligned(16))) ushort tmp[16];
#pragma unroll
  for (int i = 0; i < 16; ++i) tmp[i] = f2b(tile[c0 + i][tok]);
  ushort* d = dst + ((size_t)b * NTOK + n0 + tok) * NC + c0;
  *(uint4*)(d)     = *(const uint4*)(tmp);
  *(uint4*)(d + 8) = *(const uint4*)(tmp + 8);
}

// ---- Wq/Wk f32 [32][64] -> bf16 (same layout)
__global__ __launch_bounds__(256) void wqk_pre_kernel(
    const float* __restrict__ Wq, const float* __restrict__ Wk,
    ushort* __restrict__ wqb, ushort* __restrict__ wkb) {
  int i = blockIdx.x * 256 + threadIdx.x;
  wqb[i] = f2b(Wq[i]);
  wkb[i] = f2b(Wk[i]);
}

// ---- q,k projection via MFMA: qT/kT[b][n][32] = xT[b][n][64] x W[32][64]^T
__global__ __launch_bounds__(256) void qkproj_kernel(
    const ushort* __restrict__ xT, const ushort* __restrict__ wqb,
    const ushort* __restrict__ wkb, ushort* __restrict__ qT,
    ushort* __restrict__ kT) {
  __shared__ ushort sq[64][32], sk[64][32];
  int t = threadIdx.x, wave = t >> 6, lane = t & 63;
  int lo = lane & 15, lg = lane >> 4;
  int n0 = blockIdx.x * 64, b = blockIdx.y;
  int nw = n0 + wave * 16;
  const ushort* xrow = xT + ((size_t)b * NTOK + nw + lo) * NC + 8 * lg;
  short8 a0 = *(const short8*)(xrow);        // k = c in [0,32)
  short8 a1 = *(const short8*)(xrow + 32);   // k = c in [32,64)
  f32x4 aq[2], ak[2];
#pragma unroll
  for (int dg = 0; dg < 2; ++dg) {
    const ushort* wq = wqb + (size_t)(dg * 16 + lo) * NC + 8 * lg;
    const ushort* wk = wkb + (size_t)(dg * 16 + lo) * NC + 8 * lg;
    f32x4 z = {0.f, 0.f, 0.f, 0.f};
    aq[dg] = __builtin_amdgcn_mfma_f32_16x16x32_bf16(a0, *(const short8*)(wq), z, 0, 0, 0);
    aq[dg] = __builtin_amdgcn_mfma_f32_16x16x32_bf16(a1, *(const short8*)(wq + 32), aq[dg], 0, 0, 0);
    ak[dg] = __builtin_amdgcn_mfma_f32_16x16x32_bf16(a0, *(const short8*)(wk), z, 0, 0, 0);
    ak[dg] = __builtin_amdgcn_mfma_f32_16x16x32_bf16(a1, *(const short8*)(wk + 32), ak[dg], 0, 0, 0);
  }
#pragma unroll
  for (int dg = 0; dg < 2; ++dg)
#pragma unroll
    for (int r = 0; r < 4; ++r) {
      sq[wave * 16 + 4 * lg + r][dg * 16 + lo] = f2b(aq[dg][r]);
      sk[wave * 16 + 4 * lg + r][dg * 16 + lo] = f2b(ak[dg][r]);
    }
  __syncthreads();
  int tok = t >> 2, d0 = (t & 3) * 8;
  size_t base = ((size_t)b * NTOK + n0 + tok) * NHID + d0;
  *(short8*)(qT + base) = *(const short8*)(&sq[tok][d0]);
  *(short8*)(kT + base) = *(const short8*)(&sk[tok][d0]);
}

// ---- scores + softmax, MFMA. One wg (4 waves) per 16 n-rows.
template <bool F32OUT>
__global__ __launch_bounds__(256) void scores_softmax_kernel(
    const ushort* __restrict__ qT, const ushort* __restrict__ kT,
    float* __restrict__ attnf, ushort* __restrict__ attnb) {
  __shared__ float wmax[4][16], wsum[4][16];
  int t = threadIdx.x, wave = t >> 6, lane = t & 63;
  int lo = lane & 15, lg = lane >> 4;
  int n0 = blockIdx.x * 16, b = blockIdx.y;
  int m0 = wave * 256;
  short8 a = *(const short8*)(qT + ((size_t)b * NTOK + n0 + lo) * NHID + 8 * lg);
  f32x4 acc[16];
#pragma unroll
  for (int j = 0; j < 16; ++j) {
    short8 bf = *(const short8*)(kT + ((size_t)b * NTOK + m0 + j * 16 + lo) * NHID + 8 * lg);
    f32x4 z = {0.f, 0.f, 0.f, 0.f};
    acc[j] = __builtin_amdgcn_mfma_f32_16x16x32_bf16(a, bf, z, 0, 0, 0);
  }
  float pm[4];
#pragma unroll
  for (int r = 0; r < 4; ++r) {
    float m = acc[0][r];
#pragma unroll
    for (int j = 1; j < 16; ++j) m = fmaxf(m, acc[j][r]);
#pragma unroll
    for (int off = 1; off < 16; off <<= 1) m = fmaxf(m, __shfl_xor(m, off, 64));
    pm[r] = m;
  }
  if (lo == 0)
#pragma unroll
    for (int r = 0; r < 4; ++r) wmax[wave][4 * lg + r] = pm[r];
  __syncthreads();
  float mr[4];
#pragma unroll
  for (int r = 0; r < 4; ++r)
    mr[r] = fmaxf(fmaxf(wmax[0][4 * lg + r], wmax[1][4 * lg + r]),
                  fmaxf(wmax[2][4 * lg + r], wmax[3][4 * lg + r]));
  float ps[4] = {0.f, 0.f, 0.f, 0.f};
#pragma unroll
  for (int j = 0; j < 16; ++j)
#pragma unroll
    for (int r = 0; r < 4; ++r) {
      float e = __expf(acc[j][r] - mr[r]);
      acc[j][r] = e;
      ps[r] += e;
    }
#pragma unroll
  for (int r = 0; r < 4; ++r)
#pragma unroll
    for (int off = 1; off < 16; off <<= 1) ps[r] += __shfl_xor(ps[r], off, 64);
  if (lo == 0)
#pragma unroll
    for (int r = 0; r < 4; ++r) wsum[wave][4 * lg + r] = ps[r];
  __syncthreads();
  float inv[4];
#pragma unroll
  for (int r = 0; r < 4; ++r)
    inv[r] = 1.f / (wsum[0][4 * lg + r] + wsum[1][4 * lg + r] +
                    wsum[2][4 * lg + r] + wsum[3][4 * lg + r]);
#pragma unroll
  for (int j = 0; j < 16; ++j)
#pragma unroll
    for (int r = 0; r < 4; ++r) {
      size_t idx = ((size_t)b * NTOK + n0 + 4 * lg + r) * NTOK + m0 + j * 16 + lo;
      float val = acc[j][r] * inv[r];
      if constexpr (F32OUT) attnf[idx] = val;
      else                  attnb[idx] = f2b(val);
    }
}

// ---- v projection (scalar; writes bf16 [b][c][m])
__global__ __launch_bounds__(256) void proj_kernel(
    const float* __restrict__ W, const float* __restrict__ x,
    ushort* __restrict__ outb, int D) {
  int n = blockIdx.x * 256 + threadIdx.x;
  int d = blockIdx.y, b = blockIdx.z;
  const float* xb = x + (size_t)b * NC * NTOK + n;
  const float* wr = W + (size_t)d * NC;
  float acc = 0.f;
#pragma unroll 8
  for (int c = 0; c < NC; ++c) acc = fmaf(wr[c], xb[(size_t)c * NTOK], acc);
  outb[((size_t)b * D + d) * NTOK + n] = f2b(acc);
}

// ---- MFMA aggregate, 4-wave m-split: out = scale*(resid + V.attn^T)
// wg = (64-n tile, b), wave w covers m in [w*256, w*256+256). LDS combine.
// outb (agg1): token-major bf16 [b][n][c] (conv input). outf (agg2): f32 [b][c][n].
template <bool BF16B>
__global__ __launch_bounds__(256) void aggregate_mfma_kernel(
    const ushort* __restrict__ vb, const ushort* __restrict__ abf,
    const float* __restrict__ af32, const float* __restrict__ resid,
    float* __restrict__ outf, ushort* __restrict__ outb, float scale) {
  __shared__ float red[4 * 64 * 66];   // [wave][c][n], n-pitch 66
  int t = threadIdx.x, wave = t >> 6, lane = t & 63;
  int lo = lane & 15, lg = lane >> 4;
  int n0 = blockIdx.x * 64, b = blockIdx.y;
  const ushort* V = vb + (size_t)b * NC * NTOK;
  const ushort* Ab = BF16B ? abf + ((size_t)b * NTOK + n0) * NTOK : nullptr;
  const float*  Af = BF16B ? nullptr : af32 + ((size_t)b * NTOK + n0) * NTOK;
  int mbase = wave * 256;

  f32x4 acc[4][4];
#pragma unroll
  for (int i = 0; i < 4; ++i)
#pragma unroll
    for (int j = 0; j < 4; ++j) acc[i][j] = {0.f, 0.f, 0.f, 0.f};

  for (int m0 = 0; m0 < 256; m0 += 32) {
    int mk = mbase + m0 + 8 * lg;
    short8 a[4], bf[4];
#pragma unroll
    for (int g = 0; g < 4; ++g)
      a[g] = *(const short8*)(V + (size_t)(g * 16 + lo) * NTOK + mk);
    if constexpr (BF16B) {
#pragma unroll
      for (int g = 0; g < 4; ++g)
        bf[g] = *(const short8*)(Ab + (size_t)(g * 16 + lo) * NTOK + mk);
    } else {
#pragma unroll
      for (int g = 0; g < 4; ++g) {
        const float* p = Af + (size_t)(g * 16 + lo) * NTOK + mk;
        float4 f0 = *(const float4*)(p);
        float4 f1 = *(const float4*)(p + 4);
        short8 r;
        r[0] = (short)f2b(f0.x); r[1] = (short)f2b(f0.y);
        r[2] = (short)f2b(f0.z); r[3] = (short)f2b(f0.w);
        r[4] = (short)f2b(f1.x); r[5] = (short)f2b(f1.y);
        r[6] = (short)f2b(f1.z); r[7] = (short)f2b(f1.w);
        bf[g] = r;
      }
    }
#pragma unroll
    for (int i = 0; i < 4; ++i)
#pragma unroll
      for (int j = 0; j < 4; ++j)
        acc[i][j] = __builtin_amdgcn_mfma_f32_16x16x32_bf16(a[i], bf[j], acc[i][j], 0, 0, 0);
  }
  // write partials: c = i*16+lg*4+r, n = j*16+lo
#pragma unroll
  for (int i = 0; i < 4; ++i)
#pragma unroll
    for (int j = 0; j < 4; ++j)
#pragma unroll
      for (int r = 0; r < 4; ++r)
        red[(wave * 64 + i * 16 + lg * 4 + r) * 66 + j * 16 + lo] = acc[i][j][r];
  __syncthreads();
  // combine + epilogue: thread t -> c = t>>2, n = (t&3)*16 + i
  int c = t >> 2, nb = (t & 3) * 16;
#pragma unroll
  for (int i = 0; i < 16; ++i) {
    int n = nb + i;
    float s = red[(c) * 66 + n] + red[(64 + c) * 66 + n] +
              red[(128 + c) * 66 + n] + red[(192 + c) * 66 + n];
    size_t idx = ((size_t)b * NC + c) * NTOK + n0 + n;
    float val = scale * (resid[idx] + s);
    if (outb) outb[((size_t)b * NTOK + n0 + n) * NC + c] = f2b(val);  // token-major
    else      outf[idx] = val;
  }
}

// ---- conv weight pre-pass: W_lstm[oc][ic][5][5] f32 -> Wb[oc][25][128] bf16
__global__ __launch_bounds__(256) void wpre_kernel(
    const float* __restrict__ W, ushort* __restrict__ Wb) {
  int idx = blockIdx.x * 256 + threadIdx.x;
  int oc = idx >> 7, ic = idx & 127;
  const float* src = W + (size_t)idx * 25;
#pragma unroll
  for (int kk = 0; kk < 25; ++kk)
    Wb[((size_t)oc * 25 + kk) * 128 + ic] = f2b(src[kk]);
}

// ---- implicit-GEMM conv via bf16 MFMA, token-major inputs.
// Grid (16 rp, 2 och, 16 b): wg = 128 oc x 64 px (2 rows). Wave = 32 oc.
// LDS window [216 px][128 ic, pitch 136] bf16 = 58.75 KB -> 2 wg/CU.
// Weights ping-pong prefetched one kk ahead (8 x 16B L2 loads under 32 MFMAs).
#define ICP 136
__global__ __launch_bounds__(256, 2) void conv_mfma_kernel(
    const ushort* __restrict__ XbT,   // [b][1024 tok][64 c] bf16
    const ushort* __restrict__ hbT,   // [b][1024 tok][64 c] bf16
    const ushort* __restrict__ Wb,    // [256 oc][25 kk][128 ic] bf16
    const float* __restrict__ bias,
    float* __restrict__ gates) {
  __shared__ ushort lds[216 * ICP];
  int t = threadIdx.x, wave = t >> 6, lane = t & 63;
  int lo = lane & 15, lg = lane >> 4;
  int rp = blockIdx.x, och = blockIdx.y, b = blockIdx.z;
  int y0 = rp * 2;
  // stage: slot = (px, 8-ch chunk); zeros for padding. ds_write_b128, aligned.
  {
    const ushort* Xb_ = XbT + (size_t)b * NTOK * NC;
    const ushort* hb_ = hbT + (size_t)b * NTOK * NC;
    for (int slot = t; slot < 216 * 16; slot += 256) {
      int px = slot >> 4, ch8 = (slot & 15) * 8;
      int r = px / 36, xx = px - r * 36;
      int gr = y0 - 2 + r, gx = xx - 2;
      uint4 val = make_uint4(0u, 0u, 0u, 0u);
      if (gr >= 0 && gr < 32 && gx >= 0 && gx < 32) {
        const ushort* src = (ch8 < 64)
            ? Xb_ + (size_t)(gr * 32 + gx) * NC + ch8
            : hb_ + (size_t)(gr * 32 + gx) * NC + (ch8 - 64);
        val = *(const uint4*)src;
      }
      *(uint4*)(lds + px * ICP + ch8) = val;
    }
  }
  __syncthreads();

  int oc_base = och * 128 + wave * 32;
  const ushort* wbase = Wb + (size_t)(oc_base + lo) * 25 * 128 + 8 * lg;

  f32x4 acc[2][4];
#pragma unroll
  for (int g = 0; g < 2; ++g)
#pragma unroll
    for (int j = 0; j < 4; ++j) acc[g][j] = {0.f, 0.f, 0.f, 0.f};

  short8 aA[8], aB[8];   // [icc*2+g], static indexing only

#define LOADW(dst, kkv)                                                        \
  {                                                                            \
    const ushort* _p = wbase + (kkv) * 128;                                    \
    _Pragma("unroll") for (int icc = 0; icc < 4; ++icc)                        \
        _Pragma("unroll") for (int g = 0; g < 2; ++g)                          \
            dst[icc * 2 + g] = *(const short8*)(_p + g * 51200 + icc * 32);    \
  }

#define COMPUTE(arr, kkv)                                                      \
  {                                                                            \
    int _ky = (kkv) / 5, _kx = (kkv) - 5 * _ky;                                \
    int _pb = _ky * 36 + _kx;                                                  \
    _Pragma("unroll") for (int icc = 0; icc < 4; ++icc) {                      \
      short8 bf[4];                                                            \
      _Pragma("unroll") for (int j = 0; j < 4; ++j) {                          \
        int px = _pb + (j >> 1) * 36 + (j & 1) * 16 + lo;                      \
        bf[j] = *(const short8*)(lds + px * ICP + icc * 32 + 8 * lg);          \
      }                                                                        \
      _Pragma("unroll") for (int g = 0; g < 2; ++g)                            \
          _Pragma("unroll") for (int j = 0; j < 4; ++j)                        \
              acc[g][j] = __builtin_amdgcn_mfma_f32_16x16x32_bf16(             \
                  arr[icc * 2 + g], bf[j], acc[g][j], 0, 0, 0);                \
    }                                                                          \
  }

  LOADW(aA, 0);
  for (int kk2 = 0; kk2 < 12; ++kk2) {
    int kk = 2 * kk2;
    LOADW(aB, kk + 1);
    COMPUTE(aA, kk);
    LOADW(aA, kk + 2);
    COMPUTE(aB, kk + 1);
  }
  COMPUTE(aA, 24);
#undef LOADW
#undef COMPUTE

  // epilogue: oc = oc_base + g*16 + lg*4 + r; px = y0*32 + (j>>1)*32 + (j&1)*16 + lo
#pragma unroll
  for (int g = 0; g < 2; ++g)
#pragma unroll
    for (int j = 0; j < 4; ++j)
#pragma unroll
      for (int r = 0; r < 4; ++r) {
        int oc = oc_base + g * 16 + lg * 4 + r;
        int p  = y0 * 32 + (j >> 1) * 32 + (j & 1) * 16 + lo;
        gates[(size_t)(b * 256 + oc) * NTOK + p] = acc[g][j][r] + bias[oc];
      }
}

// ---- gates -> c_new, h_new
__global__ __launch_bounds__(256) void lstm_kernel(
    const float* __restrict__ gates, const float* __restrict__ c_in,
    float* __restrict__ c_out, float* __restrict__ h_out) {
  size_t idx = (size_t)blockIdx.x * 256 + threadIdx.x;
  size_t b = idx >> 16;
  size_t r = idx & 65535;
  const float* gb = gates + b * (size_t)(256 * NTOK);
  float iv = gb[r];
  float fv = gb[65536 + r];
  float ov = gb[131072 + r];
  float gv = gb[196608 + r];
  iv = 1.f / (1.f + expf(-iv));
  fv = 1.f / (1.f + expf(-fv));
  ov = 1.f / (1.f + expf(-ov));
  gv = tanhf(gv);
  float cn = fv * c_in[idx] + iv * gv;
  c_out[idx] = cn;
  h_out[idx] = ov * tanhf(cn);
}

extern "C" void kernel_launch(void* const* d_in, const int* in_sizes, int n_in,
                              void* d_out, int out_size, void* d_ws, size_t ws_size,
                              hipStream_t stream) {
  const float* x      = (const float*)d_in[0];
  const float* h      = (const float*)d_in[1];
  const float* c      = (const float*)d_in[2];
  const float* Wq_x   = (const float*)d_in[3];
  const float* Wk_x   = (const float*)d_in[4];
  const float* Wv_x   = (const float*)d_in[5];
  const float* Wq_h   = (const float*)d_in[6];
  const float* Wk_h   = (const float*)d_in[7];
  const float* Wv_h   = (const float*)d_in[8];
  const float* W_lstm = (const float*)d_in[9];
  const float* b_lstm = (const float*)d_in[10];

  float* out   = (float*)d_out;
  float* new_h = out;                 // [16,64,32,32]
  float* new_c = out + 1048576;       // [16,64,32,32]
  float* atten = out + 2097152;       // [16,1024,1024]

  // ws layout (ushort granularity, ~8.4 MB of proven-available 12.4 MB)
  ushort* wsu = (ushort*)d_ws;
  ushort* qT  = wsu;                  //   524,288 ushort [b][n][32]
  ushort* kT  = wsu + 524288;         //   524,288
  ushort* vb  = wsu + 1048576;        // 1,048,576 [b][c][m]
  ushort* XbT = wsu + 2097152;        // 1,048,576 token-major [b][n][64] (conv in)
  ushort* xT  = wsu + 3145728;        // 1,048,576 [b][n][64] (x, later h_mid)
  ushort* wqb = wsu + 4194304;        //     2,048
  ushort* wkb = wsu + 4196352;        //     2,048

  // scratch aliased into the atten output region:
  ushort* ab1   = (ushort*)atten;                // attn1 bf16 [b][n][m], bytes [0,32M)
  float*  gates = atten;                         // conv out (after ab1 dead), 16MB
  ushort* Wb    = (ushort*)(atten + 8388608);    // conv weights bf16, bytes [32M,33.6M)
  ushort* hbT   = (ushort*)(atten + 9437184);    // h bf16 token-major [b][n][64]
  float*  h_mid = new_h;                         // lstm h lives in new_h slot

  dim3 blk(256);
  // ---- attention 1 on x ----
  tpose_bf16_kernel<<<dim3(16, NB), blk, 0, stream>>>(x, xT);
  wqk_pre_kernel<<<8, blk, 0, stream>>>(Wq_x, Wk_x, wqb, wkb);
  qkproj_kernel<<<dim3(16, NB), blk, 0, stream>>>(xT, wqb, wkb, qT, kT);
  proj_kernel<<<dim3(4, NC, NB), blk, 0, stream>>>(Wv_x, x, vb, NC);
  scores_softmax_kernel<false><<<dim3(64, NB), blk, 0, stream>>>(qT, kT, nullptr, ab1);
  aggregate_mfma_kernel<true><<<dim3(16, NB), blk, 0, stream>>>(
      vb, ab1, nullptr, x, nullptr, XbT, 1.0f);
  // ---- conv-lstm (bf16 MFMA implicit GEMM) ----
  wpre_kernel<<<128, blk, 0, stream>>>(W_lstm, Wb);
  tpose_bf16_kernel<<<dim3(16, NB), blk, 0, stream>>>(h, hbT);
  conv_mfma_kernel<<<dim3(16, 2, NB), blk, 0, stream>>>(XbT, hbT, Wb, b_lstm, gates);
  lstm_kernel<<<4096, blk, 0, stream>>>(gates, c, new_c, h_mid);
  // ---- attention 2 on h_mid (atten f32 is a real output) ----
  tpose_bf16_kernel<<<dim3(16, NB), blk, 0, stream>>>(h_mid, xT);
  wqk_pre_kernel<<<8, blk, 0, stream>>>(Wq_h, Wk_h, wqb, wkb);
  qkproj_kernel<<<dim3(16, NB), blk, 0, stream>>>(xT, wqb, wkb, qT, kT);
  proj_kernel<<<dim3(4, NC, NB), blk, 0, stream>>>(Wv_h, h_mid, vb, NC);
  scores_softmax_kernel<true><<<dim3(64, NB), blk, 0, stream>>>(qT, kT, atten, nullptr);
  aggregate_mfma_kernel<false><<<dim3(16, NB), blk, 0, stream>>>(
      vb, nullptr, atten, h_mid, new_h, nullptr, 2.0f);
}

// Round 6
// 170.750 us; speedup vs baseline: 12.7502x; 1.0791x over previous
//
#include <hip/hip_runtime.h>
#include <hip/hip_bf16.h>
#include <cstddef>
#include <cstdint>

// Problem constants: B=16, CIN=COUT=64, HID=32, H=W=32, K=5, PAD=2
#define NTOK 1024      // H*W
#define NB   16        // batch
#define NC   64        // channels (CIN == COUT)
#define NHID 32        // attention hidden

typedef __attribute__((ext_vector_type(8))) short short8;   // 8 bf16 = 4 VGPR (MFMA A/B frag)
typedef __attribute__((ext_vector_type(4))) float f32x4;    // MFMA acc frag

// round-to-nearest-even f32 -> bf16 (as raw ushort)
__device__ __forceinline__ ushort f2b(float f) {
  uint32_t u = __builtin_bit_cast(uint32_t, f);
  return (ushort)((u + 0x7FFFu + ((u >> 16) & 1u)) >> 16);
}

// ---- transpose + convert: src f32 [b][64c][1024n] -> dst bf16 [b][1024n][64c]
__global__ __launch_bounds__(256) void tpose_bf16_kernel(
    const float* __restrict__ src, ushort* __restrict__ dst) {
  __shared__ float tile[64][65];
  int t = threadIdx.x;
  int n0 = blockIdx.x * 64, b = blockIdx.y;
  const float* s = src + (size_t)b * NC * NTOK;
#pragma unroll
  for (int r = 0; r < 4; ++r) {
    int c = r * 16 + (t >> 4);
    int nl = (t & 15) * 4;
    float4 v = *(const float4*)(s + (size_t)c * NTOK + n0 + nl);
    tile[c][nl] = v.x; tile[c][nl + 1] = v.y; tile[c][nl + 2] = v.z; tile[c][nl + 3] = v.w;
  }
  __syncthreads();
  int tok = t >> 2, c0 = (t & 3) * 16;
  __attribute__((aligned(16))) ushort tmp[16];
#pragma unroll
  for (int i = 0; i < 16; ++i) tmp[i] = f2b(tile[c0 + i][tok]);
  ushort* d = dst + ((size_t)b * NTOK + n0 + tok) * NC + c0;
  *(uint4*)(d)     = *(const uint4*)(tmp);
  *(uint4*)(d + 8) = *(const uint4*)(tmp + 8);
}

// ---- Wq/Wk [32][64] and Wv [64][64] f32 -> bf16 (same layouts). 16 x 256 threads.
__global__ __launch_bounds__(256) void wqkv_pre_kernel(
    const float* __restrict__ Wq, const float* __restrict__ Wk,
    const float* __restrict__ Wv, ushort* __restrict__ wqb,
    ushort* __restrict__ wkb, ushort* __restrict__ wvb) {
  int i = blockIdx.x * 256 + threadIdx.x;
  if (i < 2048) { wqb[i] = f2b(Wq[i]); wkb[i] = f2b(Wk[i]); }
  wvb[i] = f2b(Wv[i]);
}

// ---- q,k projection via MFMA: qT/kT[b][n][32] = xT[b][n][64] x W[32][64]^T
__global__ __launch_bounds__(256) void qkproj_kernel(
    const ushort* __restrict__ xT, const ushort* __restrict__ wqb,
    const ushort* __restrict__ wkb, ushort* __restrict__ qT,
    ushort* __restrict__ kT) {
  __shared__ ushort sq[64][32], sk[64][32];
  int t = threadIdx.x, wave = t >> 6, lane = t & 63;
  int lo = lane & 15, lg = lane >> 4;
  int n0 = blockIdx.x * 64, b = blockIdx.y;
  int nw = n0 + wave * 16;
  const ushort* xrow = xT + ((size_t)b * NTOK + nw + lo) * NC + 8 * lg;
  short8 a0 = *(const short8*)(xrow);        // k = c in [0,32)
  short8 a1 = *(const short8*)(xrow + 32);   // k = c in [32,64)
  f32x4 aq[2], ak[2];
#pragma unroll
  for (int dg = 0; dg < 2; ++dg) {
    const ushort* wq = wqb + (size_t)(dg * 16 + lo) * NC + 8 * lg;
    const ushort* wk = wkb + (size_t)(dg * 16 + lo) * NC + 8 * lg;
    f32x4 z = {0.f, 0.f, 0.f, 0.f};
    aq[dg] = __builtin_amdgcn_mfma_f32_16x16x32_bf16(a0, *(const short8*)(wq), z, 0, 0, 0);
    aq[dg] = __builtin_amdgcn_mfma_f32_16x16x32_bf16(a1, *(const short8*)(wq + 32), aq[dg], 0, 0, 0);
    ak[dg] = __builtin_amdgcn_mfma_f32_16x16x32_bf16(a0, *(const short8*)(wk), z, 0, 0, 0);
    ak[dg] = __builtin_amdgcn_mfma_f32_16x16x32_bf16(a1, *(const short8*)(wk + 32), ak[dg], 0, 0, 0);
  }
#pragma unroll
  for (int dg = 0; dg < 2; ++dg)
#pragma unroll
    for (int r = 0; r < 4; ++r) {
      sq[wave * 16 + 4 * lg + r][dg * 16 + lo] = f2b(aq[dg][r]);
      sk[wave * 16 + 4 * lg + r][dg * 16 + lo] = f2b(ak[dg][r]);
    }
  __syncthreads();
  int tok = t >> 2, d0 = (t & 3) * 8;
  size_t base = ((size_t)b * NTOK + n0 + tok) * NHID + d0;
  *(short8*)(qT + base) = *(const short8*)(&sq[tok][d0]);
  *(short8*)(kT + base) = *(const short8*)(&sk[tok][d0]);
}

// ---- v projection via MFMA: vb[b][64e][1024m] = Wv[64e][64c] x xT[b][m][64c]^T
// wg = 4 waves, wave owns 16 tokens x 64 e, K=64 (2 k-steps).
__global__ __launch_bounds__(256) void vproj_kernel(
    const ushort* __restrict__ xT, const ushort* __restrict__ wvb,
    ushort* __restrict__ vb) {
  int t = threadIdx.x, wave = t >> 6, lane = t & 63;
  int lo = lane & 15, lg = lane >> 4;
  int n0 = blockIdx.x * 64, b = blockIdx.y;
  int n = n0 + wave * 16 + lo;
  const ushort* xrow = xT + ((size_t)b * NTOK + n) * NC + 8 * lg;
  short8 b0 = *(const short8*)(xrow);
  short8 b1 = *(const short8*)(xrow + 32);
  f32x4 acc[4];
#pragma unroll
  for (int g = 0; g < 4; ++g) {
    const ushort* wv = wvb + (size_t)(g * 16 + lo) * NC + 8 * lg;
    f32x4 z = {0.f, 0.f, 0.f, 0.f};
    acc[g] = __builtin_amdgcn_mfma_f32_16x16x32_bf16(*(const short8*)(wv), b0, z, 0, 0, 0);
    acc[g] = __builtin_amdgcn_mfma_f32_16x16x32_bf16(*(const short8*)(wv + 32), b1, acc[g], 0, 0, 0);
  }
  // C/D: col = lo -> token n; row = lg*4+r within e-group g
  ushort* vbase = vb + (size_t)b * NC * NTOK + n0 + wave * 16 + lo;
#pragma unroll
  for (int g = 0; g < 4; ++g)
#pragma unroll
    for (int r = 0; r < 4; ++r)
      vbase[(size_t)(g * 16 + lg * 4 + r) * NTOK] = f2b(acc[g][r]);
}

// ---- scores + softmax, MFMA. One wg (4 waves) per 16 n-rows.
template <bool F32OUT>
__global__ __launch_bounds__(256) void scores_softmax_kernel(
    const ushort* __restrict__ qT, const ushort* __restrict__ kT,
    float* __restrict__ attnf, ushort* __restrict__ attnb) {
  __shared__ float wmax[4][16], wsum[4][16];
  int t = threadIdx.x, wave = t >> 6, lane = t & 63;
  int lo = lane & 15, lg = lane >> 4;
  int n0 = blockIdx.x * 16, b = blockIdx.y;
  int m0 = wave * 256;
  short8 a = *(const short8*)(qT + ((size_t)b * NTOK + n0 + lo) * NHID + 8 * lg);
  f32x4 acc[16];
#pragma unroll
  for (int j = 0; j < 16; ++j) {
    short8 bf = *(const short8*)(kT + ((size_t)b * NTOK + m0 + j * 16 + lo) * NHID + 8 * lg);
    f32x4 z = {0.f, 0.f, 0.f, 0.f};
    acc[j] = __builtin_amdgcn_mfma_f32_16x16x32_bf16(a, bf, z, 0, 0, 0);
  }
  float pm[4];
#pragma unroll
  for (int r = 0; r < 4; ++r) {
    float m = acc[0][r];
#pragma unroll
    for (int j = 1; j < 16; ++j) m = fmaxf(m, acc[j][r]);
#pragma unroll
    for (int off = 1; off < 16; off <<= 1) m = fmaxf(m, __shfl_xor(m, off, 64));
    pm[r] = m;
  }
  if (lo == 0)
#pragma unroll
    for (int r = 0; r < 4; ++r) wmax[wave][4 * lg + r] = pm[r];
  __syncthreads();
  float mr[4];
#pragma unroll
  for (int r = 0; r < 4; ++r)
    mr[r] = fmaxf(fmaxf(wmax[0][4 * lg + r], wmax[1][4 * lg + r]),
                  fmaxf(wmax[2][4 * lg + r], wmax[3][4 * lg + r]));
  float ps[4] = {0.f, 0.f, 0.f, 0.f};
#pragma unroll
  for (int j = 0; j < 16; ++j)
#pragma unroll
    for (int r = 0; r < 4; ++r) {
      float e = __expf(acc[j][r] - mr[r]);
      acc[j][r] = e;
      ps[r] += e;
    }
#pragma unroll
  for (int r = 0; r < 4; ++r)
#pragma unroll
    for (int off = 1; off < 16; off <<= 1) ps[r] += __shfl_xor(ps[r], off, 64);
  if (lo == 0)
#pragma unroll
    for (int r = 0; r < 4; ++r) wsum[wave][4 * lg + r] = ps[r];
  __syncthreads();
  float inv[4];
#pragma unroll
  for (int r = 0; r < 4; ++r)
    inv[r] = 1.f / (wsum[0][4 * lg + r] + wsum[1][4 * lg + r] +
                    wsum[2][4 * lg + r] + wsum[3][4 * lg + r]);
#pragma unroll
  for (int j = 0; j < 16; ++j)
#pragma unroll
    for (int r = 0; r < 4; ++r) {
      size_t idx = ((size_t)b * NTOK + n0 + 4 * lg + r) * NTOK + m0 + j * 16 + lo;
      float val = acc[j][r] * inv[r];
      if constexpr (F32OUT) attnf[idx] = val;
      else                  attnb[idx] = f2b(val);
    }
}

// ---- MFMA aggregate, 4-wave m-split: out = scale*(resid + V.attn^T)
template <bool BF16B>
__global__ __launch_bounds__(256) void aggregate_mfma_kernel(
    const ushort* __restrict__ vb, const ushort* __restrict__ abf,
    const float* __restrict__ af32, const float* __restrict__ resid,
    float* __restrict__ outf, ushort* __restrict__ outb, float scale) {
  __shared__ float red[4 * 64 * 66];   // [wave][c][n], n-pitch 66
  int t = threadIdx.x, wave = t >> 6, lane = t & 63;
  int lo = lane & 15, lg = lane >> 4;
  int n0 = blockIdx.x * 64, b = blockIdx.y;
  const ushort* V = vb + (size_t)b * NC * NTOK;
  const ushort* Ab = BF16B ? abf + ((size_t)b * NTOK + n0) * NTOK : nullptr;
  const float*  Af = BF16B ? nullptr : af32 + ((size_t)b * NTOK + n0) * NTOK;
  int mbase = wave * 256;

  f32x4 acc[4][4];
#pragma unroll
  for (int i = 0; i < 4; ++i)
#pragma unroll
    for (int j = 0; j < 4; ++j) acc[i][j] = {0.f, 0.f, 0.f, 0.f};

  for (int m0 = 0; m0 < 256; m0 += 32) {
    int mk = mbase + m0 + 8 * lg;
    short8 a[4], bf[4];
#pragma unroll
    for (int g = 0; g < 4; ++g)
      a[g] = *(const short8*)(V + (size_t)(g * 16 + lo) * NTOK + mk);
    if constexpr (BF16B) {
#pragma unroll
      for (int g = 0; g < 4; ++g)
        bf[g] = *(const short8*)(Ab + (size_t)(g * 16 + lo) * NTOK + mk);
    } else {
#pragma unroll
      for (int g = 0; g < 4; ++g) {
        const float* p = Af + (size_t)(g * 16 + lo) * NTOK + mk;
        float4 f0 = *(const float4*)(p);
        float4 f1 = *(const float4*)(p + 4);
        short8 r;
        r[0] = (short)f2b(f0.x); r[1] = (short)f2b(f0.y);
        r[2] = (short)f2b(f0.z); r[3] = (short)f2b(f0.w);
        r[4] = (short)f2b(f1.x); r[5] = (short)f2b(f1.y);
        r[6] = (short)f2b(f1.z); r[7] = (short)f2b(f1.w);
        bf[g] = r;
      }
    }
#pragma unroll
    for (int i = 0; i < 4; ++i)
#pragma unroll
      for (int j = 0; j < 4; ++j)
        acc[i][j] = __builtin_amdgcn_mfma_f32_16x16x32_bf16(a[i], bf[j], acc[i][j], 0, 0, 0);
  }
#pragma unroll
  for (int i = 0; i < 4; ++i)
#pragma unroll
    for (int j = 0; j < 4; ++j)
#pragma unroll
      for (int r = 0; r < 4; ++r)
        red[(wave * 64 + i * 16 + lg * 4 + r) * 66 + j * 16 + lo] = acc[i][j][r];
  __syncthreads();
  int c = t >> 2, nb = (t & 3) * 16;
#pragma unroll
  for (int i = 0; i < 16; ++i) {
    int n = nb + i;
    float s = red[(c) * 66 + n] + red[(64 + c) * 66 + n] +
              red[(128 + c) * 66 + n] + red[(192 + c) * 66 + n];
    size_t idx = ((size_t)b * NC + c) * NTOK + n0 + n;
    float val = scale * (resid[idx] + s);
    if (outb) outb[((size_t)b * NTOK + n0 + n) * NC + c] = f2b(val);  // token-major
    else      outf[idx] = val;
  }
}

// ---- conv weight pre-pass: W_lstm[oc][ic][5][5] f32 -> Wb[oc][25][128] bf16
__global__ __launch_bounds__(256) void wpre_kernel(
    const float* __restrict__ W, ushort* __restrict__ Wb) {
  int idx = blockIdx.x * 256 + threadIdx.x;
  int oc = idx >> 7, ic = idx & 127;
  const float* src = W + (size_t)idx * 25;
#pragma unroll
  for (int kk = 0; kk < 25; ++kk)
    Wb[((size_t)oc * 25 + kk) * 128 + ic] = f2b(src[kk]);
}

// ---- implicit-GEMM conv, K split by ic-half (kh=0: X channels, kh=1: h channels).
// Grid (16 ptile, 2 kh, 16 b) = 512 wgs, 2 wg/CU. wg = 4 waves, each 64 oc x 64 px.
// LDS window [216 px][64 ic pad 72] bf16 = 31.1 KB. Weight ping-pong from L2.
// Gate halves summed (with bias) in lstm_kernel.
#define ICP 72
__global__ __launch_bounds__(256, 2) void conv_mfma_kernel(
    const ushort* __restrict__ XbT,   // [b][1024 tok][64 c] bf16
    const ushort* __restrict__ hbT,   // [b][1024 tok][64 c] bf16
    const ushort* __restrict__ Wb,    // [256 oc][25 kk][128 ic] bf16
    float* __restrict__ gates0, float* __restrict__ gates1) {
  __shared__ ushort lds[216 * ICP];
  int t = threadIdx.x, wave = t >> 6, lane = t & 63;
  int lo = lane & 15, lg = lane >> 4;
  int rp = blockIdx.x, kh = blockIdx.y, b = blockIdx.z;
  int y0 = rp * 2;
  // stage 6 rows x 36 cols x 64 ic (this kh's source only), zeros in halo
  {
    const ushort* S = (kh ? hbT : XbT) + (size_t)b * NTOK * NC;
    for (int slot = t; slot < 216 * 8; slot += 256) {
      int px = slot >> 3, ch8 = (slot & 7) * 8;
      int r = px / 36, xx = px - r * 36;
      int gr = y0 - 2 + r, gx = xx - 2;
      uint4 val = make_uint4(0u, 0u, 0u, 0u);
      if (gr >= 0 && gr < 32 && gx >= 0 && gx < 32)
        val = *(const uint4*)(S + (size_t)(gr * 32 + gx) * NC + ch8);
      *(uint4*)(lds + px * ICP + ch8) = val;
    }
  }
  __syncthreads();

  int oc_base = wave * 64;
  const ushort* wbase = Wb + (size_t)(oc_base + lo) * 3200 + kh * 64 + 8 * lg;

  f32x4 acc[4][4];
#pragma unroll
  for (int g = 0; g < 4; ++g)
#pragma unroll
    for (int j = 0; j < 4; ++j) acc[g][j] = {0.f, 0.f, 0.f, 0.f};

  short8 aA[8], aB[8];   // [g*2+icc], static indexing only

#define LOADW(dst, kkv)                                                        \
  {                                                                            \
    const ushort* _p = wbase + (kkv) * 128;                                    \
    _Pragma("unroll") for (int g = 0; g < 4; ++g)                              \
        _Pragma("unroll") for (int icc = 0; icc < 2; ++icc)                    \
            dst[g * 2 + icc] = *(const short8*)(_p + (size_t)g * 51200 + icc * 32); \
  }

#define COMPUTE(arr, kkv)                                                      \
  {                                                                            \
    int _ky = (kkv) / 5, _kx = (kkv) - 5 * _ky;                                \
    _Pragma("unroll") for (int icc = 0; icc < 2; ++icc) {                      \
      short8 bf[4];                                                            \
      _Pragma("unroll") for (int j = 0; j < 4; ++j) {                          \
        int px = ((j >> 1) + _ky) * 36 + (j & 1) * 16 + lo + _kx;              \
        bf[j] = *(const short8*)(lds + px * ICP + icc * 32 + 8 * lg);          \
      }                                                                        \
      _Pragma("unroll") for (int g = 0; g < 4; ++g)                            \
          _Pragma("unroll") for (int j = 0; j < 4; ++j)                        \
              acc[g][j] = __builtin_amdgcn_mfma_f32_16x16x32_bf16(             \
                  arr[g * 2 + icc], bf[j], acc[g][j], 0, 0, 0);                \
    }                                                                          \
  }

  LOADW(aA, 0);
  for (int kk2 = 0; kk2 < 12; ++kk2) {
    int kk = 2 * kk2;
    LOADW(aB, kk + 1);
    COMPUTE(aA, kk);
    LOADW(aA, kk + 2);
    COMPUTE(aB, kk + 1);
  }
  COMPUTE(aA, 24);
#undef LOADW
#undef COMPUTE

  float* gp = kh ? gates1 : gates0;
#pragma unroll
  for (int g = 0; g < 4; ++g)
#pragma unroll
    for (int j = 0; j < 4; ++j)
#pragma unroll
      for (int r = 0; r < 4; ++r) {
        int oc = oc_base + g * 16 + lg * 4 + r;
        int p  = y0 * 32 + (j >> 1) * 32 + (j & 1) * 16 + lo;
        gp[(size_t)(b * 256 + oc) * NTOK + p] = acc[g][j][r];
      }
}

// ---- gates halves + bias -> c_new, h_new
__global__ __launch_bounds__(256) void lstm_kernel(
    const float* __restrict__ g0, const float* __restrict__ g1,
    const float* __restrict__ bias, const float* __restrict__ c_in,
    float* __restrict__ c_out, float* __restrict__ h_out) {
  size_t idx = (size_t)blockIdx.x * 256 + threadIdx.x;
  size_t b = idx >> 16;
  size_t r = idx & 65535;
  int ocr = (int)(r >> 10);            // uniform per block
  size_t gbo = b * (size_t)(256 * NTOK);
  float iv = g0[gbo + r]          + g1[gbo + r]          + bias[ocr];
  float fv = g0[gbo + 65536 + r]  + g1[gbo + 65536 + r]  + bias[64 + ocr];
  float ov = g0[gbo + 131072 + r] + g1[gbo + 131072 + r] + bias[128 + ocr];
  float gv = g0[gbo + 196608 + r] + g1[gbo + 196608 + r] + bias[192 + ocr];
  iv = 1.f / (1.f + expf(-iv));
  fv = 1.f / (1.f + expf(-fv));
  ov = 1.f / (1.f + expf(-ov));
  gv = tanhf(gv);
  float cn = fv * c_in[idx] + iv * gv;
  c_out[idx] = cn;
  h_out[idx] = ov * tanhf(cn);
}

extern "C" void kernel_launch(void* const* d_in, const int* in_sizes, int n_in,
                              void* d_out, int out_size, void* d_ws, size_t ws_size,
                              hipStream_t stream) {
  const float* x      = (const float*)d_in[0];
  const float* h      = (const float*)d_in[1];
  const float* c      = (const float*)d_in[2];
  const float* Wq_x   = (const float*)d_in[3];
  const float* Wk_x   = (const float*)d_in[4];
  const float* Wv_x   = (const float*)d_in[5];
  const float* Wq_h   = (const float*)d_in[6];
  const float* Wk_h   = (const float*)d_in[7];
  const float* Wv_h   = (const float*)d_in[8];
  const float* W_lstm = (const float*)d_in[9];
  const float* b_lstm = (const float*)d_in[10];

  float* out   = (float*)d_out;
  float* new_h = out;                 // [16,64,32,32]
  float* new_c = out + 1048576;       // [16,64,32,32]
  float* atten = out + 2097152;       // [16,1024,1024]

  // ws layout (ushort granularity, ~8.4 MB of proven-available 12.4 MB)
  ushort* wsu = (ushort*)d_ws;
  ushort* qT  = wsu;                  //   524,288 ushort [b][n][32]
  ushort* kT  = wsu + 524288;         //   524,288
  ushort* vb  = wsu + 1048576;        // 1,048,576 [b][c][m]
  ushort* XbT = wsu + 2097152;        // 1,048,576 token-major [b][n][64] (conv in)
  ushort* xT  = wsu + 3145728;        // 1,048,576 [b][n][64] (x, later h_mid)
  ushort* wqb = wsu + 4194304;        //     2,048
  ushort* wkb = wsu + 4196352;        //     2,048
  ushort* wvb = wsu + 4198400;        //     4,096

  // scratch aliased into the atten output region (dead until scores2):
  ushort* ab1    = (ushort*)atten;               // attn1 bf16 [b][n][m], bytes [0,32M)
  float*  gates0 = atten;                        // conv kh=0, bytes [0,16M)
  float*  gates1 = atten + 4194304;              // conv kh=1, bytes [16M,32M)
  ushort* Wb     = (ushort*)(atten + 8388608);   // conv weights bf16, bytes [32M,33.6M)
  ushort* hbT    = (ushort*)(atten + 9437184);   // h bf16 token-major [b][n][64]
  float*  h_mid  = new_h;                        // lstm h lives in new_h slot

  dim3 blk(256);
  // ---- attention 1 on x ----
  tpose_bf16_kernel<<<dim3(16, NB), blk, 0, stream>>>(x, xT);
  wqkv_pre_kernel<<<16, blk, 0, stream>>>(Wq_x, Wk_x, Wv_x, wqb, wkb, wvb);
  qkproj_kernel<<<dim3(16, NB), blk, 0, stream>>>(xT, wqb, wkb, qT, kT);
  vproj_kernel<<<dim3(16, NB), blk, 0, stream>>>(xT, wvb, vb);
  scores_softmax_kernel<false><<<dim3(64, NB), blk, 0, stream>>>(qT, kT, nullptr, ab1);
  aggregate_mfma_kernel<true><<<dim3(16, NB), blk, 0, stream>>>(
      vb, ab1, nullptr, x, nullptr, XbT, 1.0f);
  // ---- conv-lstm (bf16 MFMA implicit GEMM, K-split) ----
  wpre_kernel<<<128, blk, 0, stream>>>(W_lstm, Wb);
  tpose_bf16_kernel<<<dim3(16, NB), blk, 0, stream>>>(h, hbT);
  conv_mfma_kernel<<<dim3(16, 2, NB), blk, 0, stream>>>(XbT, hbT, Wb, gates0, gates1);
  lstm_kernel<<<4096, blk, 0, stream>>>(gates0, gates1, b_lstm, c, new_c, h_mid);
  // ---- attention 2 on h_mid (atten f32 is a real output) ----
  tpose_bf16_kernel<<<dim3(16, NB), blk, 0, stream>>>(h_mid, xT);
  wqkv_pre_kernel<<<16, blk, 0, stream>>>(Wq_h, Wk_h, Wv_h, wqb, wkb, wvb);
  qkproj_kernel<<<dim3(16, NB), blk, 0, stream>>>(xT, wqb, wkb, qT, kT);
  vproj_kernel<<<dim3(16, NB), blk, 0, stream>>>(xT, wvb, vb);
  scores_softmax_kernel<true><<<dim3(64, NB), blk, 0, stream>>>(qT, kT, atten, nullptr);
  aggregate_mfma_kernel<false><<<dim3(16, NB), blk, 0, stream>>>(
      vb, nullptr, atten, h_mid, new_h, nullptr, 2.0f);
}

// Round 7
// 152.354 us; speedup vs baseline: 14.2897x; 1.1207x over previous
//
#include <hip/hip_runtime.h>
#include <hip/hip_bf16.h>
#include <cstddef>
#include <cstdint>

// Problem constants: B=16, CIN=COUT=64, HID=32, H=W=32, K=5, PAD=2
#define NTOK 1024      // H*W
#define NB   16        // batch
#define NC   64        // channels (CIN == COUT)
#define NHID 32        // attention hidden

// padded conv input: pad[b][kh][36*36 px][64 c] bf16
#define PAD_BSTRIDE 165888   // 2*1296*64
#define PAD_KSTRIDE 82944    // 1296*64
#define PAD_BYTES   5308416  // 16 * PAD_BSTRIDE * 2

typedef __attribute__((ext_vector_type(8))) short short8;   // 8 bf16 = 4 VGPR (MFMA A/B frag)
typedef __attribute__((ext_vector_type(4))) float f32x4;    // MFMA acc frag

// round-to-nearest-even f32 -> bf16 (as raw ushort)
__device__ __forceinline__ ushort f2b(float f) {
  uint32_t u = __builtin_bit_cast(uint32_t, f);
  return (ushort)((u + 0x7FFFu + ((u >> 16) & 1u)) >> 16);
}

// ---- transpose + convert: src f32 [b][64c][1024n] -> bf16 token-major.
// padded=false: dst[b][1024n][64c].  padded=true: dst[b-stride PAD_BSTRIDE]
// interior of 36x36 ring (caller pre-offsets dst to the kh half; ring pre-zeroed).
__global__ __launch_bounds__(256) void tpose_bf16_kernel(
    const float* __restrict__ src, ushort* __restrict__ dst, int padded) {
  __shared__ float tile[64][65];
  int t = threadIdx.x;
  int n0 = blockIdx.x * 64, b = blockIdx.y;
  const float* s = src + (size_t)b * NC * NTOK;
#pragma unroll
  for (int r = 0; r < 4; ++r) {
    int c = r * 16 + (t >> 4);
    int nl = (t & 15) * 4;
    float4 v = *(const float4*)(s + (size_t)c * NTOK + n0 + nl);
    tile[c][nl] = v.x; tile[c][nl + 1] = v.y; tile[c][nl + 2] = v.z; tile[c][nl + 3] = v.w;
  }
  __syncthreads();
  int tok = t >> 2, c0 = (t & 3) * 16;
  __attribute__((aligned(16))) ushort tmp[16];
#pragma unroll
  for (int i = 0; i < 16; ++i) tmp[i] = f2b(tile[c0 + i][tok]);
  int gtok = n0 + tok;
  ushort* d;
  if (padded)
    d = dst + (size_t)b * PAD_BSTRIDE + ((gtok >> 5) + 2) * 2304 + ((gtok & 31) + 2) * 64 + c0;
  else
    d = dst + ((size_t)b * NTOK + gtok) * NC + c0;
  *(uint4*)(d)     = *(const uint4*)(tmp);
  *(uint4*)(d + 8) = *(const uint4*)(tmp + 8);
}

// ---- Wq/Wk [32][64] and Wv [64][64] f32 -> bf16 (same layouts). 16 x 256 threads.
__global__ __launch_bounds__(256) void wqkv_pre_kernel(
    const float* __restrict__ Wq, const float* __restrict__ Wk,
    const float* __restrict__ Wv, ushort* __restrict__ wqb,
    ushort* __restrict__ wkb, ushort* __restrict__ wvb) {
  int i = blockIdx.x * 256 + threadIdx.x;
  if (i < 2048) { wqb[i] = f2b(Wq[i]); wkb[i] = f2b(Wk[i]); }
  wvb[i] = f2b(Wv[i]);
}

// ---- q,k projection via MFMA: qT/kT[b][n][32] = xT[b][n][64] x W[32][64]^T
__global__ __launch_bounds__(256) void qkproj_kernel(
    const ushort* __restrict__ xT, const ushort* __restrict__ wqb,
    const ushort* __restrict__ wkb, ushort* __restrict__ qT,
    ushort* __restrict__ kT) {
  __shared__ ushort sq[64][32], sk[64][32];
  int t = threadIdx.x, wave = t >> 6, lane = t & 63;
  int lo = lane & 15, lg = lane >> 4;
  int n0 = blockIdx.x * 64, b = blockIdx.y;
  int nw = n0 + wave * 16;
  const ushort* xrow = xT + ((size_t)b * NTOK + nw + lo) * NC + 8 * lg;
  short8 a0 = *(const short8*)(xrow);        // k = c in [0,32)
  short8 a1 = *(const short8*)(xrow + 32);   // k = c in [32,64)
  f32x4 aq[2], ak[2];
#pragma unroll
  for (int dg = 0; dg < 2; ++dg) {
    const ushort* wq = wqb + (size_t)(dg * 16 + lo) * NC + 8 * lg;
    const ushort* wk = wkb + (size_t)(dg * 16 + lo) * NC + 8 * lg;
    f32x4 z = {0.f, 0.f, 0.f, 0.f};
    aq[dg] = __builtin_amdgcn_mfma_f32_16x16x32_bf16(a0, *(const short8*)(wq), z, 0, 0, 0);
    aq[dg] = __builtin_amdgcn_mfma_f32_16x16x32_bf16(a1, *(const short8*)(wq + 32), aq[dg], 0, 0, 0);
    ak[dg] = __builtin_amdgcn_mfma_f32_16x16x32_bf16(a0, *(const short8*)(wk), z, 0, 0, 0);
    ak[dg] = __builtin_amdgcn_mfma_f32_16x16x32_bf16(a1, *(const short8*)(wk + 32), ak[dg], 0, 0, 0);
  }
#pragma unroll
  for (int dg = 0; dg < 2; ++dg)
#pragma unroll
    for (int r = 0; r < 4; ++r) {
      sq[wave * 16 + 4 * lg + r][dg * 16 + lo] = f2b(aq[dg][r]);
      sk[wave * 16 + 4 * lg + r][dg * 16 + lo] = f2b(ak[dg][r]);
    }
  __syncthreads();
  int tok = t >> 2, d0 = (t & 3) * 8;
  size_t base = ((size_t)b * NTOK + n0 + tok) * NHID + d0;
  *(short8*)(qT + base) = *(const short8*)(&sq[tok][d0]);
  *(short8*)(kT + base) = *(const short8*)(&sk[tok][d0]);
}

// ---- v projection via MFMA: vb[b][64e][1024m] = Wv[64e][64c] x xT[b][m][64c]^T
__global__ __launch_bounds__(256) void vproj_kernel(
    const ushort* __restrict__ xT, const ushort* __restrict__ wvb,
    ushort* __restrict__ vb) {
  int t = threadIdx.x, wave = t >> 6, lane = t & 63;
  int lo = lane & 15, lg = lane >> 4;
  int n0 = blockIdx.x * 64, b = blockIdx.y;
  int n = n0 + wave * 16 + lo;
  const ushort* xrow = xT + ((size_t)b * NTOK + n) * NC + 8 * lg;
  short8 b0 = *(const short8*)(xrow);
  short8 b1 = *(const short8*)(xrow + 32);
  f32x4 acc[4];
#pragma unroll
  for (int g = 0; g < 4; ++g) {
    const ushort* wv = wvb + (size_t)(g * 16 + lo) * NC + 8 * lg;
    f32x4 z = {0.f, 0.f, 0.f, 0.f};
    acc[g] = __builtin_amdgcn_mfma_f32_16x16x32_bf16(*(const short8*)(wv), b0, z, 0, 0, 0);
    acc[g] = __builtin_amdgcn_mfma_f32_16x16x32_bf16(*(const short8*)(wv + 32), b1, acc[g], 0, 0, 0);
  }
  ushort* vbase = vb + (size_t)b * NC * NTOK + n0 + wave * 16 + lo;
#pragma unroll
  for (int g = 0; g < 4; ++g)
#pragma unroll
    for (int r = 0; r < 4; ++r)
      vbase[(size_t)(g * 16 + lg * 4 + r) * NTOK] = f2b(acc[g][r]);
}

// ---- scores + softmax, MFMA. One wg (4 waves) per 16 n-rows.
template <bool F32OUT>
__global__ __launch_bounds__(256) void scores_softmax_kernel(
    const ushort* __restrict__ qT, const ushort* __restrict__ kT,
    float* __restrict__ attnf, ushort* __restrict__ attnb) {
  __shared__ float wmax[4][16], wsum[4][16];
  int t = threadIdx.x, wave = t >> 6, lane = t & 63;
  int lo = lane & 15, lg = lane >> 4;
  int n0 = blockIdx.x * 16, b = blockIdx.y;
  int m0 = wave * 256;
  short8 a = *(const short8*)(qT + ((size_t)b * NTOK + n0 + lo) * NHID + 8 * lg);
  f32x4 acc[16];
#pragma unroll
  for (int j = 0; j < 16; ++j) {
    short8 bf = *(const short8*)(kT + ((size_t)b * NTOK + m0 + j * 16 + lo) * NHID + 8 * lg);
    f32x4 z = {0.f, 0.f, 0.f, 0.f};
    acc[j] = __builtin_amdgcn_mfma_f32_16x16x32_bf16(a, bf, z, 0, 0, 0);
  }
  float pm[4];
#pragma unroll
  for (int r = 0; r < 4; ++r) {
    float m = acc[0][r];
#pragma unroll
    for (int j = 1; j < 16; ++j) m = fmaxf(m, acc[j][r]);
#pragma unroll
    for (int off = 1; off < 16; off <<= 1) m = fmaxf(m, __shfl_xor(m, off, 64));
    pm[r] = m;
  }
  if (lo == 0)
#pragma unroll
    for (int r = 0; r < 4; ++r) wmax[wave][4 * lg + r] = pm[r];
  __syncthreads();
  float mr[4];
#pragma unroll
  for (int r = 0; r < 4; ++r)
    mr[r] = fmaxf(fmaxf(wmax[0][4 * lg + r], wmax[1][4 * lg + r]),
                  fmaxf(wmax[2][4 * lg + r], wmax[3][4 * lg + r]));
  float ps[4] = {0.f, 0.f, 0.f, 0.f};
#pragma unroll
  for (int j = 0; j < 16; ++j)
#pragma unroll
    for (int r = 0; r < 4; ++r) {
      float e = __expf(acc[j][r] - mr[r]);
      acc[j][r] = e;
      ps[r] += e;
    }
#pragma unroll
  for (int r = 0; r < 4; ++r)
#pragma unroll
    for (int off = 1; off < 16; off <<= 1) ps[r] += __shfl_xor(ps[r], off, 64);
  if (lo == 0)
#pragma unroll
    for (int r = 0; r < 4; ++r) wsum[wave][4 * lg + r] = ps[r];
  __syncthreads();
  float inv[4];
#pragma unroll
  for (int r = 0; r < 4; ++r)
    inv[r] = 1.f / (wsum[0][4 * lg + r] + wsum[1][4 * lg + r] +
                    wsum[2][4 * lg + r] + wsum[3][4 * lg + r]);
#pragma unroll
  for (int j = 0; j < 16; ++j)
#pragma unroll
    for (int r = 0; r < 4; ++r) {
      size_t idx = ((size_t)b * NTOK + n0 + 4 * lg + r) * NTOK + m0 + j * 16 + lo;
      float val = acc[j][r] * inv[r];
      if constexpr (F32OUT) attnf[idx] = val;
      else                  attnb[idx] = f2b(val);
    }
}

// ---- MFMA aggregate, 4-wave m-split: out = scale*(resid + V.attn^T)
// outb != nullptr (agg1): write bf16 into PADDED conv-input interior (kh0 base).
// else (agg2): f32 [b][c][n].
template <bool BF16B>
__global__ __launch_bounds__(256) void aggregate_mfma_kernel(
    const ushort* __restrict__ vb, const ushort* __restrict__ abf,
    const float* __restrict__ af32, const float* __restrict__ resid,
    float* __restrict__ outf, ushort* __restrict__ outb, float scale) {
  __shared__ float red[4 * 64 * 66];   // [wave][c][n], n-pitch 66
  int t = threadIdx.x, wave = t >> 6, lane = t & 63;
  int lo = lane & 15, lg = lane >> 4;
  int n0 = blockIdx.x * 64, b = blockIdx.y;
  const ushort* V = vb + (size_t)b * NC * NTOK;
  const ushort* Ab = BF16B ? abf + ((size_t)b * NTOK + n0) * NTOK : nullptr;
  const float*  Af = BF16B ? nullptr : af32 + ((size_t)b * NTOK + n0) * NTOK;
  int mbase = wave * 256;

  f32x4 acc[4][4];
#pragma unroll
  for (int i = 0; i < 4; ++i)
#pragma unroll
    for (int j = 0; j < 4; ++j) acc[i][j] = {0.f, 0.f, 0.f, 0.f};

  for (int m0 = 0; m0 < 256; m0 += 32) {
    int mk = mbase + m0 + 8 * lg;
    short8 a[4], bf[4];
#pragma unroll
    for (int g = 0; g < 4; ++g)
      a[g] = *(const short8*)(V + (size_t)(g * 16 + lo) * NTOK + mk);
    if constexpr (BF16B) {
#pragma unroll
      for (int g = 0; g < 4; ++g)
        bf[g] = *(const short8*)(Ab + (size_t)(g * 16 + lo) * NTOK + mk);
    } else {
#pragma unroll
      for (int g = 0; g < 4; ++g) {
        const float* p = Af + (size_t)(g * 16 + lo) * NTOK + mk;
        float4 f0 = *(const float4*)(p);
        float4 f1 = *(const float4*)(p + 4);
        short8 r;
        r[0] = (short)f2b(f0.x); r[1] = (short)f2b(f0.y);
        r[2] = (short)f2b(f0.z); r[3] = (short)f2b(f0.w);
        r[4] = (short)f2b(f1.x); r[5] = (short)f2b(f1.y);
        r[6] = (short)f2b(f1.z); r[7] = (short)f2b(f1.w);
        bf[g] = r;
      }
    }
#pragma unroll
    for (int i = 0; i < 4; ++i)
#pragma unroll
      for (int j = 0; j < 4; ++j)
        acc[i][j] = __builtin_amdgcn_mfma_f32_16x16x32_bf16(a[i], bf[j], acc[i][j], 0, 0, 0);
  }
#pragma unroll
  for (int i = 0; i < 4; ++i)
#pragma unroll
    for (int j = 0; j < 4; ++j)
#pragma unroll
      for (int r = 0; r < 4; ++r)
        red[(wave * 64 + i * 16 + lg * 4 + r) * 66 + j * 16 + lo] = acc[i][j][r];
  __syncthreads();
  int c = t >> 2, nb = (t & 3) * 16;
#pragma unroll
  for (int i = 0; i < 16; ++i) {
    int n = nb + i;
    float s = red[(c) * 66 + n] + red[(64 + c) * 66 + n] +
              red[(128 + c) * 66 + n] + red[(192 + c) * 66 + n];
    size_t idx = ((size_t)b * NC + c) * NTOK + n0 + n;
    float val = scale * (resid[idx] + s);
    if (outb) {
      int tok = n0 + n;
      outb[(size_t)b * PAD_BSTRIDE + ((tok >> 5) + 2) * 2304 + ((tok & 31) + 2) * 64 + c] = f2b(val);
    } else {
      outf[idx] = val;
    }
  }
}

// ---- conv weight pre-pass: W_lstm[oc][ic][5][5] f32 -> Wb[oc][25][128] bf16
__global__ __launch_bounds__(256) void wpre_kernel(
    const float* __restrict__ W, ushort* __restrict__ Wb) {
  int idx = blockIdx.x * 256 + threadIdx.x;
  int oc = idx >> 7, ic = idx & 127;
  const float* src = W + (size_t)idx * 25;
#pragma unroll
  for (int kk = 0; kk < 25; ++kk)
    Wb[((size_t)oc * 25 + kk) * 128 + ic] = f2b(src[kk]);
}

// ---- implicit-GEMM conv, GEMM-tiled: wg = 8 waves = 256 oc x 128 px (4 rows),
// K-loop = 25 taps x 64 ic (kh halves in grid). Weights: reg-prefetch next tap
// during MFMA, ds_write into shared A-tile (32KB) after barrier. Input window
// (8 rows x 36 x 64ic) staged once from the pre-padded buffer (branch-free).
// Pitch 76 (152B stride = 6 banks mod 32): conflict-free frag reads.
// Grid (8 ptile, 2 kh, 16 b) = 256 wgs. Gate halves summed in lstm_kernel.
#define AP 76
#define BP 76
__global__ __launch_bounds__(512, 2) void conv_mfma_kernel(
    const ushort* __restrict__ pad,   // [b][2][36*36][64] bf16
    const ushort* __restrict__ Wb,    // [256 oc][25 kk][128 ic] bf16
    float* __restrict__ gates0, float* __restrict__ gates1) {
  __shared__ ushort ldsA[256 * AP];   // [oc][64 ic], pitch 76
  __shared__ ushort ldsB[288 * BP];   // [8 rows x 36 cols][64 ic], pitch 76
  int t = threadIdx.x;
  int lane = t & 63, lo = lane & 15, lg = lane >> 4;
  int wid = t >> 6, oc_g = wid & 3, px_g = wid >> 2;
  int rp = blockIdx.x, kh = blockIdx.y, b = blockIdx.z;
  const ushort* padKH = pad + (size_t)b * PAD_BSTRIDE + (size_t)kh * PAD_KSTRIDE
                        + (size_t)(rp * 4) * 2304;   // window rows rp*4 .. rp*4+7

  // stage B window: 288 px x 64 ic (contiguous source, pre-padded zeros)
  for (int i = t; i < 2304; i += 512) {
    int pxw = i >> 3, ch8 = (i & 7) * 8;
    uint4 v = *(const uint4*)(padKH + (size_t)pxw * 64 + ch8);
    *(uint4*)(ldsB + pxw * BP + ch8) = v;
  }

  // per-thread A staging addresses (4 x 16B chunks cover 256oc x 64ic)
  const ushort* wsrc0; const ushort* wsrc1; const ushort* wsrc2; const ushort* wsrc3;
  int adst[4];
  {
    int idx0 = t, idx1 = 512 + t, idx2 = 1024 + t, idx3 = 1536 + t;
    wsrc0 = Wb + (size_t)(idx0 >> 3) * 3200 + kh * 64 + (idx0 & 7) * 8;
    wsrc1 = Wb + (size_t)(idx1 >> 3) * 3200 + kh * 64 + (idx1 & 7) * 8;
    wsrc2 = Wb + (size_t)(idx2 >> 3) * 3200 + kh * 64 + (idx2 & 7) * 8;
    wsrc3 = Wb + (size_t)(idx3 >> 3) * 3200 + kh * 64 + (idx3 & 7) * 8;
    adst[0] = (idx0 >> 3) * AP + (idx0 & 7) * 8;
    adst[1] = (idx1 >> 3) * AP + (idx1 & 7) * 8;
    adst[2] = (idx2 >> 3) * AP + (idx2 & 7) * 8;
    adst[3] = (idx3 >> 3) * AP + (idx3 & 7) * 8;
  }
  uint4 w0 = *(const uint4*)(wsrc0);
  uint4 w1 = *(const uint4*)(wsrc1);
  uint4 w2 = *(const uint4*)(wsrc2);
  uint4 w3 = *(const uint4*)(wsrc3);

  f32x4 acc[4][4];
#pragma unroll
  for (int i = 0; i < 4; ++i)
#pragma unroll
    for (int j = 0; j < 4; ++j) acc[i][j] = {0.f, 0.f, 0.f, 0.f};

  __syncthreads();   // B ready; safe to write A

  for (int kk = 0; kk < 25; ++kk) {
    // commit tap kk weights to LDS
    *(uint4*)(ldsA + adst[0]) = w0;
    *(uint4*)(ldsA + adst[1]) = w1;
    *(uint4*)(ldsA + adst[2]) = w2;
    *(uint4*)(ldsA + adst[3]) = w3;
    // prefetch tap kk+1 (last iter re-loads tap 24, harmless)
    int kkn = (kk < 24) ? kk + 1 : 24;
    w0 = *(const uint4*)(wsrc0 + kkn * 128);
    w1 = *(const uint4*)(wsrc1 + kkn * 128);
    w2 = *(const uint4*)(wsrc2 + kkn * 128);
    w3 = *(const uint4*)(wsrc3 + kkn * 128);
    __syncthreads();  // A ready
    int ky = kk / 5, kx = kk - 5 * ky;
    int tapoff = (ky * 36 + kx) * BP;
#pragma unroll
    for (int icc = 0; icc < 2; ++icc) {
      short8 af[4], bf[4];
#pragma unroll
      for (int i = 0; i < 4; ++i)
        af[i] = *(const short8*)(ldsA + (oc_g * 64 + i * 16 + lo) * AP + icc * 32 + 8 * lg);
#pragma unroll
      for (int j = 0; j < 4; ++j) {
        int pxw = (px_g * 2 + (j >> 1)) * 36 + (j & 1) * 16 + lo;
        bf[j] = *(const short8*)(ldsB + tapoff + pxw * BP + icc * 32 + 8 * lg);
      }
#pragma unroll
      for (int i = 0; i < 4; ++i)
#pragma unroll
        for (int j = 0; j < 4; ++j)
          acc[i][j] = __builtin_amdgcn_mfma_f32_16x16x32_bf16(af[i], bf[j], acc[i][j], 0, 0, 0);
    }
    __syncthreads();  // all frag reads done before next tap's A writes
  }

  float* gp = kh ? gates1 : gates0;
#pragma unroll
  for (int i = 0; i < 4; ++i)
#pragma unroll
    for (int j = 0; j < 4; ++j)
#pragma unroll
      for (int r = 0; r < 4; ++r) {
        int oc = oc_g * 64 + i * 16 + lg * 4 + r;
        int p  = rp * 128 + px_g * 64 + j * 16 + lo;
        gp[(size_t)(b * 256 + oc) * NTOK + p] = acc[i][j][r];
      }
}

// ---- gates halves + bias -> c_new, h_new
__global__ __launch_bounds__(256) void lstm_kernel(
    const float* __restrict__ g0, const float* __restrict__ g1,
    const float* __restrict__ bias, const float* __restrict__ c_in,
    float* __restrict__ c_out, float* __restrict__ h_out) {
  size_t idx = (size_t)blockIdx.x * 256 + threadIdx.x;
  size_t b = idx >> 16;
  size_t r = idx & 65535;
  int ocr = (int)(r >> 10);            // uniform per block
  size_t gbo = b * (size_t)(256 * NTOK);
  float iv = g0[gbo + r]          + g1[gbo + r]          + bias[ocr];
  float fv = g0[gbo + 65536 + r]  + g1[gbo + 65536 + r]  + bias[64 + ocr];
  float ov = g0[gbo + 131072 + r] + g1[gbo + 131072 + r] + bias[128 + ocr];
  float gv = g0[gbo + 196608 + r] + g1[gbo + 196608 + r] + bias[192 + ocr];
  iv = 1.f / (1.f + expf(-iv));
  fv = 1.f / (1.f + expf(-fv));
  ov = 1.f / (1.f + expf(-ov));
  gv = tanhf(gv);
  float cn = fv * c_in[idx] + iv * gv;
  c_out[idx] = cn;
  h_out[idx] = ov * tanhf(cn);
}

extern "C" void kernel_launch(void* const* d_in, const int* in_sizes, int n_in,
                              void* d_out, int out_size, void* d_ws, size_t ws_size,
                              hipStream_t stream) {
  const float* x      = (const float*)d_in[0];
  const float* h      = (const float*)d_in[1];
  const float* c      = (const float*)d_in[2];
  const float* Wq_x   = (const float*)d_in[3];
  const float* Wk_x   = (const float*)d_in[4];
  const float* Wv_x   = (const float*)d_in[5];
  const float* Wq_h   = (const float*)d_in[6];
  const float* Wk_h   = (const float*)d_in[7];
  const float* Wv_h   = (const float*)d_in[8];
  const float* W_lstm = (const float*)d_in[9];
  const float* b_lstm = (const float*)d_in[10];

  float* out   = (float*)d_out;
  float* new_h = out;                 // [16,64,32,32]
  float* new_c = out + 1048576;       // [16,64,32,32]
  float* atten = out + 2097152;       // [16,1024,1024]

  // ws layout (ushort granularity)
  ushort* wsu = (ushort*)d_ws;
  ushort* qT  = wsu;                  //   524,288 ushort [b][n][32]
  ushort* kT  = wsu + 524288;         //   524,288
  ushort* vb  = wsu + 1048576;        // 1,048,576 [b][c][m]
  ushort* xT  = wsu + 2097152;        // 1,048,576 [b][n][64] (x / h_mid token-major)
  ushort* wqb = wsu + 3145728;        //     2,048
  ushort* wkb = wsu + 3147776;        //     2,048
  ushort* wvb = wsu + 3149824;        //     4,096

  // scratch aliased into the atten output region (dead until scores2):
  ushort* ab1    = (ushort*)atten;               // attn1 bf16 [b][n][m], bytes [0,33.55M)
  float*  gates0 = atten;                        // conv kh=0, bytes [0,16.8M)
  float*  gates1 = atten + 4194304;              // conv kh=1, bytes [16.8M,33.55M)
  ushort* Wb     = (ushort*)(atten + 8388608);   // conv weights bf16, bytes [33.55M,35.2M)
  ushort* pad    = (ushort*)(atten + 9437184);   // padded conv input, bytes [37.7M,43.1M)
  float*  h_mid  = new_h;                        // lstm h lives in new_h slot

  dim3 blk(256);
  // zero the padded conv-input ring (interiors overwritten below)
  hipMemsetAsync(pad, 0, PAD_BYTES, stream);
  // ---- attention 1 on x ----
  tpose_bf16_kernel<<<dim3(16, NB), blk, 0, stream>>>(x, xT, 0);
  wqkv_pre_kernel<<<16, blk, 0, stream>>>(Wq_x, Wk_x, Wv_x, wqb, wkb, wvb);
  qkproj_kernel<<<dim3(16, NB), blk, 0, stream>>>(xT, wqb, wkb, qT, kT);
  vproj_kernel<<<dim3(16, NB), blk, 0, stream>>>(xT, wvb, vb);
  scores_softmax_kernel<false><<<dim3(64, NB), blk, 0, stream>>>(qT, kT, nullptr, ab1);
  aggregate_mfma_kernel<true><<<dim3(16, NB), blk, 0, stream>>>(
      vb, ab1, nullptr, x, nullptr, pad /*kh0 interior*/, 1.0f);
  // ---- conv-lstm (bf16 MFMA implicit GEMM, GEMM-tiled) ----
  wpre_kernel<<<128, blk, 0, stream>>>(W_lstm, Wb);
  tpose_bf16_kernel<<<dim3(16, NB), blk, 0, stream>>>(h, pad + PAD_KSTRIDE, 1);
  conv_mfma_kernel<<<dim3(8, 2, NB), 512, 0, stream>>>(pad, Wb, gates0, gates1);
  lstm_kernel<<<4096, blk, 0, stream>>>(gates0, gates1, b_lstm, c, new_c, h_mid);
  // ---- attention 2 on h_mid (atten f32 is a real output) ----
  tpose_bf16_kernel<<<dim3(16, NB), blk, 0, stream>>>(h_mid, xT, 0);
  wqkv_pre_kernel<<<16, blk, 0, stream>>>(Wq_h, Wk_h, Wv_h, wqb, wkb, wvb);
  qkproj_kernel<<<dim3(16, NB), blk, 0, stream>>>(xT, wqb, wkb, qT, kT);
  vproj_kernel<<<dim3(16, NB), blk, 0, stream>>>(xT, wvb, vb);
  scores_softmax_kernel<true><<<dim3(64, NB), blk, 0, stream>>>(qT, kT, atten, nullptr);
  aggregate_mfma_kernel<false><<<dim3(16, NB), blk, 0, stream>>>(
      vb, nullptr, atten, h_mid, new_h, nullptr, 2.0f);
}

// Round 8
// 137.579 us; speedup vs baseline: 15.8242x; 1.1074x over previous
//
#include <hip/hip_runtime.h>
#include <hip/hip_bf16.h>
#include <cstddef>
#include <cstdint>

// Problem constants: B=16, CIN=COUT=64, HID=32, H=W=32, K=5, PAD=2
#define NTOK 1024      // H*W
#define NB   16        // batch
#define NC   64        // channels (CIN == COUT)
#define NHID 32        // attention hidden

// padded conv input: pad[b][kh][36*36 px][64 c] bf16
#define PAD_BSTRIDE 165888   // 2*1296*64
#define PAD_KSTRIDE 82944    // 1296*64
#define PAD_BYTES   5308416  // 16 * PAD_BSTRIDE * 2

typedef __attribute__((ext_vector_type(8))) short short8;   // 8 bf16 = 4 VGPR (MFMA A/B frag)
typedef __attribute__((ext_vector_type(4))) float f32x4;    // MFMA acc frag

// round-to-nearest-even f32 -> bf16 (as raw ushort)
__device__ __forceinline__ ushort f2b(float f) {
  uint32_t u = __builtin_bit_cast(uint32_t, f);
  return (ushort)((u + 0x7FFFu + ((u >> 16) & 1u)) >> 16);
}

// ---- transpose + convert: src f32 [b][64c][1024n] -> bf16 token-major.
// padded=0: dst[b][1024n][64c].  padded=1: interior of 36x36 ring (kh half
// pre-offset by caller; ring pre-zeroed).
__global__ __launch_bounds__(256) void tpose_bf16_kernel(
    const float* __restrict__ src, ushort* __restrict__ dst, int padded) {
  __shared__ float tile[64][65];
  int t = threadIdx.x;
  int n0 = blockIdx.x * 64, b = blockIdx.y;
  const float* s = src + (size_t)b * NC * NTOK;
#pragma unroll
  for (int r = 0; r < 4; ++r) {
    int c = r * 16 + (t >> 4);
    int nl = (t & 15) * 4;
    float4 v = *(const float4*)(s + (size_t)c * NTOK + n0 + nl);
    tile[c][nl] = v.x; tile[c][nl + 1] = v.y; tile[c][nl + 2] = v.z; tile[c][nl + 3] = v.w;
  }
  __syncthreads();
  int tok = t >> 2, c0 = (t & 3) * 16;
  __attribute__((aligned(16))) ushort tmp[16];
#pragma unroll
  for (int i = 0; i < 16; ++i) tmp[i] = f2b(tile[c0 + i][tok]);
  int gtok = n0 + tok;
  ushort* d;
  if (padded)
    d = dst + (size_t)b * PAD_BSTRIDE + ((gtok >> 5) + 2) * 2304 + ((gtok & 31) + 2) * 64 + c0;
  else
    d = dst + ((size_t)b * NTOK + gtok) * NC + c0;
  *(uint4*)(d)     = *(const uint4*)(tmp);
  *(uint4*)(d + 8) = *(const uint4*)(tmp + 8);
}

// ---- Wq/Wk [32][64] and Wv [64][64] f32 -> bf16. 16 x 256 threads.
__global__ __launch_bounds__(256) void wqkv_pre_kernel(
    const float* __restrict__ Wq, const float* __restrict__ Wk,
    const float* __restrict__ Wv, ushort* __restrict__ wqb,
    ushort* __restrict__ wkb, ushort* __restrict__ wvb) {
  int i = blockIdx.x * 256 + threadIdx.x;
  if (i < 2048) { wqb[i] = f2b(Wq[i]); wkb[i] = f2b(Wk[i]); }
  wvb[i] = f2b(Wv[i]);
}

// ---- fused q,k,v projection via MFMA. qT/kT[b][n][32], vb[b][64e][1024m].
// One wg (4 waves) per 64 tokens; q/k/v share the same xT fragments.
__global__ __launch_bounds__(256) void qkvproj_kernel(
    const ushort* __restrict__ xT, const ushort* __restrict__ wqb,
    const ushort* __restrict__ wkb, const ushort* __restrict__ wvb,
    ushort* __restrict__ qT, ushort* __restrict__ kT, ushort* __restrict__ vb) {
  __shared__ ushort sq[64][32], sk[64][32];
  int t = threadIdx.x, wave = t >> 6, lane = t & 63;
  int lo = lane & 15, lg = lane >> 4;
  int n0 = blockIdx.x * 64, b = blockIdx.y;
  int nw = n0 + wave * 16;
  const ushort* xrow = xT + ((size_t)b * NTOK + nw + lo) * NC + 8 * lg;
  short8 a0 = *(const short8*)(xrow);        // k = c in [0,32)
  short8 a1 = *(const short8*)(xrow + 32);   // k = c in [32,64)
  // q,k: token rows = A operand
  f32x4 aq[2], ak[2];
#pragma unroll
  for (int dg = 0; dg < 2; ++dg) {
    const ushort* wq = wqb + (size_t)(dg * 16 + lo) * NC + 8 * lg;
    const ushort* wk = wkb + (size_t)(dg * 16 + lo) * NC + 8 * lg;
    f32x4 z = {0.f, 0.f, 0.f, 0.f};
    aq[dg] = __builtin_amdgcn_mfma_f32_16x16x32_bf16(a0, *(const short8*)(wq), z, 0, 0, 0);
    aq[dg] = __builtin_amdgcn_mfma_f32_16x16x32_bf16(a1, *(const short8*)(wq + 32), aq[dg], 0, 0, 0);
    ak[dg] = __builtin_amdgcn_mfma_f32_16x16x32_bf16(a0, *(const short8*)(wk), z, 0, 0, 0);
    ak[dg] = __builtin_amdgcn_mfma_f32_16x16x32_bf16(a1, *(const short8*)(wk + 32), ak[dg], 0, 0, 0);
  }
  // v: token cols = B operand, Wv rows = A operand
  f32x4 av[4];
#pragma unroll
  for (int g = 0; g < 4; ++g) {
    const ushort* wv = wvb + (size_t)(g * 16 + lo) * NC + 8 * lg;
    f32x4 z = {0.f, 0.f, 0.f, 0.f};
    av[g] = __builtin_amdgcn_mfma_f32_16x16x32_bf16(*(const short8*)(wv), a0, z, 0, 0, 0);
    av[g] = __builtin_amdgcn_mfma_f32_16x16x32_bf16(*(const short8*)(wv + 32), a1, av[g], 0, 0, 0);
  }
#pragma unroll
  for (int dg = 0; dg < 2; ++dg)
#pragma unroll
    for (int r = 0; r < 4; ++r) {
      sq[wave * 16 + 4 * lg + r][dg * 16 + lo] = f2b(aq[dg][r]);
      sk[wave * 16 + 4 * lg + r][dg * 16 + lo] = f2b(ak[dg][r]);
    }
  ushort* vbase = vb + (size_t)b * NC * NTOK + nw + lo;
#pragma unroll
  for (int g = 0; g < 4; ++g)
#pragma unroll
    for (int r = 0; r < 4; ++r)
      vbase[(size_t)(g * 16 + lg * 4 + r) * NTOK] = f2b(av[g][r]);
  __syncthreads();
  int tok = t >> 2, d0 = (t & 3) * 8;
  size_t base = ((size_t)b * NTOK + n0 + tok) * NHID + d0;
  *(short8*)(qT + base) = *(const short8*)(&sq[tok][d0]);
  *(short8*)(kT + base) = *(const short8*)(&sk[tok][d0]);
}

// ---- FUSED attention: scores (MFMA) -> softmax -> S->bf16 LDS -> PV (MFMA)
// -> residual+scale epilogue. One wg (4 waves) per 16 n-rows x full m=1024.
// ATTN2=false: no attn output; result -> padded conv input (bf16), scale=1.
// ATTN2=true:  attn f32 -> attnf (real output); result -> outf f32, scale=2.
#define SP 1048   // S-LDS pitch (ushorts): bank stride 12 -> <=2-way
template <bool ATTN2>
__global__ __launch_bounds__(256) void attn_fused_kernel(
    const ushort* __restrict__ qT, const ushort* __restrict__ kT,
    const ushort* __restrict__ vb, const float* __restrict__ resid,
    float* __restrict__ attnf, float* __restrict__ outf,
    ushort* __restrict__ outb_pad, float scale) {
  __shared__ ushort s_lds[16 * SP];
  __shared__ float wmax[4][16], wsum[4][16];
  int t = threadIdx.x, wave = t >> 6, lane = t & 63;
  int lo = lane & 15, lg = lane >> 4;
  int n0 = blockIdx.x * 16, b = blockIdx.y;
  int m0 = wave * 256;
  // ---- scores: S[n][m] = sum_d q[n][d] k[m][d], K=32 = one mfma step
  short8 a = *(const short8*)(qT + ((size_t)b * NTOK + n0 + lo) * NHID + 8 * lg);
  f32x4 acc[16];
#pragma unroll
  for (int j = 0; j < 16; ++j) {
    short8 bf = *(const short8*)(kT + ((size_t)b * NTOK + m0 + j * 16 + lo) * NHID + 8 * lg);
    f32x4 z = {0.f, 0.f, 0.f, 0.f};
    acc[j] = __builtin_amdgcn_mfma_f32_16x16x32_bf16(a, bf, z, 0, 0, 0);
  }
  // ---- softmax over m (rows n = 4*lg + r)
  float pm[4];
#pragma unroll
  for (int r = 0; r < 4; ++r) {
    float m = acc[0][r];
#pragma unroll
    for (int j = 1; j < 16; ++j) m = fmaxf(m, acc[j][r]);
#pragma unroll
    for (int off = 1; off < 16; off <<= 1) m = fmaxf(m, __shfl_xor(m, off, 64));
    pm[r] = m;
  }
  if (lo == 0)
#pragma unroll
    for (int r = 0; r < 4; ++r) wmax[wave][4 * lg + r] = pm[r];
  __syncthreads();
  float mr[4];
#pragma unroll
  for (int r = 0; r < 4; ++r)
    mr[r] = fmaxf(fmaxf(wmax[0][4 * lg + r], wmax[1][4 * lg + r]),
                  fmaxf(wmax[2][4 * lg + r], wmax[3][4 * lg + r]));
  float ps[4] = {0.f, 0.f, 0.f, 0.f};
#pragma unroll
  for (int j = 0; j < 16; ++j)
#pragma unroll
    for (int r = 0; r < 4; ++r) {
      float e = __expf(acc[j][r] - mr[r]);
      acc[j][r] = e;
      ps[r] += e;
    }
#pragma unroll
  for (int r = 0; r < 4; ++r)
#pragma unroll
    for (int off = 1; off < 16; off <<= 1) ps[r] += __shfl_xor(ps[r], off, 64);
  if (lo == 0)
#pragma unroll
    for (int r = 0; r < 4; ++r) wsum[wave][4 * lg + r] = ps[r];
  __syncthreads();
  float inv[4];
#pragma unroll
  for (int r = 0; r < 4; ++r)
    inv[r] = 1.f / (wsum[0][4 * lg + r] + wsum[1][4 * lg + r] +
                    wsum[2][4 * lg + r] + wsum[3][4 * lg + r]);
  // ---- normalized probs -> bf16 S-LDS (+ f32 atten out for attn2)
#pragma unroll
  for (int j = 0; j < 16; ++j)
#pragma unroll
    for (int r = 0; r < 4; ++r) {
      float val = acc[j][r] * inv[r];
      int n = 4 * lg + r, m = m0 + j * 16 + lo;
      s_lds[n * SP + m] = f2b(val);
      if constexpr (ATTN2)
        attnf[((size_t)b * NTOK + n0 + n) * NTOK + m] = val;
    }
  __syncthreads();
  // ---- PV: out[n][c] = sum_m S[n][m] v[c][m]; wave owns c-block wave*16
  int cb = wave * 16;
  const ushort* vbb = vb + ((size_t)b * NC + cb + lo) * NTOK;
  f32x4 acc2 = {0.f, 0.f, 0.f, 0.f};
  for (int ms = 0; ms < NTOK; ms += 32) {
    short8 af = *(const short8*)(s_lds + lo * SP + ms + 8 * lg);   // A row = n
    short8 bf = *(const short8*)(vbb + ms + 8 * lg);               // B col = c
    acc2 = __builtin_amdgcn_mfma_f32_16x16x32_bf16(af, bf, acc2, 0, 0, 0);
  }
  // D: row = n = 4*lg + r, col = c = cb + lo
  int c = cb + lo;
  float4 rv = *(const float4*)(resid + ((size_t)b * NC + c) * NTOK + n0 + 4 * lg);
  float rvv[4] = {rv.x, rv.y, rv.z, rv.w};
  if constexpr (ATTN2) {
    float4 o;
    o.x = scale * (rvv[0] + acc2[0]); o.y = scale * (rvv[1] + acc2[1]);
    o.z = scale * (rvv[2] + acc2[2]); o.w = scale * (rvv[3] + acc2[3]);
    *(float4*)(outf + ((size_t)b * NC + c) * NTOK + n0 + 4 * lg) = o;
  } else {
#pragma unroll
    for (int r = 0; r < 4; ++r) {
      int tok = n0 + 4 * lg + r;
      float val = scale * (rvv[r] + acc2[r]);
      outb_pad[(size_t)b * PAD_BSTRIDE + ((tok >> 5) + 2) * 2304 +
               ((tok & 31) + 2) * 64 + c] = f2b(val);
    }
  }
}

// ---- conv weight pre-pass: W_lstm[oc][ic][5][5] f32 -> Wb[oc][25][128] bf16
__global__ __launch_bounds__(256) void wpre_kernel(
    const float* __restrict__ W, ushort* __restrict__ Wb) {
  int idx = blockIdx.x * 256 + threadIdx.x;
  int oc = idx >> 7, ic = idx & 127;
  const float* src = W + (size_t)idx * 25;
#pragma unroll
  for (int kk = 0; kk < 25; ++kk)
    Wb[((size_t)oc * 25 + kk) * 128 + ic] = f2b(src[kk]);
}

// ---- implicit-GEMM conv, GEMM-tiled, DOUBLE-BUFFERED A: wg = 8 waves =
// 256 oc x 128 px (4 rows), K = 25 taps x 64 ic (kh in grid). One barrier/tap;
// next tap's weights load from L2 under current tap's 64 MFMAs.
#define AP 76
#define BP 76
__global__ __launch_bounds__(512, 1) void conv_mfma_kernel(
    const ushort* __restrict__ pad,   // [b][2][36*36][64] bf16
    const ushort* __restrict__ Wb,    // [256 oc][25 kk][128 ic] bf16
    float* __restrict__ gates0, float* __restrict__ gates1) {
  __shared__ ushort ldsA[2][256 * AP];  // ping-pong [oc][64 ic]
  __shared__ ushort ldsB[288 * BP];     // [8 rows x 36 cols][64 ic]
  int t = threadIdx.x;
  int lane = t & 63, lo = lane & 15, lg = lane >> 4;
  int wid = t >> 6, oc_g = wid & 3, px_g = wid >> 2;
  int rp = blockIdx.x, kh = blockIdx.y, b = blockIdx.z;
  const ushort* padKH = pad + (size_t)b * PAD_BSTRIDE + (size_t)kh * PAD_KSTRIDE
                        + (size_t)(rp * 4) * 2304;

  // stage B window: 288 px x 64 ic (contiguous, pre-padded zeros)
  for (int i = t; i < 2304; i += 512) {
    int pxw = i >> 3, ch8 = (i & 7) * 8;
    uint4 v = *(const uint4*)(padKH + (size_t)pxw * 64 + ch8);
    *(uint4*)(ldsB + pxw * BP + ch8) = v;
  }

  // per-thread A staging addresses (4 x 16B chunks cover 256oc x 64ic)
  const ushort *wsrc0, *wsrc1, *wsrc2, *wsrc3;
  int adst0, adst1, adst2, adst3;
  {
    int i0 = t, i1 = 512 + t, i2 = 1024 + t, i3 = 1536 + t;
    wsrc0 = Wb + (size_t)(i0 >> 3) * 3200 + kh * 64 + (i0 & 7) * 8;
    wsrc1 = Wb + (size_t)(i1 >> 3) * 3200 + kh * 64 + (i1 & 7) * 8;
    wsrc2 = Wb + (size_t)(i2 >> 3) * 3200 + kh * 64 + (i2 & 7) * 8;
    wsrc3 = Wb + (size_t)(i3 >> 3) * 3200 + kh * 64 + (i3 & 7) * 8;
    adst0 = (i0 >> 3) * AP + (i0 & 7) * 8;
    adst1 = (i1 >> 3) * AP + (i1 & 7) * 8;
    adst2 = (i2 >> 3) * AP + (i2 & 7) * 8;
    adst3 = (i3 >> 3) * AP + (i3 & 7) * 8;
  }
  uint4 w0 = *(const uint4*)(wsrc0);
  uint4 w1 = *(const uint4*)(wsrc1);
  uint4 w2 = *(const uint4*)(wsrc2);
  uint4 w3 = *(const uint4*)(wsrc3);

  f32x4 acc[4][4];
#pragma unroll
  for (int i = 0; i < 4; ++i)
#pragma unroll
    for (int j = 0; j < 4; ++j) acc[i][j] = {0.f, 0.f, 0.f, 0.f};

  __syncthreads();            // B staged; safe to write A0
  *(uint4*)(&ldsA[0][adst0]) = w0;
  *(uint4*)(&ldsA[0][adst1]) = w1;
  *(uint4*)(&ldsA[0][adst2]) = w2;
  *(uint4*)(&ldsA[0][adst3]) = w3;
  w0 = *(const uint4*)(wsrc0 + 128);   // tap 1
  w1 = *(const uint4*)(wsrc1 + 128);
  w2 = *(const uint4*)(wsrc2 + 128);
  w3 = *(const uint4*)(wsrc3 + 128);
  __syncthreads();            // A0 ready

  for (int kk = 0; kk < 25; ++kk) {
    int cur = kk & 1;
    if (kk < 24) {
      // commit tap kk+1 into the other buffer (its last readers finished
      // at the barrier ending iteration kk-1), prefetch tap kk+2
      int nxt = cur ^ 1;
      *(uint4*)(&ldsA[nxt][adst0]) = w0;
      *(uint4*)(&ldsA[nxt][adst1]) = w1;
      *(uint4*)(&ldsA[nxt][adst2]) = w2;
      *(uint4*)(&ldsA[nxt][adst3]) = w3;
      int kkn = (kk < 23) ? kk + 2 : 24;
      w0 = *(const uint4*)(wsrc0 + kkn * 128);
      w1 = *(const uint4*)(wsrc1 + kkn * 128);
      w2 = *(const uint4*)(wsrc2 + kkn * 128);
      w3 = *(const uint4*)(wsrc3 + kkn * 128);
    }
    int ky = kk / 5, kx = kk - 5 * ky;
    int tapoff = (ky * 36 + kx) * BP;
#pragma unroll
    for (int icc = 0; icc < 2; ++icc) {
      short8 af[4], bf[4];
#pragma unroll
      for (int i = 0; i < 4; ++i)
        af[i] = *(const short8*)(&ldsA[cur][(oc_g * 64 + i * 16 + lo) * AP + icc * 32 + 8 * lg]);
#pragma unroll
      for (int j = 0; j < 4; ++j) {
        int pxw = (px_g * 2 + (j >> 1)) * 36 + (j & 1) * 16 + lo;
        bf[j] = *(const short8*)(ldsB + tapoff + pxw * BP + icc * 32 + 8 * lg);
      }
#pragma unroll
      for (int i = 0; i < 4; ++i)
#pragma unroll
        for (int j = 0; j < 4; ++j)
          acc[i][j] = __builtin_amdgcn_mfma_f32_16x16x32_bf16(af[i], bf[j], acc[i][j], 0, 0, 0);
    }
    __syncthreads();          // next-tap A writes visible; readers done
  }

  float* gp = kh ? gates1 : gates0;
#pragma unroll
  for (int i = 0; i < 4; ++i)
#pragma unroll
    for (int j = 0; j < 4; ++j)
#pragma unroll
      for (int r = 0; r < 4; ++r) {
        int oc = oc_g * 64 + i * 16 + lg * 4 + r;
        int p  = rp * 128 + px_g * 64 + j * 16 + lo;
        gp[(size_t)(b * 256 + oc) * NTOK + p] = acc[i][j][r];
      }
}

// ---- gates halves + bias -> c_new, h_new
__global__ __launch_bounds__(256) void lstm_kernel(
    const float* __restrict__ g0, const float* __restrict__ g1,
    const float* __restrict__ bias, const float* __restrict__ c_in,
    float* __restrict__ c_out, float* __restrict__ h_out) {
  size_t idx = (size_t)blockIdx.x * 256 + threadIdx.x;
  size_t b = idx >> 16;
  size_t r = idx & 65535;
  int ocr = (int)(r >> 10);            // uniform per block
  size_t gbo = b * (size_t)(256 * NTOK);
  float iv = g0[gbo + r]          + g1[gbo + r]          + bias[ocr];
  float fv = g0[gbo + 65536 + r]  + g1[gbo + 65536 + r]  + bias[64 + ocr];
  float ov = g0[gbo + 131072 + r] + g1[gbo + 131072 + r] + bias[128 + ocr];
  float gv = g0[gbo + 196608 + r] + g1[gbo + 196608 + r] + bias[192 + ocr];
  iv = 1.f / (1.f + expf(-iv));
  fv = 1.f / (1.f + expf(-fv));
  ov = 1.f / (1.f + expf(-ov));
  gv = tanhf(gv);
  float cn = fv * c_in[idx] + iv * gv;
  c_out[idx] = cn;
  h_out[idx] = ov * tanhf(cn);
}

extern "C" void kernel_launch(void* const* d_in, const int* in_sizes, int n_in,
                              void* d_out, int out_size, void* d_ws, size_t ws_size,
                              hipStream_t stream) {
  const float* x      = (const float*)d_in[0];
  const float* h      = (const float*)d_in[1];
  const float* c      = (const float*)d_in[2];
  const float* Wq_x   = (const float*)d_in[3];
  const float* Wk_x   = (const float*)d_in[4];
  const float* Wv_x   = (const float*)d_in[5];
  const float* Wq_h   = (const float*)d_in[6];
  const float* Wk_h   = (const float*)d_in[7];
  const float* Wv_h   = (const float*)d_in[8];
  const float* W_lstm = (const float*)d_in[9];
  const float* b_lstm = (const float*)d_in[10];

  float* out   = (float*)d_out;
  float* new_h = out;                 // [16,64,32,32]
  float* new_c = out + 1048576;       // [16,64,32,32]
  float* atten = out + 2097152;       // [16,1024,1024]

  // ws layout (ushort granularity)
  ushort* wsu = (ushort*)d_ws;
  ushort* qT  = wsu;                  //   524,288 ushort [b][n][32]
  ushort* kT  = wsu + 524288;         //   524,288
  ushort* vb  = wsu + 1048576;        // 1,048,576 [b][c][m]
  ushort* xT  = wsu + 2097152;        // 1,048,576 [b][n][64] (x / h_mid token-major)
  ushort* wqb = wsu + 3145728;        //     2,048
  ushort* wkb = wsu + 3147776;        //     2,048
  ushort* wvb = wsu + 3149824;        //     4,096

  // scratch aliased into the atten output region (dead until attnfused2):
  float*  gates0 = atten;                        // conv kh=0, bytes [0,16.8M)
  float*  gates1 = atten + 4194304;              // conv kh=1, bytes [16.8M,33.55M)
  ushort* Wb     = (ushort*)(atten + 8388608);   // conv weights, bytes [33.55M,35.2M)
  ushort* pad    = (ushort*)(atten + 9437184);   // padded conv input, [37.7M,43.1M)
  float*  h_mid  = new_h;                        // lstm h lives in new_h slot

  dim3 blk(256);
  // zero the padded conv-input ring (interiors overwritten below)
  hipMemsetAsync(pad, 0, PAD_BYTES, stream);
  // ---- attention 1 on x (fused; scores never touch HBM) ----
  tpose_bf16_kernel<<<dim3(16, NB), blk, 0, stream>>>(x, xT, 0);
  wqkv_pre_kernel<<<16, blk, 0, stream>>>(Wq_x, Wk_x, Wv_x, wqb, wkb, wvb);
  qkvproj_kernel<<<dim3(16, NB), blk, 0, stream>>>(xT, wqb, wkb, wvb, qT, kT, vb);
  attn_fused_kernel<false><<<dim3(64, NB), blk, 0, stream>>>(
      qT, kT, vb, x, nullptr, nullptr, pad /*kh0 interior*/, 1.0f);
  // ---- conv-lstm (bf16 MFMA implicit GEMM, dbuf-A) ----
  wpre_kernel<<<128, blk, 0, stream>>>(W_lstm, Wb);
  tpose_bf16_kernel<<<dim3(16, NB), blk, 0, stream>>>(h, pad + PAD_KSTRIDE, 1);
  conv_mfma_kernel<<<dim3(8, 2, NB), 512, 0, stream>>>(pad, Wb, gates0, gates1);
  lstm_kernel<<<4096, blk, 0, stream>>>(gates0, gates1, b_lstm, c, new_c, h_mid);
  // ---- attention 2 on h_mid (atten f32 is a real output) ----
  tpose_bf16_kernel<<<dim3(16, NB), blk, 0, stream>>>(h_mid, xT, 0);
  wqkv_pre_kernel<<<16, blk, 0, stream>>>(Wq_h, Wk_h, Wv_h, wqb, wkb, wvb);
  qkvproj_kernel<<<dim3(16, NB), blk, 0, stream>>>(xT, wqb, wkb, wvb, qT, kT, vb);
  attn_fused_kernel<true><<<dim3(64, NB), blk, 0, stream>>>(
      qT, kT, vb, h_mid, atten, new_h, nullptr, 2.0f);
}

// Round 9
// 131.483 us; speedup vs baseline: 16.5579x; 1.0464x over previous
//
#include <hip/hip_runtime.h>
#include <hip/hip_bf16.h>
#include <cstddef>
#include <cstdint>

// Problem constants: B=16, CIN=COUT=64, HID=32, H=W=32, K=5, PAD=2
#define NTOK 1024      // H*W
#define NB   16        // batch
#define NC   64        // channels (CIN == COUT)
#define NHID 32        // attention hidden

// padded conv input: pad[b][kh][36*36 px][64 c] bf16
#define PAD_BSTRIDE 165888   // 2*1296*64
#define PAD_KSTRIDE 82944    // 1296*64
#define PAD_BYTES   5308416  // 16 * PAD_BSTRIDE * 2

typedef __attribute__((ext_vector_type(8))) short short8;   // 8 bf16 = 4 VGPR (MFMA A/B frag)
typedef __attribute__((ext_vector_type(4))) float f32x4;    // MFMA acc frag

// round-to-nearest-even f32 -> bf16 (as raw ushort)
__device__ __forceinline__ ushort f2b(float f) {
  uint32_t u = __builtin_bit_cast(uint32_t, f);
  return (ushort)((u + 0x7FFFu + ((u >> 16) & 1u)) >> 16);
}
__device__ __forceinline__ float b2f(ushort u) {
  return __builtin_bit_cast(float, (uint32_t)u << 16);
}

// ---- transpose + convert: src f32 [b][64c][1024n] -> bf16 token-major.
// padded=0: dst[b][1024n][64c].  padded=1: interior of 36x36 ring (kh half
// pre-offset by caller; ring pre-zeroed).
__global__ __launch_bounds__(256) void tpose_bf16_kernel(
    const float* __restrict__ src, ushort* __restrict__ dst, int padded) {
  __shared__ float tile[64][65];
  int t = threadIdx.x;
  int n0 = blockIdx.x * 64, b = blockIdx.y;
  const float* s = src + (size_t)b * NC * NTOK;
#pragma unroll
  for (int r = 0; r < 4; ++r) {
    int c = r * 16 + (t >> 4);
    int nl = (t & 15) * 4;
    float4 v = *(const float4*)(s + (size_t)c * NTOK + n0 + nl);
    tile[c][nl] = v.x; tile[c][nl + 1] = v.y; tile[c][nl + 2] = v.z; tile[c][nl + 3] = v.w;
  }
  __syncthreads();
  int tok = t >> 2, c0 = (t & 3) * 16;
  __attribute__((aligned(16))) ushort tmp[16];
#pragma unroll
  for (int i = 0; i < 16; ++i) tmp[i] = f2b(tile[c0 + i][tok]);
  int gtok = n0 + tok;
  ushort* d;
  if (padded)
    d = dst + (size_t)b * PAD_BSTRIDE + ((gtok >> 5) + 2) * 2304 + ((gtok & 31) + 2) * 64 + c0;
  else
    d = dst + ((size_t)b * NTOK + gtok) * NC + c0;
  *(uint4*)(d)     = *(const uint4*)(tmp);
  *(uint4*)(d + 8) = *(const uint4*)(tmp + 8);
}

// ---- Wq/Wk [32][64] and Wv [64][64] f32 -> bf16. 16 x 256 threads.
__global__ __launch_bounds__(256) void wqkv_pre_kernel(
    const float* __restrict__ Wq, const float* __restrict__ Wk,
    const float* __restrict__ Wv, ushort* __restrict__ wqb,
    ushort* __restrict__ wkb, ushort* __restrict__ wvb) {
  int i = blockIdx.x * 256 + threadIdx.x;
  if (i < 2048) { wqb[i] = f2b(Wq[i]); wkb[i] = f2b(Wk[i]); }
  wvb[i] = f2b(Wv[i]);
}

// ---- fused q,k,v projection via MFMA. qT/kT[b][n][32], vb[b][64e][1024m].
__global__ __launch_bounds__(256) void qkvproj_kernel(
    const ushort* __restrict__ xT, const ushort* __restrict__ wqb,
    const ushort* __restrict__ wkb, const ushort* __restrict__ wvb,
    ushort* __restrict__ qT, ushort* __restrict__ kT, ushort* __restrict__ vb) {
  __shared__ ushort sq[64][32], sk[64][32];
  int t = threadIdx.x, wave = t >> 6, lane = t & 63;
  int lo = lane & 15, lg = lane >> 4;
  int n0 = blockIdx.x * 64, b = blockIdx.y;
  int nw = n0 + wave * 16;
  const ushort* xrow = xT + ((size_t)b * NTOK + nw + lo) * NC + 8 * lg;
  short8 a0 = *(const short8*)(xrow);        // k = c in [0,32)
  short8 a1 = *(const short8*)(xrow + 32);   // k = c in [32,64)
  f32x4 aq[2], ak[2];
#pragma unroll
  for (int dg = 0; dg < 2; ++dg) {
    const ushort* wq = wqb + (size_t)(dg * 16 + lo) * NC + 8 * lg;
    const ushort* wk = wkb + (size_t)(dg * 16 + lo) * NC + 8 * lg;
    f32x4 z = {0.f, 0.f, 0.f, 0.f};
    aq[dg] = __builtin_amdgcn_mfma_f32_16x16x32_bf16(a0, *(const short8*)(wq), z, 0, 0, 0);
    aq[dg] = __builtin_amdgcn_mfma_f32_16x16x32_bf16(a1, *(const short8*)(wq + 32), aq[dg], 0, 0, 0);
    ak[dg] = __builtin_amdgcn_mfma_f32_16x16x32_bf16(a0, *(const short8*)(wk), z, 0, 0, 0);
    ak[dg] = __builtin_amdgcn_mfma_f32_16x16x32_bf16(a1, *(const short8*)(wk + 32), ak[dg], 0, 0, 0);
  }
  f32x4 av[4];
#pragma unroll
  for (int g = 0; g < 4; ++g) {
    const ushort* wv = wvb + (size_t)(g * 16 + lo) * NC + 8 * lg;
    f32x4 z = {0.f, 0.f, 0.f, 0.f};
    av[g] = __builtin_amdgcn_mfma_f32_16x16x32_bf16(*(const short8*)(wv), a0, z, 0, 0, 0);
    av[g] = __builtin_amdgcn_mfma_f32_16x16x32_bf16(*(const short8*)(wv + 32), a1, av[g], 0, 0, 0);
  }
#pragma unroll
  for (int dg = 0; dg < 2; ++dg)
#pragma unroll
    for (int r = 0; r < 4; ++r) {
      sq[wave * 16 + 4 * lg + r][dg * 16 + lo] = f2b(aq[dg][r]);
      sk[wave * 16 + 4 * lg + r][dg * 16 + lo] = f2b(ak[dg][r]);
    }
  ushort* vbase = vb + (size_t)b * NC * NTOK + nw + lo;
#pragma unroll
  for (int g = 0; g < 4; ++g)
#pragma unroll
    for (int r = 0; r < 4; ++r)
      vbase[(size_t)(g * 16 + lg * 4 + r) * NTOK] = f2b(av[g][r]);
  __syncthreads();
  int tok = t >> 2, d0 = (t & 3) * 8;
  size_t base = ((size_t)b * NTOK + n0 + tok) * NHID + d0;
  *(short8*)(qT + base) = *(const short8*)(&sq[tok][d0]);
  *(short8*)(kT + base) = *(const short8*)(&sk[tok][d0]);
}

// ---- FUSED attention: scores (MFMA) -> softmax -> S->bf16 LDS -> coalesced
// atten write (ATTN2) -> PV (MFMA, 2-chain) -> residual+scale epilogue.
// One wg (4 waves) per 16 n-rows x full m=1024.
#define SP 1048   // S-LDS pitch (ushorts): bank stride 12 -> <=2-way
template <bool ATTN2>
__global__ __launch_bounds__(256) void attn_fused_kernel(
    const ushort* __restrict__ qT, const ushort* __restrict__ kT,
    const ushort* __restrict__ vb, const float* __restrict__ resid,
    float* __restrict__ attnf, float* __restrict__ outf,
    ushort* __restrict__ outb_pad, float scale) {
  __shared__ ushort s_lds[16 * SP];
  __shared__ float wmax[4][16], wsum[4][16];
  int t = threadIdx.x, wave = t >> 6, lane = t & 63;
  int lo = lane & 15, lg = lane >> 4;
  int n0 = blockIdx.x * 16, b = blockIdx.y;
  int m0 = wave * 256;
  // ---- scores: S[n][m] = sum_d q[n][d] k[m][d], K=32 = one mfma step
  short8 a = *(const short8*)(qT + ((size_t)b * NTOK + n0 + lo) * NHID + 8 * lg);
  f32x4 acc[16];
#pragma unroll
  for (int j = 0; j < 16; ++j) {
    short8 bf = *(const short8*)(kT + ((size_t)b * NTOK + m0 + j * 16 + lo) * NHID + 8 * lg);
    f32x4 z = {0.f, 0.f, 0.f, 0.f};
    acc[j] = __builtin_amdgcn_mfma_f32_16x16x32_bf16(a, bf, z, 0, 0, 0);
  }
  // ---- softmax over m (rows n = 4*lg + r)
  float pm[4];
#pragma unroll
  for (int r = 0; r < 4; ++r) {
    float m = acc[0][r];
#pragma unroll
    for (int j = 1; j < 16; ++j) m = fmaxf(m, acc[j][r]);
#pragma unroll
    for (int off = 1; off < 16; off <<= 1) m = fmaxf(m, __shfl_xor(m, off, 64));
    pm[r] = m;
  }
  if (lo == 0)
#pragma unroll
    for (int r = 0; r < 4; ++r) wmax[wave][4 * lg + r] = pm[r];
  __syncthreads();
  float mr[4];
#pragma unroll
  for (int r = 0; r < 4; ++r)
    mr[r] = fmaxf(fmaxf(wmax[0][4 * lg + r], wmax[1][4 * lg + r]),
                  fmaxf(wmax[2][4 * lg + r], wmax[3][4 * lg + r]));
  float ps[4] = {0.f, 0.f, 0.f, 0.f};
#pragma unroll
  for (int j = 0; j < 16; ++j)
#pragma unroll
    for (int r = 0; r < 4; ++r) {
      float e = __expf(acc[j][r] - mr[r]);
      acc[j][r] = e;
      ps[r] += e;
    }
#pragma unroll
  for (int r = 0; r < 4; ++r)
#pragma unroll
    for (int off = 1; off < 16; off <<= 1) ps[r] += __shfl_xor(ps[r], off, 64);
  if (lo == 0)
#pragma unroll
    for (int r = 0; r < 4; ++r) wsum[wave][4 * lg + r] = ps[r];
  __syncthreads();
  float inv[4];
#pragma unroll
  for (int r = 0; r < 4; ++r)
    inv[r] = 1.f / (wsum[0][4 * lg + r] + wsum[1][4 * lg + r] +
                    wsum[2][4 * lg + r] + wsum[3][4 * lg + r]);
  // ---- normalized probs -> bf16 S-LDS only (no global stores in this loop)
#pragma unroll
  for (int j = 0; j < 16; ++j)
#pragma unroll
    for (int r = 0; r < 4; ++r)
      s_lds[(4 * lg + r) * SP + m0 + j * 16 + lo] = f2b(acc[j][r] * inv[r]);
  __syncthreads();
  // ---- coalesced atten f32 write from S-LDS (wave-contiguous 1KB/instr)
  if constexpr (ATTN2) {
    int ml = lane * 4;
    float* abase = attnf + ((size_t)b * NTOK + n0) * NTOK + m0;
#pragma unroll
    for (int n = 0; n < 16; ++n) {
      ushort4 sv = *(const ushort4*)(s_lds + n * SP + m0 + ml);
      float4 o;
      o.x = b2f(sv.x); o.y = b2f(sv.y); o.z = b2f(sv.z); o.w = b2f(sv.w);
      *(float4*)(abase + (size_t)n * NTOK + ml) = o;
    }
  }
  // ---- PV: out[n][c] = sum_m S[n][m] v[c][m]; wave owns c-block wave*16.
  // Two independent accumulate chains for ILP.
  int cb = wave * 16;
  const ushort* vbb = vb + ((size_t)b * NC + cb + lo) * NTOK;
  f32x4 acc2 = {0.f, 0.f, 0.f, 0.f}, acc3 = {0.f, 0.f, 0.f, 0.f};
  for (int ms = 0; ms < NTOK; ms += 64) {
    short8 af0 = *(const short8*)(s_lds + lo * SP + ms + 8 * lg);
    short8 bf0 = *(const short8*)(vbb + ms + 8 * lg);
    short8 af1 = *(const short8*)(s_lds + lo * SP + ms + 32 + 8 * lg);
    short8 bf1 = *(const short8*)(vbb + ms + 32 + 8 * lg);
    acc2 = __builtin_amdgcn_mfma_f32_16x16x32_bf16(af0, bf0, acc2, 0, 0, 0);
    acc3 = __builtin_amdgcn_mfma_f32_16x16x32_bf16(af1, bf1, acc3, 0, 0, 0);
  }
#pragma unroll
  for (int r = 0; r < 4; ++r) acc2[r] += acc3[r];
  // D: row = n = 4*lg + r, col = c = cb + lo
  int c = cb + lo;
  float4 rv = *(const float4*)(resid + ((size_t)b * NC + c) * NTOK + n0 + 4 * lg);
  float rvv[4] = {rv.x, rv.y, rv.z, rv.w};
  if constexpr (ATTN2) {
    float4 o;
    o.x = scale * (rvv[0] + acc2[0]); o.y = scale * (rvv[1] + acc2[1]);
    o.z = scale * (rvv[2] + acc2[2]); o.w = scale * (rvv[3] + acc2[3]);
    *(float4*)(outf + ((size_t)b * NC + c) * NTOK + n0 + 4 * lg) = o;
  } else {
#pragma unroll
    for (int r = 0; r < 4; ++r) {
      int tok = n0 + 4 * lg + r;
      float val = scale * (rvv[r] + acc2[r]);
      outb_pad[(size_t)b * PAD_BSTRIDE + ((tok >> 5) + 2) * 2304 +
               ((tok & 31) + 2) * 64 + c] = f2b(val);
    }
  }
}

// ---- conv weight pre-pass: W_lstm[oc][ic][5][5] f32 -> Wb[oc][25][128] bf16
__global__ __launch_bounds__(256) void wpre_kernel(
    const float* __restrict__ W, ushort* __restrict__ Wb) {
  int idx = blockIdx.x * 256 + threadIdx.x;
  int oc = idx >> 7, ic = idx & 127;
  const float* src = W + (size_t)idx * 25;
#pragma unroll
  for (int kk = 0; kk < 25; ++kk)
    Wb[((size_t)oc * 25 + kk) * 128 + ic] = f2b(src[kk]);
}

// ---- implicit-GEMM conv, GEMM-tiled, DOUBLE-BUFFERED A: wg = 8 waves =
// 256 oc x 128 px (4 rows), K = 25 taps x 64 ic (kh in grid). One barrier/tap.
#define AP 76
#define BP 76
__global__ __launch_bounds__(512, 1) void conv_mfma_kernel(
    const ushort* __restrict__ pad,   // [b][2][36*36][64] bf16
    const ushort* __restrict__ Wb,    // [256 oc][25 kk][128 ic] bf16
    float* __restrict__ gates0, float* __restrict__ gates1) {
  __shared__ ushort ldsA[2][256 * AP];  // ping-pong [oc][64 ic]
  __shared__ ushort ldsB[288 * BP];     // [8 rows x 36 cols][64 ic]
  int t = threadIdx.x;
  int lane = t & 63, lo = lane & 15, lg = lane >> 4;
  int wid = t >> 6, oc_g = wid & 3, px_g = wid >> 2;
  int rp = blockIdx.x, kh = blockIdx.y, b = blockIdx.z;
  const ushort* padKH = pad + (size_t)b * PAD_BSTRIDE + (size_t)kh * PAD_KSTRIDE
                        + (size_t)(rp * 4) * 2304;

  for (int i = t; i < 2304; i += 512) {
    int pxw = i >> 3, ch8 = (i & 7) * 8;
    uint4 v = *(const uint4*)(padKH + (size_t)pxw * 64 + ch8);
    *(uint4*)(ldsB + pxw * BP + ch8) = v;
  }

  const ushort *wsrc0, *wsrc1, *wsrc2, *wsrc3;
  int adst0, adst1, adst2, adst3;
  {
    int i0 = t, i1 = 512 + t, i2 = 1024 + t, i3 = 1536 + t;
    wsrc0 = Wb + (size_t)(i0 >> 3) * 3200 + kh * 64 + (i0 & 7) * 8;
    wsrc1 = Wb + (size_t)(i1 >> 3) * 3200 + kh * 64 + (i1 & 7) * 8;
    wsrc2 = Wb + (size_t)(i2 >> 3) * 3200 + kh * 64 + (i2 & 7) * 8;
    wsrc3 = Wb + (size_t)(i3 >> 3) * 3200 + kh * 64 + (i3 & 7) * 8;
    adst0 = (i0 >> 3) * AP + (i0 & 7) * 8;
    adst1 = (i1 >> 3) * AP + (i1 & 7) * 8;
    adst2 = (i2 >> 3) * AP + (i2 & 7) * 8;
    adst3 = (i3 >> 3) * AP + (i3 & 7) * 8;
  }
  uint4 w0 = *(const uint4*)(wsrc0);
  uint4 w1 = *(const uint4*)(wsrc1);
  uint4 w2 = *(const uint4*)(wsrc2);
  uint4 w3 = *(const uint4*)(wsrc3);

  f32x4 acc[4][4];
#pragma unroll
  for (int i = 0; i < 4; ++i)
#pragma unroll
    for (int j = 0; j < 4; ++j) acc[i][j] = {0.f, 0.f, 0.f, 0.f};

  __syncthreads();            // B staged; safe to write A0
  *(uint4*)(&ldsA[0][adst0]) = w0;
  *(uint4*)(&ldsA[0][adst1]) = w1;
  *(uint4*)(&ldsA[0][adst2]) = w2;
  *(uint4*)(&ldsA[0][adst3]) = w3;
  w0 = *(const uint4*)(wsrc0 + 128);   // tap 1
  w1 = *(const uint4*)(wsrc1 + 128);
  w2 = *(const uint4*)(wsrc2 + 128);
  w3 = *(const uint4*)(wsrc3 + 128);
  __syncthreads();            // A0 ready

  for (int kk = 0; kk < 25; ++kk) {
    int cur = kk & 1;
    if (kk < 24) {
      int nxt = cur ^ 1;
      *(uint4*)(&ldsA[nxt][adst0]) = w0;
      *(uint4*)(&ldsA[nxt][adst1]) = w1;
      *(uint4*)(&ldsA[nxt][adst2]) = w2;
      *(uint4*)(&ldsA[nxt][adst3]) = w3;
      int kkn = (kk < 23) ? kk + 2 : 24;
      w0 = *(const uint4*)(wsrc0 + kkn * 128);
      w1 = *(const uint4*)(wsrc1 + kkn * 128);
      w2 = *(const uint4*)(wsrc2 + kkn * 128);
      w3 = *(const uint4*)(wsrc3 + kkn * 128);
    }
    int ky = kk / 5, kx = kk - 5 * ky;
    int tapoff = (ky * 36 + kx) * BP;
#pragma unroll
    for (int icc = 0; icc < 2; ++icc) {
      short8 af[4], bf[4];
#pragma unroll
      for (int i = 0; i < 4; ++i)
        af[i] = *(const short8*)(&ldsA[cur][(oc_g * 64 + i * 16 + lo) * AP + icc * 32 + 8 * lg]);
#pragma unroll
      for (int j = 0; j < 4; ++j) {
        int pxw = (px_g * 2 + (j >> 1)) * 36 + (j & 1) * 16 + lo;
        bf[j] = *(const short8*)(ldsB + tapoff + pxw * BP + icc * 32 + 8 * lg);
      }
#pragma unroll
      for (int i = 0; i < 4; ++i)
#pragma unroll
        for (int j = 0; j < 4; ++j)
          acc[i][j] = __builtin_amdgcn_mfma_f32_16x16x32_bf16(af[i], bf[j], acc[i][j], 0, 0, 0);
    }
    __syncthreads();
  }

  float* gp = kh ? gates1 : gates0;
#pragma unroll
  for (int i = 0; i < 4; ++i)
#pragma unroll
    for (int j = 0; j < 4; ++j)
#pragma unroll
      for (int r = 0; r < 4; ++r) {
        int oc = oc_g * 64 + i * 16 + lg * 4 + r;
        int p  = rp * 128 + px_g * 64 + j * 16 + lo;
        gp[(size_t)(b * 256 + oc) * NTOK + p] = acc[i][j][r];
      }
}

// ---- gates halves + bias -> c_new, h_new
__global__ __launch_bounds__(256) void lstm_kernel(
    const float* __restrict__ g0, const float* __restrict__ g1,
    const float* __restrict__ bias, const float* __restrict__ c_in,
    float* __restrict__ c_out, float* __restrict__ h_out) {
  size_t idx = (size_t)blockIdx.x * 256 + threadIdx.x;
  size_t b = idx >> 16;
  size_t r = idx & 65535;
  int ocr = (int)(r >> 10);            // uniform per block
  size_t gbo = b * (size_t)(256 * NTOK);
  float iv = g0[gbo + r]          + g1[gbo + r]          + bias[ocr];
  float fv = g0[gbo + 65536 + r]  + g1[gbo + 65536 + r]  + bias[64 + ocr];
  float ov = g0[gbo + 131072 + r] + g1[gbo + 131072 + r] + bias[128 + ocr];
  float gv = g0[gbo + 196608 + r] + g1[gbo + 196608 + r] + bias[192 + ocr];
  iv = 1.f / (1.f + expf(-iv));
  fv = 1.f / (1.f + expf(-fv));
  ov = 1.f / (1.f + expf(-ov));
  gv = tanhf(gv);
  float cn = fv * c_in[idx] + iv * gv;
  c_out[idx] = cn;
  h_out[idx] = ov * tanhf(cn);
}

extern "C" void kernel_launch(void* const* d_in, const int* in_sizes, int n_in,
                              void* d_out, int out_size, void* d_ws, size_t ws_size,
                              hipStream_t stream) {
  const float* x      = (const float*)d_in[0];
  const float* h      = (const float*)d_in[1];
  const float* c      = (const float*)d_in[2];
  const float* Wq_x   = (const float*)d_in[3];
  const float* Wk_x   = (const float*)d_in[4];
  const float* Wv_x   = (const float*)d_in[5];
  const float* Wq_h   = (const float*)d_in[6];
  const float* Wk_h   = (const float*)d_in[7];
  const float* Wv_h   = (const float*)d_in[8];
  const float* W_lstm = (const float*)d_in[9];
  const float* b_lstm = (const float*)d_in[10];

  float* out   = (float*)d_out;
  float* new_h = out;                 // [16,64,32,32]
  float* new_c = out + 1048576;       // [16,64,32,32]
  float* atten = out + 2097152;       // [16,1024,1024]

  // ws layout (ushort granularity)
  ushort* wsu = (ushort*)d_ws;
  ushort* qT  = wsu;                  //   524,288 ushort [b][n][32]
  ushort* kT  = wsu + 524288;         //   524,288
  ushort* vb  = wsu + 1048576;        // 1,048,576 [b][c][m]
  ushort* xT  = wsu + 2097152;        // 1,048,576 [b][n][64] (x / h_mid token-major)
  ushort* wqb = wsu + 3145728;        //     2,048
  ushort* wkb = wsu + 3147776;        //     2,048
  ushort* wvb = wsu + 3149824;        //     4,096

  // scratch aliased into the atten output region (dead until attnfused2):
  float*  gates0 = atten;                        // conv kh=0, bytes [0,16.8M)
  float*  gates1 = atten + 4194304;              // conv kh=1, bytes [16.8M,33.55M)
  ushort* Wb     = (ushort*)(atten + 8388608);   // conv weights, bytes [33.55M,35.2M)
  ushort* pad    = (ushort*)(atten + 9437184);   // padded conv input, [37.7M,43.1M)
  float*  h_mid  = new_h;                        // lstm h lives in new_h slot

  dim3 blk(256);
  // zero the padded conv-input ring (interiors overwritten below)
  hipMemsetAsync(pad, 0, PAD_BYTES, stream);
  // ---- attention 1 on x (fused; scores never touch HBM) ----
  tpose_bf16_kernel<<<dim3(16, NB), blk, 0, stream>>>(x, xT, 0);
  wqkv_pre_kernel<<<16, blk, 0, stream>>>(Wq_x, Wk_x, Wv_x, wqb, wkb, wvb);
  qkvproj_kernel<<<dim3(16, NB), blk, 0, stream>>>(xT, wqb, wkb, wvb, qT, kT, vb);
  attn_fused_kernel<false><<<dim3(64, NB), blk, 0, stream>>>(
      qT, kT, vb, x, nullptr, nullptr, pad /*kh0 interior*/, 1.0f);
  // ---- conv-lstm (bf16 MFMA implicit GEMM, dbuf-A) ----
  wpre_kernel<<<128, blk, 0, stream>>>(W_lstm, Wb);
  tpose_bf16_kernel<<<dim3(16, NB), blk, 0, stream>>>(h, pad + PAD_KSTRIDE, 1);
  conv_mfma_kernel<<<dim3(8, 2, NB), 512, 0, stream>>>(pad, Wb, gates0, gates1);
  lstm_kernel<<<4096, blk, 0, stream>>>(gates0, gates1, b_lstm, c, new_c, h_mid);
  // ---- attention 2 on h_mid (atten f32 is a real output) ----
  tpose_bf16_kernel<<<dim3(16, NB), blk, 0, stream>>>(h_mid, xT, 0);
  wqkv_pre_kernel<<<16, blk, 0, stream>>>(Wq_h, Wk_h, Wv_h, wqb, wkb, wvb);
  qkvproj_kernel<<<dim3(16, NB), blk, 0, stream>>>(xT, wqb, wkb, wvb, qT, kT, vb);
  attn_fused_kernel<true><<<dim3(64, NB), blk, 0, stream>>>(
      qT, kT, vb, h_mid, atten, new_h, nullptr, 2.0f);
}

// Round 10
// 129.525 us; speedup vs baseline: 16.8083x; 1.0151x over previous
//
#include <hip/hip_runtime.h>
#include <hip/hip_bf16.h>
#include <cstddef>
#include <cstdint>

// Problem constants: B=16, CIN=COUT=64, HID=32, H=W=32, K=5, PAD=2
#define NTOK 1024      // H*W
#define NB   16        // batch
#define NC   64        // channels (CIN == COUT)
#define NHID 32        // attention hidden

// padded conv input: pad[b][kh][36*36 px][64 c] bf16
#define PAD_BSTRIDE 165888   // 2*1296*64
#define PAD_KSTRIDE 82944    // 1296*64
#define PAD_BYTES   5308416  // 16 * PAD_BSTRIDE * 2

typedef __attribute__((ext_vector_type(8))) short short8;   // 8 bf16 = 4 VGPR (MFMA A/B frag)
typedef __attribute__((ext_vector_type(4))) float f32x4;    // MFMA acc frag

// round-to-nearest-even f32 -> bf16 (as raw ushort)
__device__ __forceinline__ ushort f2b(float f) {
  uint32_t u = __builtin_bit_cast(uint32_t, f);
  return (ushort)((u + 0x7FFFu + ((u >> 16) & 1u)) >> 16);
}
__device__ __forceinline__ float b2f(ushort u) {
  return __builtin_bit_cast(float, (uint32_t)u << 16);
}
// 8 consecutive f32 -> bf16x8 frag
__device__ __forceinline__ short8 ldw8(const float* __restrict__ p) {
  float4 f0 = *(const float4*)p, f1 = *(const float4*)(p + 4);
  short8 r;
  r[0] = (short)f2b(f0.x); r[1] = (short)f2b(f0.y);
  r[2] = (short)f2b(f0.z); r[3] = (short)f2b(f0.w);
  r[4] = (short)f2b(f1.x); r[5] = (short)f2b(f1.y);
  r[6] = (short)f2b(f1.z); r[7] = (short)f2b(f1.w);
  return r;
}
__device__ __forceinline__ float sigm(float x) { return 1.f / (1.f + __expf(-x)); }
__device__ __forceinline__ float tanh_fast(float x) {
  float e = __expf(2.f * x);
  return 1.f - 2.f / (e + 1.f);   // safe at +/-inf
}

// ---- transpose + convert h f32 [b][64c][1024n] -> padded conv-input interior
__global__ __launch_bounds__(256) void tpose_pad_kernel(
    const float* __restrict__ src, ushort* __restrict__ dst) {
  __shared__ float tile[64][65];
  int t = threadIdx.x;
  int n0 = blockIdx.x * 64, b = blockIdx.y;
  const float* s = src + (size_t)b * NC * NTOK;
#pragma unroll
  for (int r = 0; r < 4; ++r) {
    int c = r * 16 + (t >> 4);
    int nl = (t & 15) * 4;
    float4 v = *(const float4*)(s + (size_t)c * NTOK + n0 + nl);
    tile[c][nl] = v.x; tile[c][nl + 1] = v.y; tile[c][nl + 2] = v.z; tile[c][nl + 3] = v.w;
  }
  __syncthreads();
  int tok = t >> 2, c0 = (t & 3) * 16;
  __attribute__((aligned(16))) ushort tmp[16];
#pragma unroll
  for (int i = 0; i < 16; ++i) tmp[i] = f2b(tile[c0 + i][tok]);
  int gtok = n0 + tok;
  ushort* d = dst + (size_t)b * PAD_BSTRIDE +
              ((gtok >> 5) + 2) * 2304 + ((gtok & 31) + 2) * 64 + c0;
  *(uint4*)(d)     = *(const uint4*)(tmp);
  *(uint4*)(d + 8) = *(const uint4*)(tmp + 8);
}

// ---- fused transpose + q,k,v projection via MFMA (reads f32 channel-major x).
// qT/kT[b][n][32] bf16, vb[b][64e][1024m] bf16. One wg (4 waves) per 64 tokens.
__global__ __launch_bounds__(256) void qkvproj_kernel(
    const float* __restrict__ x, const float* __restrict__ Wq,
    const float* __restrict__ Wk, const float* __restrict__ Wv,
    ushort* __restrict__ qT, ushort* __restrict__ kT, ushort* __restrict__ vb) {
  __shared__ float tile[64][65];
  __shared__ ushort xb[64][72];
  __shared__ ushort sq[64][32], sk[64][32];
  int t = threadIdx.x, wave = t >> 6, lane = t & 63;
  int lo = lane & 15, lg = lane >> 4;
  int n0 = blockIdx.x * 64, b = blockIdx.y;
  // phase 1: f32 transpose tile
  const float* s = x + (size_t)b * NC * NTOK;
#pragma unroll
  for (int r = 0; r < 4; ++r) {
    int c = r * 16 + (t >> 4);
    int nl = (t & 15) * 4;
    float4 v = *(const float4*)(s + (size_t)c * NTOK + n0 + nl);
    tile[c][nl] = v.x; tile[c][nl + 1] = v.y; tile[c][nl + 2] = v.z; tile[c][nl + 3] = v.w;
  }
  __syncthreads();
  {
    int tok = t >> 2, c0 = (t & 3) * 16;
    __attribute__((aligned(16))) ushort tmp[16];
#pragma unroll
    for (int i = 0; i < 16; ++i) tmp[i] = f2b(tile[c0 + i][tok]);
    *(uint4*)(&xb[tok][c0])     = *(const uint4*)(tmp);
    *(uint4*)(&xb[tok][c0 + 8]) = *(const uint4*)(tmp + 8);
  }
  __syncthreads();
  // phase 2: MFMA projections (weights converted in-register, L2-hot)
  const ushort* xrow = &xb[wave * 16 + lo][8 * lg];
  short8 a0 = *(const short8*)(xrow);        // k = c in [0,32)
  short8 a1 = *(const short8*)(xrow + 32);   // k = c in [32,64)
  f32x4 aq[2], ak[2];
#pragma unroll
  for (int dg = 0; dg < 2; ++dg) {
    short8 wq0 = ldw8(Wq + (size_t)(dg * 16 + lo) * NC + 8 * lg);
    short8 wq1 = ldw8(Wq + (size_t)(dg * 16 + lo) * NC + 32 + 8 * lg);
    short8 wk0 = ldw8(Wk + (size_t)(dg * 16 + lo) * NC + 8 * lg);
    short8 wk1 = ldw8(Wk + (size_t)(dg * 16 + lo) * NC + 32 + 8 * lg);
    f32x4 z = {0.f, 0.f, 0.f, 0.f};
    aq[dg] = __builtin_amdgcn_mfma_f32_16x16x32_bf16(a0, wq0, z, 0, 0, 0);
    aq[dg] = __builtin_amdgcn_mfma_f32_16x16x32_bf16(a1, wq1, aq[dg], 0, 0, 0);
    ak[dg] = __builtin_amdgcn_mfma_f32_16x16x32_bf16(a0, wk0, z, 0, 0, 0);
    ak[dg] = __builtin_amdgcn_mfma_f32_16x16x32_bf16(a1, wk1, ak[dg], 0, 0, 0);
  }
  f32x4 av[4];
#pragma unroll
  for (int g = 0; g < 4; ++g) {
    short8 wv0 = ldw8(Wv + (size_t)(g * 16 + lo) * NC + 8 * lg);
    short8 wv1 = ldw8(Wv + (size_t)(g * 16 + lo) * NC + 32 + 8 * lg);
    f32x4 z = {0.f, 0.f, 0.f, 0.f};
    av[g] = __builtin_amdgcn_mfma_f32_16x16x32_bf16(wv0, a0, z, 0, 0, 0);
    av[g] = __builtin_amdgcn_mfma_f32_16x16x32_bf16(wv1, a1, av[g], 0, 0, 0);
  }
#pragma unroll
  for (int dg = 0; dg < 2; ++dg)
#pragma unroll
    for (int r = 0; r < 4; ++r) {
      sq[wave * 16 + 4 * lg + r][dg * 16 + lo] = f2b(aq[dg][r]);
      sk[wave * 16 + 4 * lg + r][dg * 16 + lo] = f2b(ak[dg][r]);
    }
  ushort* vbase = vb + (size_t)b * NC * NTOK + n0 + wave * 16 + lo;
#pragma unroll
  for (int g = 0; g < 4; ++g)
#pragma unroll
    for (int r = 0; r < 4; ++r)
      vbase[(size_t)(g * 16 + lg * 4 + r) * NTOK] = f2b(av[g][r]);
  __syncthreads();
  int tok = t >> 2, d0 = (t & 3) * 8;
  size_t base = ((size_t)b * NTOK + n0 + tok) * NHID + d0;
  *(short8*)(qT + base) = *(const short8*)(&sq[tok][d0]);
  *(short8*)(kT + base) = *(const short8*)(&sk[tok][d0]);
}

// ---- FUSED attention: scores (MFMA) -> softmax -> S->bf16 LDS -> coalesced
// atten write (ATTN2) -> PV (MFMA, 2-chain) -> residual+scale epilogue.
#define SP 1048   // S-LDS pitch (ushorts): bank stride 12 -> <=2-way
template <bool ATTN2>
__global__ __launch_bounds__(256) void attn_fused_kernel(
    const ushort* __restrict__ qT, const ushort* __restrict__ kT,
    const ushort* __restrict__ vb, const float* __restrict__ resid,
    float* __restrict__ attnf, float* __restrict__ outf,
    ushort* __restrict__ outb_pad, float scale) {
  __shared__ ushort s_lds[16 * SP];
  __shared__ float wmax[4][16], wsum[4][16];
  int t = threadIdx.x, wave = t >> 6, lane = t & 63;
  int lo = lane & 15, lg = lane >> 4;
  int n0 = blockIdx.x * 16, b = blockIdx.y;
  int m0 = wave * 256;
  short8 a = *(const short8*)(qT + ((size_t)b * NTOK + n0 + lo) * NHID + 8 * lg);
  f32x4 acc[16];
#pragma unroll
  for (int j = 0; j < 16; ++j) {
    short8 bf = *(const short8*)(kT + ((size_t)b * NTOK + m0 + j * 16 + lo) * NHID + 8 * lg);
    f32x4 z = {0.f, 0.f, 0.f, 0.f};
    acc[j] = __builtin_amdgcn_mfma_f32_16x16x32_bf16(a, bf, z, 0, 0, 0);
  }
  float pm[4];
#pragma unroll
  for (int r = 0; r < 4; ++r) {
    float m = acc[0][r];
#pragma unroll
    for (int j = 1; j < 16; ++j) m = fmaxf(m, acc[j][r]);
#pragma unroll
    for (int off = 1; off < 16; off <<= 1) m = fmaxf(m, __shfl_xor(m, off, 64));
    pm[r] = m;
  }
  if (lo == 0)
#pragma unroll
    for (int r = 0; r < 4; ++r) wmax[wave][4 * lg + r] = pm[r];
  __syncthreads();
  float mr[4];
#pragma unroll
  for (int r = 0; r < 4; ++r)
    mr[r] = fmaxf(fmaxf(wmax[0][4 * lg + r], wmax[1][4 * lg + r]),
                  fmaxf(wmax[2][4 * lg + r], wmax[3][4 * lg + r]));
  float ps[4] = {0.f, 0.f, 0.f, 0.f};
#pragma unroll
  for (int j = 0; j < 16; ++j)
#pragma unroll
    for (int r = 0; r < 4; ++r) {
      float e = __expf(acc[j][r] - mr[r]);
      acc[j][r] = e;
      ps[r] += e;
    }
#pragma unroll
  for (int r = 0; r < 4; ++r)
#pragma unroll
    for (int off = 1; off < 16; off <<= 1) ps[r] += __shfl_xor(ps[r], off, 64);
  if (lo == 0)
#pragma unroll
    for (int r = 0; r < 4; ++r) wsum[wave][4 * lg + r] = ps[r];
  __syncthreads();
  float inv[4];
#pragma unroll
  for (int r = 0; r < 4; ++r)
    inv[r] = 1.f / (wsum[0][4 * lg + r] + wsum[1][4 * lg + r] +
                    wsum[2][4 * lg + r] + wsum[3][4 * lg + r]);
#pragma unroll
  for (int j = 0; j < 16; ++j)
#pragma unroll
    for (int r = 0; r < 4; ++r)
      s_lds[(4 * lg + r) * SP + m0 + j * 16 + lo] = f2b(acc[j][r] * inv[r]);
  __syncthreads();
  if constexpr (ATTN2) {
    int ml = lane * 4;
    float* abase = attnf + ((size_t)b * NTOK + n0) * NTOK + m0;
#pragma unroll
    for (int n = 0; n < 16; ++n) {
      ushort4 sv = *(const ushort4*)(s_lds + n * SP + m0 + ml);
      float4 o;
      o.x = b2f(sv.x); o.y = b2f(sv.y); o.z = b2f(sv.z); o.w = b2f(sv.w);
      *(float4*)(abase + (size_t)n * NTOK + ml) = o;
    }
  }
  int cb = wave * 16;
  const ushort* vbb = vb + ((size_t)b * NC + cb + lo) * NTOK;
  f32x4 acc2 = {0.f, 0.f, 0.f, 0.f}, acc3 = {0.f, 0.f, 0.f, 0.f};
  for (int ms = 0; ms < NTOK; ms += 64) {
    short8 af0 = *(const short8*)(s_lds + lo * SP + ms + 8 * lg);
    short8 bf0 = *(const short8*)(vbb + ms + 8 * lg);
    short8 af1 = *(const short8*)(s_lds + lo * SP + ms + 32 + 8 * lg);
    short8 bf1 = *(const short8*)(vbb + ms + 32 + 8 * lg);
    acc2 = __builtin_amdgcn_mfma_f32_16x16x32_bf16(af0, bf0, acc2, 0, 0, 0);
    acc3 = __builtin_amdgcn_mfma_f32_16x16x32_bf16(af1, bf1, acc3, 0, 0, 0);
  }
#pragma unroll
  for (int r = 0; r < 4; ++r) acc2[r] += acc3[r];
  int c = cb + lo;
  float4 rv = *(const float4*)(resid + ((size_t)b * NC + c) * NTOK + n0 + 4 * lg);
  float rvv[4] = {rv.x, rv.y, rv.z, rv.w};
  if constexpr (ATTN2) {
    float4 o;
    o.x = scale * (rvv[0] + acc2[0]); o.y = scale * (rvv[1] + acc2[1]);
    o.z = scale * (rvv[2] + acc2[2]); o.w = scale * (rvv[3] + acc2[3]);
    *(float4*)(outf + ((size_t)b * NC + c) * NTOK + n0 + 4 * lg) = o;
  } else {
#pragma unroll
    for (int r = 0; r < 4; ++r) {
      int tok = n0 + 4 * lg + r;
      float val = scale * (rvv[r] + acc2[r]);
      outb_pad[(size_t)b * PAD_BSTRIDE + ((tok >> 5) + 2) * 2304 +
               ((tok & 31) + 2) * 64 + c] = f2b(val);
    }
  }
}

// ---- conv weight pre-pass: W_lstm[oc][ic][5][5] f32 -> Wb[oc][25][128] bf16
__global__ __launch_bounds__(256) void wpre_kernel(
    const float* __restrict__ W, ushort* __restrict__ Wb) {
  int idx = blockIdx.x * 256 + threadIdx.x;
  const float* src = W + (size_t)idx * 25;
#pragma unroll
  for (int kk = 0; kk < 25; ++kk)
    Wb[((size_t)(idx >> 7) * 25 + kk) * 128 + (idx & 127)] = f2b(src[kk]);
}

// ---- FUSED conv + LSTM. wg = 8 waves = 256 oc x 64 px (2 rows); wave's 4
// A-frags are the 4 GATES of one 16-channel block (A row = gate*64 + ocr), so
// each thread ends holding i,f,o,g for its (channel,px) -> LSTM in epilogue.
// K = 50 steps (25 taps x 2 ic-halves) of 256x64ic A-tiles, dbuf, 1 barrier/step.
// Grid (16 px-tiles, 16 b) = 256 wgs. LDS 140.1 KB.
#define AP 76
#define BP 76
__global__ __launch_bounds__(512, 1) void conv_lstm_kernel(
    const ushort* __restrict__ pad,   // [b][2][36*36][64] bf16
    const ushort* __restrict__ Wb,    // [256 oc][25 kk][128 ic] bf16
    const float* __restrict__ bias, const float* __restrict__ c_in,
    float* __restrict__ c_out, float* __restrict__ h_out) {
  __shared__ ushort ldsA[2][256 * AP];  // ping-pong [oc][64 ic]
  __shared__ ushort ldsB[432 * BP];     // [2 kh][6 rows x 36 cols][64 ic]
  int t = threadIdx.x;
  int lane = t & 63, lo = lane & 15, lg = lane >> 4;
  int wid = t >> 6, ocr_base = (wid & 3) * 16, ph = wid >> 2;
  int pt = blockIdx.x, b = blockIdx.y;
  // stage B: both kh windows (6 rows x 36 cols x 64 ic each, contiguous src)
  {
    const ushort* pb = pad + (size_t)b * PAD_BSTRIDE + (size_t)(pt * 2) * 2304;
    for (int i = t; i < 432 * 8; i += 512) {
      int pxw = i >> 3, ch8 = (i & 7) * 8;
      int kh = pxw >= 216, w = pxw - kh * 216;
      uint4 v = *(const uint4*)(pb + (size_t)kh * PAD_KSTRIDE + w * 64 + ch8);
      *(uint4*)(ldsB + pxw * BP + ch8) = v;
    }
  }
  // per-thread A staging addresses (4 x 16B chunks cover 256oc x 64ic)
  const ushort *wsrc0, *wsrc1, *wsrc2, *wsrc3;
  int adst0, adst1, adst2, adst3;
  {
    int i0 = t, i1 = 512 + t, i2 = 1024 + t, i3 = 1536 + t;
    wsrc0 = Wb + (size_t)(i0 >> 3) * 3200 + (i0 & 7) * 8;
    wsrc1 = Wb + (size_t)(i1 >> 3) * 3200 + (i1 & 7) * 8;
    wsrc2 = Wb + (size_t)(i2 >> 3) * 3200 + (i2 & 7) * 8;
    wsrc3 = Wb + (size_t)(i3 >> 3) * 3200 + (i3 & 7) * 8;
    adst0 = (i0 >> 3) * AP + (i0 & 7) * 8;
    adst1 = (i1 >> 3) * AP + (i1 & 7) * 8;
    adst2 = (i2 >> 3) * AP + (i2 & 7) * 8;
    adst3 = (i3 >> 3) * AP + (i3 & 7) * 8;
  }
  // koff(s) = tap*128 + kh*64, s = kh*25 + tap
  uint4 w0 = *(const uint4*)(wsrc0);        // step 0
  uint4 w1 = *(const uint4*)(wsrc1);
  uint4 w2 = *(const uint4*)(wsrc2);
  uint4 w3 = *(const uint4*)(wsrc3);

  f32x4 acc[4][2];
#pragma unroll
  for (int i = 0; i < 4; ++i)
#pragma unroll
    for (int j = 0; j < 2; ++j) acc[i][j] = {0.f, 0.f, 0.f, 0.f};

  __syncthreads();            // B staged
  *(uint4*)(&ldsA[0][adst0]) = w0;
  *(uint4*)(&ldsA[0][adst1]) = w1;
  *(uint4*)(&ldsA[0][adst2]) = w2;
  *(uint4*)(&ldsA[0][adst3]) = w3;
  w0 = *(const uint4*)(wsrc0 + 128);        // step 1 (tap1 kh0)
  w1 = *(const uint4*)(wsrc1 + 128);
  w2 = *(const uint4*)(wsrc2 + 128);
  w3 = *(const uint4*)(wsrc3 + 128);
  __syncthreads();            // A0 ready

  for (int s = 0; s < 50; ++s) {
    int cur = s & 1;
    if (s < 49) {
      int nxt = cur ^ 1;
      *(uint4*)(&ldsA[nxt][adst0]) = w0;
      *(uint4*)(&ldsA[nxt][adst1]) = w1;
      *(uint4*)(&ldsA[nxt][adst2]) = w2;
      *(uint4*)(&ldsA[nxt][adst3]) = w3;
      int s2 = (s < 48) ? s + 2 : 49;
      int koff = (s2 < 25) ? s2 * 128 : (s2 - 25) * 128 + 64;
      w0 = *(const uint4*)(wsrc0 + koff);
      w1 = *(const uint4*)(wsrc1 + koff);
      w2 = *(const uint4*)(wsrc2 + koff);
      w3 = *(const uint4*)(wsrc3 + koff);
    }
    int kh = (s >= 25);
    int tap = s - kh * 25;
    int ky = tap / 5, kx = tap - 5 * ky;
    int bbase = (kh * 216 + ky * 36 + kx) * BP;
#pragma unroll
    for (int icc = 0; icc < 2; ++icc) {
      short8 af[4], bf[2];
#pragma unroll
      for (int i = 0; i < 4; ++i)   // i = gate
        af[i] = *(const short8*)(&ldsA[cur][(i * 64 + ocr_base + lo) * AP + icc * 32 + 8 * lg]);
#pragma unroll
      for (int j = 0; j < 2; ++j)
        bf[j] = *(const short8*)(ldsB + bbase + (ph * 36 + j * 16 + lo) * BP + icc * 32 + 8 * lg);
#pragma unroll
      for (int i = 0; i < 4; ++i)
#pragma unroll
        for (int j = 0; j < 2; ++j)
          acc[i][j] = __builtin_amdgcn_mfma_f32_16x16x32_bf16(af[i], bf[j], acc[i][j], 0, 0, 0);
    }
    __syncthreads();
  }

  // LSTM epilogue: thread holds gates i/f/o/g at (ocr, p)
#pragma unroll
  for (int j = 0; j < 2; ++j)
#pragma unroll
    for (int r = 0; r < 4; ++r) {
      int ocr = ocr_base + lg * 4 + r;
      int p = pt * 64 + ph * 32 + j * 16 + lo;
      size_t ci = ((size_t)b * NC + ocr) * NTOK + p;
      float iv = sigm(acc[0][j][r] + bias[ocr]);
      float fv = sigm(acc[1][j][r] + bias[64 + ocr]);
      float ov = sigm(acc[2][j][r] + bias[128 + ocr]);
      float gv = tanh_fast(acc[3][j][r] + bias[192 + ocr]);
      float cn = fv * c_in[ci] + iv * gv;
      c_out[ci] = cn;
      h_out[ci] = ov * tanh_fast(cn);
    }
}

extern "C" void kernel_launch(void* const* d_in, const int* in_sizes, int n_in,
                              void* d_out, int out_size, void* d_ws, size_t ws_size,
                              hipStream_t stream) {
  const float* x      = (const float*)d_in[0];
  const float* h      = (const float*)d_in[1];
  const float* c      = (const float*)d_in[2];
  const float* Wq_x   = (const float*)d_in[3];
  const float* Wk_x   = (const float*)d_in[4];
  const float* Wv_x   = (const float*)d_in[5];
  const float* Wq_h   = (const float*)d_in[6];
  const float* Wk_h   = (const float*)d_in[7];
  const float* Wv_h   = (const float*)d_in[8];
  const float* W_lstm = (const float*)d_in[9];
  const float* b_lstm = (const float*)d_in[10];

  float* out   = (float*)d_out;
  float* new_h = out;                 // [16,64,32,32]
  float* new_c = out + 1048576;       // [16,64,32,32]
  float* atten = out + 2097152;       // [16,1024,1024]

  // ws layout (ushort granularity)
  ushort* wsu = (ushort*)d_ws;
  ushort* qT  = wsu;                  //   524,288 ushort [b][n][32]
  ushort* kT  = wsu + 524288;         //   524,288
  ushort* vb  = wsu + 1048576;        // 1,048,576 [b][c][m]

  // scratch aliased into the atten output region (dead until attn2):
  ushort* Wb    = (ushort*)(atten + 8388608);   // conv weights, bytes [33.55M,35.2M)
  ushort* pad   = (ushort*)(atten + 9437184);   // padded conv input, [37.7M,43.1M)
  float*  h_mid = new_h;                        // lstm h lives in new_h slot

  dim3 blk(256);
  // zero the padded conv-input ring (interiors overwritten below)
  hipMemsetAsync(pad, 0, PAD_BYTES, stream);
  // ---- attention 1 on x (fused; scores never touch HBM) ----
  qkvproj_kernel<<<dim3(16, NB), blk, 0, stream>>>(x, Wq_x, Wk_x, Wv_x, qT, kT, vb);
  attn_fused_kernel<false><<<dim3(64, NB), blk, 0, stream>>>(
      qT, kT, vb, x, nullptr, nullptr, pad /*kh0 interior*/, 1.0f);
  // ---- conv-lstm (bf16 MFMA implicit GEMM, fused LSTM epilogue) ----
  wpre_kernel<<<128, blk, 0, stream>>>(W_lstm, Wb);
  tpose_pad_kernel<<<dim3(16, NB), blk, 0, stream>>>(h, pad + PAD_KSTRIDE);
  conv_lstm_kernel<<<dim3(16, NB), 512, 0, stream>>>(pad, Wb, b_lstm, c, new_c, h_mid);
  // ---- attention 2 on h_mid (atten f32 is a real output) ----
  qkvproj_kernel<<<dim3(16, NB), blk, 0, stream>>>(h_mid, Wq_h, Wk_h, Wv_h, qT, kT, vb);
  attn_fused_kernel<true><<<dim3(64, NB), blk, 0, stream>>>(
      qT, kT, vb, h_mid, atten, new_h, nullptr, 2.0f);
}

// Round 11
// 127.733 us; speedup vs baseline: 17.0440x; 1.0140x over previous
//
#include <hip/hip_runtime.h>
#include <hip/hip_bf16.h>
#include <cstddef>
#include <cstdint>

// Problem constants: B=16, CIN=COUT=64, HID=32, H=W=32, K=5, PAD=2
#define NTOK 1024      // H*W
#define NB   16        // batch
#define NC   64        // channels (CIN == COUT)
#define NHID 32        // attention hidden

// padded conv input: pad[b][kh][36*36 px][64 c] bf16
#define PAD_BSTRIDE 165888   // 2*1296*64
#define PAD_KSTRIDE 82944    // 1296*64
#define PAD_BYTES   5308416  // 16 * PAD_BSTRIDE * 2

typedef __attribute__((ext_vector_type(8))) short short8;   // 8 bf16 = 4 VGPR (MFMA A/B frag)
typedef __attribute__((ext_vector_type(4))) float f32x4;    // MFMA acc frag

// round-to-nearest-even f32 -> bf16 (as raw ushort)
__device__ __forceinline__ ushort f2b(float f) {
  uint32_t u = __builtin_bit_cast(uint32_t, f);
  return (ushort)((u + 0x7FFFu + ((u >> 16) & 1u)) >> 16);
}
__device__ __forceinline__ float b2f(ushort u) {
  return __builtin_bit_cast(float, (uint32_t)u << 16);
}
// 8 consecutive f32 -> bf16x8 frag
__device__ __forceinline__ short8 ldw8(const float* __restrict__ p) {
  float4 f0 = *(const float4*)p, f1 = *(const float4*)(p + 4);
  short8 r;
  r[0] = (short)f2b(f0.x); r[1] = (short)f2b(f0.y);
  r[2] = (short)f2b(f0.z); r[3] = (short)f2b(f0.w);
  r[4] = (short)f2b(f1.x); r[5] = (short)f2b(f1.y);
  r[6] = (short)f2b(f1.z); r[7] = (short)f2b(f1.w);
  return r;
}
__device__ __forceinline__ float sigm(float x) { return 1.f / (1.f + __expf(-x)); }
__device__ __forceinline__ float tanh_fast(float x) {
  float e = __expf(2.f * x);
  return 1.f - 2.f / (e + 1.f);   // safe at +/-inf
}

// ---- transpose + convert h f32 [b][64c][1024n] -> padded conv-input interior
__global__ __launch_bounds__(256) void tpose_pad_kernel(
    const float* __restrict__ src, ushort* __restrict__ dst) {
  __shared__ float tile[64][65];
  int t = threadIdx.x;
  int n0 = blockIdx.x * 64, b = blockIdx.y;
  const float* s = src + (size_t)b * NC * NTOK;
#pragma unroll
  for (int r = 0; r < 4; ++r) {
    int c = r * 16 + (t >> 4);
    int nl = (t & 15) * 4;
    float4 v = *(const float4*)(s + (size_t)c * NTOK + n0 + nl);
    tile[c][nl] = v.x; tile[c][nl + 1] = v.y; tile[c][nl + 2] = v.z; tile[c][nl + 3] = v.w;
  }
  __syncthreads();
  int tok = t >> 2, c0 = (t & 3) * 16;
  __attribute__((aligned(16))) ushort tmp[16];
#pragma unroll
  for (int i = 0; i < 16; ++i) tmp[i] = f2b(tile[c0 + i][tok]);
  int gtok = n0 + tok;
  ushort* d = dst + (size_t)b * PAD_BSTRIDE +
              ((gtok >> 5) + 2) * 2304 + ((gtok & 31) + 2) * 64 + c0;
  *(uint4*)(d)     = *(const uint4*)(tmp);
  *(uint4*)(d + 8) = *(const uint4*)(tmp + 8);
}

// ---- fused transpose + q,k,v projection via MFMA (reads f32 channel-major x).
__global__ __launch_bounds__(256) void qkvproj_kernel(
    const float* __restrict__ x, const float* __restrict__ Wq,
    const float* __restrict__ Wk, const float* __restrict__ Wv,
    ushort* __restrict__ qT, ushort* __restrict__ kT, ushort* __restrict__ vb) {
  __shared__ float tile[64][65];
  __shared__ ushort xb[64][72];
  __shared__ ushort sq[64][32], sk[64][32];
  int t = threadIdx.x, wave = t >> 6, lane = t & 63;
  int lo = lane & 15, lg = lane >> 4;
  int n0 = blockIdx.x * 64, b = blockIdx.y;
  const float* s = x + (size_t)b * NC * NTOK;
#pragma unroll
  for (int r = 0; r < 4; ++r) {
    int c = r * 16 + (t >> 4);
    int nl = (t & 15) * 4;
    float4 v = *(const float4*)(s + (size_t)c * NTOK + n0 + nl);
    tile[c][nl] = v.x; tile[c][nl + 1] = v.y; tile[c][nl + 2] = v.z; tile[c][nl + 3] = v.w;
  }
  __syncthreads();
  {
    int tok = t >> 2, c0 = (t & 3) * 16;
    __attribute__((aligned(16))) ushort tmp[16];
#pragma unroll
    for (int i = 0; i < 16; ++i) tmp[i] = f2b(tile[c0 + i][tok]);
    *(uint4*)(&xb[tok][c0])     = *(const uint4*)(tmp);
    *(uint4*)(&xb[tok][c0 + 8]) = *(const uint4*)(tmp + 8);
  }
  __syncthreads();
  const ushort* xrow = &xb[wave * 16 + lo][8 * lg];
  short8 a0 = *(const short8*)(xrow);
  short8 a1 = *(const short8*)(xrow + 32);
  f32x4 aq[2], ak[2];
#pragma unroll
  for (int dg = 0; dg < 2; ++dg) {
    short8 wq0 = ldw8(Wq + (size_t)(dg * 16 + lo) * NC + 8 * lg);
    short8 wq1 = ldw8(Wq + (size_t)(dg * 16 + lo) * NC + 32 + 8 * lg);
    short8 wk0 = ldw8(Wk + (size_t)(dg * 16 + lo) * NC + 8 * lg);
    short8 wk1 = ldw8(Wk + (size_t)(dg * 16 + lo) * NC + 32 + 8 * lg);
    f32x4 z = {0.f, 0.f, 0.f, 0.f};
    aq[dg] = __builtin_amdgcn_mfma_f32_16x16x32_bf16(a0, wq0, z, 0, 0, 0);
    aq[dg] = __builtin_amdgcn_mfma_f32_16x16x32_bf16(a1, wq1, aq[dg], 0, 0, 0);
    ak[dg] = __builtin_amdgcn_mfma_f32_16x16x32_bf16(a0, wk0, z, 0, 0, 0);
    ak[dg] = __builtin_amdgcn_mfma_f32_16x16x32_bf16(a1, wk1, ak[dg], 0, 0, 0);
  }
  f32x4 av[4];
#pragma unroll
  for (int g = 0; g < 4; ++g) {
    short8 wv0 = ldw8(Wv + (size_t)(g * 16 + lo) * NC + 8 * lg);
    short8 wv1 = ldw8(Wv + (size_t)(g * 16 + lo) * NC + 32 + 8 * lg);
    f32x4 z = {0.f, 0.f, 0.f, 0.f};
    av[g] = __builtin_amdgcn_mfma_f32_16x16x32_bf16(wv0, a0, z, 0, 0, 0);
    av[g] = __builtin_amdgcn_mfma_f32_16x16x32_bf16(wv1, a1, av[g], 0, 0, 0);
  }
#pragma unroll
  for (int dg = 0; dg < 2; ++dg)
#pragma unroll
    for (int r = 0; r < 4; ++r) {
      sq[wave * 16 + 4 * lg + r][dg * 16 + lo] = f2b(aq[dg][r]);
      sk[wave * 16 + 4 * lg + r][dg * 16 + lo] = f2b(ak[dg][r]);
    }
  ushort* vbase = vb + (size_t)b * NC * NTOK + n0 + wave * 16 + lo;
#pragma unroll
  for (int g = 0; g < 4; ++g)
#pragma unroll
    for (int r = 0; r < 4; ++r)
      vbase[(size_t)(g * 16 + lg * 4 + r) * NTOK] = f2b(av[g][r]);
  __syncthreads();
  int tok = t >> 2, d0 = (t & 3) * 8;
  size_t base = ((size_t)b * NTOK + n0 + tok) * NHID + d0;
  *(short8*)(qT + base) = *(const short8*)(&sq[tok][d0]);
  *(short8*)(kT + base) = *(const short8*)(&sk[tok][d0]);
}

// ---- FUSED attention: scores (MFMA) -> softmax -> S->bf16 LDS -> coalesced
// atten write (ATTN2) -> PV (MFMA, 2-chain) -> residual+scale epilogue.
#define SP 1048   // S-LDS pitch (ushorts): bank stride 12 -> <=2-way
template <bool ATTN2>
__global__ __launch_bounds__(256) void attn_fused_kernel(
    const ushort* __restrict__ qT, const ushort* __restrict__ kT,
    const ushort* __restrict__ vb, const float* __restrict__ resid,
    float* __restrict__ attnf, float* __restrict__ outf,
    ushort* __restrict__ outb_pad, float scale) {
  __shared__ ushort s_lds[16 * SP];
  __shared__ float wmax[4][16], wsum[4][16];
  int t = threadIdx.x, wave = t >> 6, lane = t & 63;
  int lo = lane & 15, lg = lane >> 4;
  int n0 = blockIdx.x * 16, b = blockIdx.y;
  int m0 = wave * 256;
  short8 a = *(const short8*)(qT + ((size_t)b * NTOK + n0 + lo) * NHID + 8 * lg);
  f32x4 acc[16];
#pragma unroll
  for (int j = 0; j < 16; ++j) {
    short8 bf = *(const short8*)(kT + ((size_t)b * NTOK + m0 + j * 16 + lo) * NHID + 8 * lg);
    f32x4 z = {0.f, 0.f, 0.f, 0.f};
    acc[j] = __builtin_amdgcn_mfma_f32_16x16x32_bf16(a, bf, z, 0, 0, 0);
  }
  float pm[4];
#pragma unroll
  for (int r = 0; r < 4; ++r) {
    float m = acc[0][r];
#pragma unroll
    for (int j = 1; j < 16; ++j) m = fmaxf(m, acc[j][r]);
#pragma unroll
    for (int off = 1; off < 16; off <<= 1) m = fmaxf(m, __shfl_xor(m, off, 64));
    pm[r] = m;
  }
  if (lo == 0)
#pragma unroll
    for (int r = 0; r < 4; ++r) wmax[wave][4 * lg + r] = pm[r];
  __syncthreads();
  float mr[4];
#pragma unroll
  for (int r = 0; r < 4; ++r)
    mr[r] = fmaxf(fmaxf(wmax[0][4 * lg + r], wmax[1][4 * lg + r]),
                  fmaxf(wmax[2][4 * lg + r], wmax[3][4 * lg + r]));
  float ps[4] = {0.f, 0.f, 0.f, 0.f};
#pragma unroll
  for (int j = 0; j < 16; ++j)
#pragma unroll
    for (int r = 0; r < 4; ++r) {
      float e = __expf(acc[j][r] - mr[r]);
      acc[j][r] = e;
      ps[r] += e;
    }
#pragma unroll
  for (int r = 0; r < 4; ++r)
#pragma unroll
    for (int off = 1; off < 16; off <<= 1) ps[r] += __shfl_xor(ps[r], off, 64);
  if (lo == 0)
#pragma unroll
    for (int r = 0; r < 4; ++r) wsum[wave][4 * lg + r] = ps[r];
  __syncthreads();
  float inv[4];
#pragma unroll
  for (int r = 0; r < 4; ++r)
    inv[r] = 1.f / (wsum[0][4 * lg + r] + wsum[1][4 * lg + r] +
                    wsum[2][4 * lg + r] + wsum[3][4 * lg + r]);
#pragma unroll
  for (int j = 0; j < 16; ++j)
#pragma unroll
    for (int r = 0; r < 4; ++r)
      s_lds[(4 * lg + r) * SP + m0 + j * 16 + lo] = f2b(acc[j][r] * inv[r]);
  __syncthreads();
  if constexpr (ATTN2) {
    int ml = lane * 4;
    float* abase = attnf + ((size_t)b * NTOK + n0) * NTOK + m0;
#pragma unroll
    for (int n = 0; n < 16; ++n) {
      ushort4 sv = *(const ushort4*)(s_lds + n * SP + m0 + ml);
      float4 o;
      o.x = b2f(sv.x); o.y = b2f(sv.y); o.z = b2f(sv.z); o.w = b2f(sv.w);
      *(float4*)(abase + (size_t)n * NTOK + ml) = o;
    }
  }
  int cb = wave * 16;
  const ushort* vbb = vb + ((size_t)b * NC + cb + lo) * NTOK;
  f32x4 acc2 = {0.f, 0.f, 0.f, 0.f}, acc3 = {0.f, 0.f, 0.f, 0.f};
  for (int ms = 0; ms < NTOK; ms += 64) {
    short8 af0 = *(const short8*)(s_lds + lo * SP + ms + 8 * lg);
    short8 bf0 = *(const short8*)(vbb + ms + 8 * lg);
    short8 af1 = *(const short8*)(s_lds + lo * SP + ms + 32 + 8 * lg);
    short8 bf1 = *(const short8*)(vbb + ms + 32 + 8 * lg);
    acc2 = __builtin_amdgcn_mfma_f32_16x16x32_bf16(af0, bf0, acc2, 0, 0, 0);
    acc3 = __builtin_amdgcn_mfma_f32_16x16x32_bf16(af1, bf1, acc3, 0, 0, 0);
  }
#pragma unroll
  for (int r = 0; r < 4; ++r) acc2[r] += acc3[r];
  int c = cb + lo;
  float4 rv = *(const float4*)(resid + ((size_t)b * NC + c) * NTOK + n0 + 4 * lg);
  float rvv[4] = {rv.x, rv.y, rv.z, rv.w};
  if constexpr (ATTN2) {
    float4 o;
    o.x = scale * (rvv[0] + acc2[0]); o.y = scale * (rvv[1] + acc2[1]);
    o.z = scale * (rvv[2] + acc2[2]); o.w = scale * (rvv[3] + acc2[3]);
    *(float4*)(outf + ((size_t)b * NC + c) * NTOK + n0 + 4 * lg) = o;
  } else {
#pragma unroll
    for (int r = 0; r < 4; ++r) {
      int tok = n0 + 4 * lg + r;
      float val = scale * (rvv[r] + acc2[r]);
      outb_pad[(size_t)b * PAD_BSTRIDE + ((tok >> 5) + 2) * 2304 +
               ((tok & 31) + 2) * 64 + c] = f2b(val);
    }
  }
}

// ---- conv weight pre-pass: W_lstm[oc][ic][5][5] f32 -> Wb[oc][25][128] bf16
__global__ __launch_bounds__(256) void wpre_kernel(
    const float* __restrict__ W, ushort* __restrict__ Wb) {
  int idx = blockIdx.x * 256 + threadIdx.x;
  const float* src = W + (size_t)idx * 25;
#pragma unroll
  for (int kk = 0; kk < 25; ++kk)
    Wb[((size_t)(idx >> 7) * 25 + kk) * 128 + (idx & 127)] = f2b(src[kk]);
}

// ---- FUSED conv + LSTM, 2 wg/CU. wg = 4 waves = 128 gate-rows (32 ch x 4
// gates, chh half in grid) x 64 px (2 rows). Wave: gate-quad of a 16-ch block
// x 32 px -> thread holds i,f,o,g for its (channel,px) -> LSTM in epilogue.
// K = 50 steps (25 taps x 2 kh) of 128x64ic A-tiles, dbuf, 1 barrier/step;
// B window (6x36x64ic, one kh) restaged once at the kh switch.
// Grid (16 pt, 2 chh, 16 b) = 512 wgs. LDS 71.7 KB -> 2 wg/CU.
#define AP 76
#define BP 76
__global__ __launch_bounds__(256, 2) void conv_lstm_kernel(
    const ushort* __restrict__ pad,   // [b][2][36*36][64] bf16
    const ushort* __restrict__ Wb,    // [256 oc][25 kk][128 ic] bf16
    const float* __restrict__ bias, const float* __restrict__ c_in,
    float* __restrict__ c_out, float* __restrict__ h_out) {
  __shared__ ushort ldsA[2][128 * AP];  // ping-pong [gate-row][64 ic]
  __shared__ ushort ldsB[216 * BP];     // [6 rows x 36 cols][64 ic], one kh
  int t = threadIdx.x;
  int lane = t & 63, lo = lane & 15, lg = lane >> 4;
  int wid = t >> 6, cb = wid & 1, ph = wid >> 1;   // cb: 16-ch block, ph: px row
  int pt = blockIdx.x, chh = blockIdx.y, b = blockIdx.z;
  const ushort* pb = pad + (size_t)b * PAD_BSTRIDE + (size_t)(pt * 2) * 2304;

  // stage B window for kh=0 (contiguous src, pre-padded zeros)
  for (int i = t; i < 1728; i += 256) {
    int pxw = i >> 3, ch8 = (i & 7) * 8;
    uint4 v = *(const uint4*)(pb + (size_t)pxw * 64 + ch8);
    *(uint4*)(ldsB + pxw * BP + ch8) = v;
  }

  // per-thread A staging: 4 x 16B chunks cover 128 rows x 64 ic.
  // row r: gate = r>>5, oc = gate*64 + chh*32 + (r&31)
  const ushort *wsrc0, *wsrc1, *wsrc2, *wsrc3;
  int adst0, adst1, adst2, adst3;
  {
    int i0 = t, i1 = 256 + t, i2 = 512 + t, i3 = 768 + t;
    int r0 = i0 >> 3, r1 = i1 >> 3, r2 = i2 >> 3, r3 = i3 >> 3;
    wsrc0 = Wb + (size_t)((r0 >> 5) * 64 + chh * 32 + (r0 & 31)) * 3200 + (i0 & 7) * 8;
    wsrc1 = Wb + (size_t)((r1 >> 5) * 64 + chh * 32 + (r1 & 31)) * 3200 + (i1 & 7) * 8;
    wsrc2 = Wb + (size_t)((r2 >> 5) * 64 + chh * 32 + (r2 & 31)) * 3200 + (i2 & 7) * 8;
    wsrc3 = Wb + (size_t)((r3 >> 5) * 64 + chh * 32 + (r3 & 31)) * 3200 + (i3 & 7) * 8;
    adst0 = r0 * AP + (i0 & 7) * 8;
    adst1 = r1 * AP + (i1 & 7) * 8;
    adst2 = r2 * AP + (i2 & 7) * 8;
    adst3 = r3 * AP + (i3 & 7) * 8;
  }
  // koff(s) = tap*128 + kh*64, s = kh*25 + tap
  uint4 w0 = *(const uint4*)(wsrc0);        // step 0
  uint4 w1 = *(const uint4*)(wsrc1);
  uint4 w2 = *(const uint4*)(wsrc2);
  uint4 w3 = *(const uint4*)(wsrc3);

  f32x4 acc[4][2];
#pragma unroll
  for (int i = 0; i < 4; ++i)
#pragma unroll
    for (int j = 0; j < 2; ++j) acc[i][j] = {0.f, 0.f, 0.f, 0.f};

  __syncthreads();            // B staged
  *(uint4*)(&ldsA[0][adst0]) = w0;
  *(uint4*)(&ldsA[0][adst1]) = w1;
  *(uint4*)(&ldsA[0][adst2]) = w2;
  *(uint4*)(&ldsA[0][adst3]) = w3;
  w0 = *(const uint4*)(wsrc0 + 128);        // step 1
  w1 = *(const uint4*)(wsrc1 + 128);
  w2 = *(const uint4*)(wsrc2 + 128);
  w3 = *(const uint4*)(wsrc3 + 128);
  __syncthreads();            // A0 ready

  for (int s = 0; s < 50; ++s) {
    int cur = s & 1;
    if (s < 49) {
      int nxt = cur ^ 1;
      *(uint4*)(&ldsA[nxt][adst0]) = w0;
      *(uint4*)(&ldsA[nxt][adst1]) = w1;
      *(uint4*)(&ldsA[nxt][adst2]) = w2;
      *(uint4*)(&ldsA[nxt][adst3]) = w3;
      int s2 = (s < 48) ? s + 2 : 49;
      int koff = (s2 < 25) ? s2 * 128 : (s2 - 25) * 128 + 64;
      w0 = *(const uint4*)(wsrc0 + koff);
      w1 = *(const uint4*)(wsrc1 + koff);
      w2 = *(const uint4*)(wsrc2 + koff);
      w3 = *(const uint4*)(wsrc3 + koff);
    }
    int kh = (s >= 25);
    int tap = s - kh * 25;
    int ky = tap / 5, kx = tap - 5 * ky;
    int bbase = (ky * 36 + kx) * BP;
#pragma unroll
    for (int icc = 0; icc < 2; ++icc) {
      short8 af[4], bf[2];
#pragma unroll
      for (int i = 0; i < 4; ++i)   // i = gate; A row = gate*32 + cb*16 + lo
        af[i] = *(const short8*)(&ldsA[cur][(i * 32 + cb * 16 + lo) * AP + icc * 32 + 8 * lg]);
#pragma unroll
      for (int j = 0; j < 2; ++j)
        bf[j] = *(const short8*)(ldsB + bbase + (ph * 36 + j * 16 + lo) * BP + icc * 32 + 8 * lg);
#pragma unroll
      for (int i = 0; i < 4; ++i)
#pragma unroll
        for (int j = 0; j < 2; ++j)
          acc[i][j] = __builtin_amdgcn_mfma_f32_16x16x32_bf16(af[i], bf[j], acc[i][j], 0, 0, 0);
    }
    __syncthreads();
    if (s == 24) {
      // restage B for kh=1 (reads of kh0 window all done at the barrier above)
      for (int i = t; i < 1728; i += 256) {
        int pxw = i >> 3, ch8 = (i & 7) * 8;
        uint4 v = *(const uint4*)(pb + PAD_KSTRIDE + (size_t)pxw * 64 + ch8);
        *(uint4*)(ldsB + pxw * BP + ch8) = v;
      }
      __syncthreads();
    }
  }

  // LSTM epilogue: thread holds gates i/f/o/g at (ch, p)
#pragma unroll
  for (int j = 0; j < 2; ++j)
#pragma unroll
    for (int r = 0; r < 4; ++r) {
      int ch = chh * 32 + cb * 16 + lg * 4 + r;
      int p = pt * 64 + ph * 32 + j * 16 + lo;
      size_t ci = ((size_t)b * NC + ch) * NTOK + p;
      float iv = sigm(acc[0][j][r] + bias[ch]);
      float fv = sigm(acc[1][j][r] + bias[64 + ch]);
      float ov = sigm(acc[2][j][r] + bias[128 + ch]);
      float gv = tanh_fast(acc[3][j][r] + bias[192 + ch]);
      float cn = fv * c_in[ci] + iv * gv;
      c_out[ci] = cn;
      h_out[ci] = ov * tanh_fast(cn);
    }
}

extern "C" void kernel_launch(void* const* d_in, const int* in_sizes, int n_in,
                              void* d_out, int out_size, void* d_ws, size_t ws_size,
                              hipStream_t stream) {
  const float* x      = (const float*)d_in[0];
  const float* h      = (const float*)d_in[1];
  const float* c      = (const float*)d_in[2];
  const float* Wq_x   = (const float*)d_in[3];
  const float* Wk_x   = (const float*)d_in[4];
  const float* Wv_x   = (const float*)d_in[5];
  const float* Wq_h   = (const float*)d_in[6];
  const float* Wk_h   = (const float*)d_in[7];
  const float* Wv_h   = (const float*)d_in[8];
  const float* W_lstm = (const float*)d_in[9];
  const float* b_lstm = (const float*)d_in[10];

  float* out   = (float*)d_out;
  float* new_h = out;                 // [16,64,32,32]
  float* new_c = out + 1048576;       // [16,64,32,32]
  float* atten = out + 2097152;       // [16,1024,1024]

  // ws layout (ushort granularity)
  ushort* wsu = (ushort*)d_ws;
  ushort* qT  = wsu;                  //   524,288 ushort [b][n][32]
  ushort* kT  = wsu + 524288;         //   524,288
  ushort* vb  = wsu + 1048576;        // 1,048,576 [b][c][m]

  // scratch aliased into the atten output region (dead until attn2):
  ushort* Wb    = (ushort*)(atten + 8388608);   // conv weights, bytes [33.55M,35.2M)
  ushort* pad   = (ushort*)(atten + 9437184);   // padded conv input, [37.7M,43.1M)
  float*  h_mid = new_h;                        // lstm h lives in new_h slot

  dim3 blk(256);
  // zero the padded conv-input ring (interiors overwritten below)
  hipMemsetAsync(pad, 0, PAD_BYTES, stream);
  // ---- attention 1 on x (fused; scores never touch HBM) ----
  qkvproj_kernel<<<dim3(16, NB), blk, 0, stream>>>(x, Wq_x, Wk_x, Wv_x, qT, kT, vb);
  attn_fused_kernel<false><<<dim3(64, NB), blk, 0, stream>>>(
      qT, kT, vb, x, nullptr, nullptr, pad /*kh0 interior*/, 1.0f);
  // ---- conv-lstm (bf16 MFMA implicit GEMM, fused LSTM epilogue, 2 wg/CU) ----
  wpre_kernel<<<128, blk, 0, stream>>>(W_lstm, Wb);
  tpose_pad_kernel<<<dim3(16, NB), blk, 0, stream>>>(h, pad + PAD_KSTRIDE);
  conv_lstm_kernel<<<dim3(16, 2, NB), blk, 0, stream>>>(pad, Wb, b_lstm, c, new_c, h_mid);
  // ---- attention 2 on h_mid (atten f32 is a real output) ----
  qkvproj_kernel<<<dim3(16, NB), blk, 0, stream>>>(h_mid, Wq_h, Wk_h, Wv_h, qT, kT, vb);
  attn_fused_kernel<true><<<dim3(64, NB), blk, 0, stream>>>(
      qT, kT, vb, h_mid, atten, new_h, nullptr, 2.0f);
}